// Round 5
// baseline (2157.989 us; speedup 1.0000x reference)
//
#include <hip/hip_runtime.h>
#include <hip/hip_bf16.h>

#define NLAYERS 4

// ---------------- small zero kernels ----------------
__global__ void zero_ints(int* __restrict__ p, int n)
{
    int i = blockIdx.x * 256 + threadIdx.x;
    if (i < n) p[i] = 0;
}
__global__ void zero_dacc(double* __restrict__ p)
{
    int i = threadIdx.x;
    if (i < 128) p[i] = 0.0;
}

// ---------------- CSR build ----------------
__global__ void hist_kernel(const int* __restrict__ dsts, int* __restrict__ counts, int E)
{
    int i = blockIdx.x * 256 + threadIdx.x;
    if (i < E) atomicAdd(&counts[dsts[i]], 1);
}

// exclusive scan, 1024 elems per block (256 thr x 4)
__global__ __launch_bounds__(256) void scan1(const int* __restrict__ counts,
                                             int* __restrict__ offsets,
                                             int* __restrict__ blocksums, int N)
{
    __shared__ int sdata[256];
    int t = threadIdx.x;
    int bbase = blockIdx.x * 1024;
    int v[4]; int s = 0;
#pragma unroll
    for (int q = 0; q < 4; q++) {
        int idx = bbase + t * 4 + q;
        v[q] = (idx < N) ? counts[idx] : 0;
        s += v[q];
    }
    sdata[t] = s;
    __syncthreads();
    for (int off = 1; off < 256; off <<= 1) {
        int x = (t >= off) ? sdata[t - off] : 0;
        __syncthreads();
        sdata[t] += x;
        __syncthreads();
    }
    int excl = sdata[t] - s;
    int run = excl;
#pragma unroll
    for (int q = 0; q < 4; q++) {
        int idx = bbase + t * 4 + q;
        if (idx < N) offsets[idx] = run;
        run += v[q];
    }
    if (t == 255) blocksums[blockIdx.x] = sdata[255];
}

__global__ void scan2(int* __restrict__ blocksums, int nb)
{
    if (threadIdx.x == 0 && blockIdx.x == 0) {
        int run = 0;
        for (int b = 0; b < nb; b++) { int t = blocksums[b]; blocksums[b] = run; run += t; }
    }
}

__global__ void scan3(int* __restrict__ offsets, const int* __restrict__ blocksums,
                      int* __restrict__ cursor, int N)
{
    int i = blockIdx.x * 256 + threadIdx.x;
    if (i < N) {
        int v = offsets[i] + blocksums[i >> 10];
        offsets[i] = v;
        cursor[i] = v;
    }
}

__global__ void scatter_kernel(const int* __restrict__ srcs, const int* __restrict__ dsts,
                               int* __restrict__ cursor, int* __restrict__ perm,
                               int* __restrict__ srcp, int* __restrict__ dstp, int E)
{
    int i = blockIdx.x * 256 + threadIdx.x;
    if (i < E) {
        int d = dsts[i];
        int slot = atomicAdd(&cursor[d], 1);
        perm[slot] = i;
        srcp[slot] = srcs[i];
        dstp[slot] = d;
    }
}

// ---------------- init projections ----------------
__global__ void init_proj4(const float* __restrict__ in, const float* __restrict__ w,
                           const float* __restrict__ b, float4* __restrict__ out, size_t n4)
{
    size_t i = (size_t)blockIdx.x * 256 + threadIdx.x;
    if (i < n4) {
        int j4 = (int)(i & 7) * 4;
        float xv = in[i >> 3];
        float4 wv = *(const float4*)(w + j4);
        float4 bv = *(const float4*)(b + j4);
        out[i] = make_float4(fmaf(xv, wv.x, bv.x), fmaf(xv, wv.y, bv.y),
                             fmaf(xv, wv.z, bv.z), fmaf(xv, wv.w, bv.w));
    }
}

// permuted edge init: row i gets e_in[perm[i]]
__global__ void init_ep4(const float* __restrict__ e_in, const int* __restrict__ perm,
                         const float* __restrict__ w, const float* __restrict__ b,
                         float4* __restrict__ out, size_t n4)
{
    size_t i = (size_t)blockIdx.x * 256 + threadIdx.x;
    if (i < n4) {
        int row = (int)(i >> 3);
        float xv = e_in[perm[row]];
        int j4 = (int)(i & 7) * 4;
        float4 wv = *(const float4*)(w + j4);
        float4 bv = *(const float4*)(b + j4);
        out[i] = make_float4(fmaf(xv, wv.x, bv.x), fmaf(xv, wv.y, bv.y),
                             fmaf(xv, wv.z, bv.z), fmaf(xv, wv.w, bv.w));
    }
}

// ---------------- node GEMMs: one node per thread, scalar-broadcast weights ----------------
__device__ __forceinline__ void mat32(const float* __restrict__ hrow,
                                      const float* __restrict__ W, const float* __restrict__ Wb,
                                      float* __restrict__ dst)
{
    float acc[32];
#pragma unroll
    for (int j = 0; j < 32; j++) acc[j] = Wb[j];
#pragma unroll 4
    for (int k = 0; k < 32; k++) {
        float hk = hrow[k];
#pragma unroll
        for (int j = 0; j < 32; j++) acc[j] = fmaf(hk, W[k * 32 + j], acc[j]);
    }
    float4* o = (float4*)dst;
#pragma unroll
    for (int q = 0; q < 8; q++) o[q] = make_float4(acc[4*q], acc[4*q+1], acc[4*q+2], acc[4*q+3]);
}

__global__ __launch_bounds__(64) void node_gemm(
    const float* __restrict__ h,
    const float* __restrict__ Aw, const float* __restrict__ Ab,
    const float* __restrict__ Bw, const float* __restrict__ Bb,
    const float* __restrict__ Uw, const float* __restrict__ Ub,
    const float* __restrict__ Vw, const float* __restrict__ Vb,
    float* __restrict__ Ahh, float* __restrict__ Bhh,
    float* __restrict__ Uhh, float* __restrict__ Vhh, int N)
{
    int nid = blockIdx.x * 64 + threadIdx.x;
    if (nid >= N) return;
    const float* hrow = h + (size_t)nid * 32;
    size_t o = (size_t)nid * 32;
    mat32(hrow, Aw, Ab, Ahh + o);
    mat32(hrow, Bw, Bb, Bhh + o);
    mat32(hrow, Uw, Ub, Uhh + o);
    mat32(hrow, Vw, Vb, Vhh + o);
}

// ---- aggregation: one 32-lane group per node, CSR segment walk, no atomics ----
__global__ __launch_bounds__(256) void agg_kernel(
    const float* __restrict__ ep, const int* __restrict__ srcp,
    const int* __restrict__ offsets, const int* __restrict__ counts,
    const float* __restrict__ Ah, const float* __restrict__ Bh,
    const float* __restrict__ Vh, const float* __restrict__ Uh,
    const float* __restrict__ Cw, const float* __restrict__ Cb,
    float* __restrict__ hnew, double* __restrict__ dacc, int N)
{
    __shared__ float red[256];
    int tid = threadIdx.x, j = tid & 31, half = tid >> 5;
    int node = blockIdx.x * 8 + half;
    float cw[32];
#pragma unroll
    for (int k = 0; k < 32; k++) cw[k] = Cw[k * 32 + j];
    float cb = Cb[j];
    float esum = 0.f, esq = 0.f, hsum = 0.f, hsq = 0.f;
    if (node < N) {
        int start = offsets[node], len = counts[node];
        float anum = 0.f, aden = 0.f;
        float ahd = Ah[(size_t)node * 32 + j];
        for (int q = 0; q < len; q++) {
            int pos = start + q;
            int s = srcp[pos];
            const float4* er = (const float4*)(ep + (size_t)pos * 32);
            float4 e0 = er[0], e1 = er[1], e2 = er[2], e3 = er[3];
            float4 e4 = er[4], e5 = er[5], e6 = er[6], e7 = er[7];
            float a0 = cb, a1 = 0.f, a2 = 0.f, a3 = 0.f;
            a0 = fmaf(e0.x, cw[0],  a0); a0 = fmaf(e0.y, cw[1],  a0);
            a0 = fmaf(e0.z, cw[2],  a0); a0 = fmaf(e0.w, cw[3],  a0);
            a1 = fmaf(e1.x, cw[4],  a1); a1 = fmaf(e1.y, cw[5],  a1);
            a1 = fmaf(e1.z, cw[6],  a1); a1 = fmaf(e1.w, cw[7],  a1);
            a2 = fmaf(e2.x, cw[8],  a2); a2 = fmaf(e2.y, cw[9],  a2);
            a2 = fmaf(e2.z, cw[10], a2); a2 = fmaf(e2.w, cw[11], a2);
            a3 = fmaf(e3.x, cw[12], a3); a3 = fmaf(e3.y, cw[13], a3);
            a3 = fmaf(e3.z, cw[14], a3); a3 = fmaf(e3.w, cw[15], a3);
            a0 = fmaf(e4.x, cw[16], a0); a0 = fmaf(e4.y, cw[17], a0);
            a0 = fmaf(e4.z, cw[18], a0); a0 = fmaf(e4.w, cw[19], a0);
            a1 = fmaf(e5.x, cw[20], a1); a1 = fmaf(e5.y, cw[21], a1);
            a1 = fmaf(e5.z, cw[22], a1); a1 = fmaf(e5.w, cw[23], a1);
            a2 = fmaf(e6.x, cw[24], a2); a2 = fmaf(e6.y, cw[25], a2);
            a2 = fmaf(e6.z, cw[26], a2); a2 = fmaf(e6.w, cw[27], a2);
            a3 = fmaf(e7.x, cw[28], a3); a3 = fmaf(e7.y, cw[29], a3);
            a3 = fmaf(e7.z, cw[30], a3); a3 = fmaf(e7.w, cw[31], a3);
            float en = (a0 + a1) + (a2 + a3) + ahd + Bh[(size_t)s * 32 + j];
            float sg = 1.f / (1.f + __expf(-en));
            anum = fmaf(sg, Vh[(size_t)s * 32 + j], anum);
            aden += sg;
            esum += en; esq += en * en;
        }
        float hv = Uh[(size_t)node * 32 + j] + anum / (aden + 1e-6f);
        hnew[(size_t)node * 32 + j] = hv;
        hsum = hv; hsq = hv * hv;
    }
    red[tid] = esum; __syncthreads();
    if (tid < 32) { float s = 0.f; for (int r = 0; r < 8; r++) s += red[r * 32 + tid]; atomicAdd(&dacc[64 + tid], (double)s); }
    __syncthreads();
    red[tid] = esq; __syncthreads();
    if (tid < 32) { float s = 0.f; for (int r = 0; r < 8; r++) s += red[r * 32 + tid]; atomicAdd(&dacc[96 + tid], (double)s); }
    __syncthreads();
    red[tid] = hsum; __syncthreads();
    if (tid < 32) { float s = 0.f; for (int r = 0; r < 8; r++) s += red[r * 32 + tid]; atomicAdd(&dacc[tid], (double)s); }
    __syncthreads();
    red[tid] = hsq; __syncthreads();
    if (tid < 32) { float s = 0.f; for (int r = 0; r < 8; r++) s += red[r * 32 + tid]; atomicAdd(&dacc[32 + tid], (double)s); }
}

// ---------------- finalize BN stats from double accumulators ----------------
__global__ void stats_finalize(const double* __restrict__ dacc, double cntH, double cntE,
                               const float* __restrict__ gH, const float* __restrict__ bH,
                               const float* __restrict__ gE, const float* __restrict__ bE,
                               float* __restrict__ stats)
{
    int tid = threadIdx.x;
    const double* p = dacc + blockIdx.x * 64;
    double cnt = blockIdx.x ? cntE : cntH;
    const float* g = blockIdx.x ? gE : gH;
    const float* b = blockIdx.x ? bE : bH;
    float* outp = stats + blockIdx.x * 64;
    if (tid < 32) {
        double mean = p[tid] / cnt;
        double var = p[32 + tid] / cnt - mean * mean;
        float scale = g[tid] * (float)(1.0 / sqrt(var + 1e-5));
        outp[tid] = scale;
        outp[32 + tid] = b[tid] - (float)mean * scale;
    }
}

// ---------------- apply (h, float4): acc += relu(pre*scale + shift) ----------------
__global__ void apply4(const float4* __restrict__ pre, const float* __restrict__ scale,
                       const float* __restrict__ shift, float4* __restrict__ acc, size_t n4)
{
    size_t i = (size_t)blockIdx.x * 256 + threadIdx.x;
    if (i < n4) {
        int j4 = (int)(i & 7) * 4;
        float4 sc = *(const float4*)(scale + j4);
        float4 sh = *(const float4*)(shift + j4);
        float4 p = pre[i], a = acc[i];
        a.x += fmaxf(fmaf(p.x, sc.x, sh.x), 0.f);
        a.y += fmaxf(fmaf(p.y, sc.y, sh.y), 0.f);
        a.z += fmaxf(fmaf(p.z, sc.z, sh.z), 0.f);
        a.w += fmaxf(fmaf(p.w, sc.w, sh.w), 0.f);
        acc[i] = a;
    }
}

// ---- edge apply: recompute e_new (same FMA order as agg), BN+ReLU+residual in place ----
__global__ __launch_bounds__(256) void apply_ep(
    float* __restrict__ ep, const int* __restrict__ srcp, const int* __restrict__ dstp,
    const float* __restrict__ Ah, const float* __restrict__ Bh,
    const float* __restrict__ Cw, const float* __restrict__ Cb,
    const float* __restrict__ sc, const float* __restrict__ sh, int E)
{
    __shared__ float le[256];
    __shared__ int lsrc[8], ldst[8];
    int tid = threadIdx.x, j = tid & 31, el = tid >> 5;
    float cw[32];
#pragma unroll
    for (int k = 0; k < 32; k++) cw[k] = Cw[k * 32 + j];
    float cb = Cb[j];
    float scale = sc[j], shift = sh[j];
    int ng = (E + 7) >> 3;
    for (int g = blockIdx.x; g < ng; g += gridDim.x) {
        int base = g << 3;
        __syncthreads();
        if (tid < 64) {
            int row = base + (tid >> 3);
            if (row < E) ((float4*)le)[tid] = ((const float4*)(ep + (size_t)base * 32))[tid];
        }
        if (tid < 8) {
            int ee = base + tid;
            if (ee < E) { lsrc[tid] = srcp[ee]; ldst[tid] = dstp[ee]; }
        }
        __syncthreads();
        int eid = base + el;
        if (eid < E) {
            const float4* lr = (const float4*)(le + el * 32);
            float4 e0 = lr[0], e1 = lr[1], e2 = lr[2], e3 = lr[3];
            float4 e4 = lr[4], e5 = lr[5], e6 = lr[6], e7 = lr[7];
            float a0 = cb, a1 = 0.f, a2 = 0.f, a3 = 0.f;
            a0 = fmaf(e0.x, cw[0],  a0); a0 = fmaf(e0.y, cw[1],  a0);
            a0 = fmaf(e0.z, cw[2],  a0); a0 = fmaf(e0.w, cw[3],  a0);
            a1 = fmaf(e1.x, cw[4],  a1); a1 = fmaf(e1.y, cw[5],  a1);
            a1 = fmaf(e1.z, cw[6],  a1); a1 = fmaf(e1.w, cw[7],  a1);
            a2 = fmaf(e2.x, cw[8],  a2); a2 = fmaf(e2.y, cw[9],  a2);
            a2 = fmaf(e2.z, cw[10], a2); a2 = fmaf(e2.w, cw[11], a2);
            a3 = fmaf(e3.x, cw[12], a3); a3 = fmaf(e3.y, cw[13], a3);
            a3 = fmaf(e3.z, cw[14], a3); a3 = fmaf(e3.w, cw[15], a3);
            a0 = fmaf(e4.x, cw[16], a0); a0 = fmaf(e4.y, cw[17], a0);
            a0 = fmaf(e4.z, cw[18], a0); a0 = fmaf(e4.w, cw[19], a0);
            a1 = fmaf(e5.x, cw[20], a1); a1 = fmaf(e5.y, cw[21], a1);
            a1 = fmaf(e5.z, cw[22], a1); a1 = fmaf(e5.w, cw[23], a1);
            a2 = fmaf(e6.x, cw[24], a2); a2 = fmaf(e6.y, cw[25], a2);
            a2 = fmaf(e6.z, cw[26], a2); a2 = fmaf(e6.w, cw[27], a2);
            a3 = fmaf(e7.x, cw[28], a3); a3 = fmaf(e7.y, cw[29], a3);
            a3 = fmaf(e7.z, cw[30], a3); a3 = fmaf(e7.w, cw[31], a3);
            int s = lsrc[el], d = ldst[el];
            float en = (a0 + a1) + (a2 + a3) + Ah[(size_t)d * 32 + j] + Bh[(size_t)s * 32 + j];
            float v = fmaf(en, scale, shift);
            ep[(size_t)eid * 32 + j] = le[el * 32 + j] + fmaxf(v, 0.f);
        }
    }
}

// ---------------- predictor: one permuted edge per thread, scatter output ----------------
__global__ __launch_bounds__(256) void predictor(
    const float* __restrict__ h, const float* __restrict__ ep,
    const int* __restrict__ srcp, const int* __restrict__ dstp, const int* __restrict__ perm,
    const float* __restrict__ W1, const float* __restrict__ b1,
    const float* __restrict__ W2, const float* __restrict__ b2v,
    float* __restrict__ out, int E)
{
    int pos = blockIdx.x * 256 + threadIdx.x;
    if (pos >= E) return;
    int s = srcp[pos], d = dstp[pos];
    float acc[32];
#pragma unroll
    for (int j = 0; j < 32; j++) acc[j] = b1[j];
    const float* zs = h + (size_t)s * 32;
    const float* zd = h + (size_t)d * 32;
    const float* ze = ep + (size_t)pos * 32;
#pragma unroll 4
    for (int k = 0; k < 32; k++) {
        float zk = zs[k];
#pragma unroll
        for (int j = 0; j < 32; j++) acc[j] = fmaf(zk, W1[k * 32 + j], acc[j]);
    }
#pragma unroll 4
    for (int k = 0; k < 32; k++) {
        float zk = zd[k];
#pragma unroll
        for (int j = 0; j < 32; j++) acc[j] = fmaf(zk, W1[(32 + k) * 32 + j], acc[j]);
    }
#pragma unroll 4
    for (int k = 0; k < 32; k++) {
        float zk = ze[k];
#pragma unroll
        for (int j = 0; j < 32; j++) acc[j] = fmaf(zk, W1[(64 + k) * 32 + j], acc[j]);
    }
    float t = b2v[0];
#pragma unroll
    for (int j = 0; j < 32; j++) t += fmaxf(acc[j], 0.f) * W2[j];
    out[perm[pos]] = t;
}

extern "C" void kernel_launch(void* const* d_in, const int* in_sizes, int n_in,
                              void* d_out, int out_size, void* d_ws, size_t ws_size,
                              hipStream_t stream)
{
    const int N = in_sizes[0];
    const int E = in_sizes[1];

    const float* x    = (const float*)d_in[0];
    const float* e_in = (const float*)d_in[1];
    const int*   eidx = (const int*)d_in[2];
    const float* pe_w = (const float*)d_in[3];
    const float* pe_b = (const float*)d_in[4];
    const float* ed_w = (const float*)d_in[5];
    const float* ed_b = (const float*)d_in[6];
    const float* Aw = (const float*)d_in[7];
    const float* Ab = (const float*)d_in[8];
    const float* Bw = (const float*)d_in[9];
    const float* Bb = (const float*)d_in[10];
    const float* Cw = (const float*)d_in[11];
    const float* Cb = (const float*)d_in[12];
    const float* Uw = (const float*)d_in[13];
    const float* Ub = (const float*)d_in[14];
    const float* Vw = (const float*)d_in[15];
    const float* Vb = (const float*)d_in[16];
    const float* bn_h_g = (const float*)d_in[17];
    const float* bn_h_b = (const float*)d_in[18];
    const float* bn_e_g = (const float*)d_in[19];
    const float* bn_e_b = (const float*)d_in[20];
    const float* W1w = (const float*)d_in[21];
    const float* W1b = (const float*)d_in[22];
    const float* W2w = (const float*)d_in[23];
    const float* W2b = (const float*)d_in[24];

    const int* srcs = eidx;
    const int* dsts = eidx + E;

    size_t nh = (size_t)N * 32;
    size_t eh = (size_t)E * 32;

    double* dacc = (double*)d_ws;            // 128 doubles
    float* stats = (float*)(dacc + 128);     // 128 floats
    float* h    = stats + 128;
    float* Ah   = h + nh;
    float* Bh   = Ah + nh;
    float* Uh   = Bh + nh;
    float* Vh   = Uh + nh;
    float* hnew = Vh + nh;
    float* ep   = hnew + nh;
    int* counts    = (int*)(ep + eh);
    int* offsets   = counts + N;
    int* cursor    = offsets + N;
    int* blocksums = cursor + N;   // 128
    int* perm      = blocksums + 128;
    int* srcp      = perm + E;
    int* dstp      = srcp + E;

    size_t nh4 = nh / 4, eh4 = eh / 4;
    int gh4 = (int)((nh4 + 255) / 256);
    int ge4 = (int)((eh4 + 255) / 256);
    int gN = (N + 255) / 256;
    int gE = (E + 255) / 256;
    int nb = (N + 1023) / 1024;

    // ---- CSR build (dst-sorted edge permutation) ----
    zero_ints<<<gN, 256, 0, stream>>>(counts, N);
    hist_kernel<<<gE, 256, 0, stream>>>(dsts, counts, E);
    scan1<<<nb, 256, 0, stream>>>(counts, offsets, blocksums, N);
    scan2<<<1, 64, 0, stream>>>(blocksums, nb);
    scan3<<<gN, 256, 0, stream>>>(offsets, blocksums, cursor, N);
    scatter_kernel<<<gE, 256, 0, stream>>>(srcs, dsts, cursor, perm, srcp, dstp, E);

    // ---- input projections ----
    init_proj4<<<gh4, 256, 0, stream>>>(x, pe_w, pe_b, (float4*)h, nh4);
    init_ep4<<<ge4, 256, 0, stream>>>(e_in, perm, ed_w, ed_b, (float4*)ep, eh4);

    for (int l = 0; l < NLAYERS; l++) {
        zero_dacc<<<1, 128, 0, stream>>>(dacc);
        node_gemm<<<(N + 63) / 64, 64, 0, stream>>>(h,
            Aw + l * 1024, Ab + l * 32,
            Bw + l * 1024, Bb + l * 32,
            Uw + l * 1024, Ub + l * 32,
            Vw + l * 1024, Vb + l * 32,
            Ah, Bh, Uh, Vh, N);
        agg_kernel<<<(N + 7) / 8, 256, 0, stream>>>(ep, srcp, offsets, counts,
            Ah, Bh, Vh, Uh, Cw + l * 1024, Cb + l * 32, hnew, dacc, N);
        stats_finalize<<<2, 64, 0, stream>>>(dacc, (double)N, (double)E,
            bn_h_g + l * 32, bn_h_b + l * 32, bn_e_g + l * 32, bn_e_b + l * 32, stats);
        apply4<<<gh4, 256, 0, stream>>>((const float4*)hnew, stats + 0, stats + 32, (float4*)h, nh4);
        apply_ep<<<4096, 256, 0, stream>>>(ep, srcp, dstp, Ah, Bh,
            Cw + l * 1024, Cb + l * 32, stats + 64, stats + 96, E);
    }

    predictor<<<gE, 256, 0, stream>>>(h, ep, srcp, dstp, perm, W1w, W1b, W2w, W2b,
                                      (float*)d_out, E);
}

// Round 6
// 1796.955 us; speedup vs baseline: 1.2009x; 1.2009x over previous
//
#include <hip/hip_runtime.h>
#include <hip/hip_bf16.h>

#define NLAYERS 4
#define AGG_BLOCKS 8192

// ---------------- small zero kernel ----------------
__global__ void zero_ints(int* __restrict__ p, int n)
{
    int i = blockIdx.x * 256 + threadIdx.x;
    if (i < n) p[i] = 0;
}

// ---------------- CSR build ----------------
__global__ void hist_kernel(const int* __restrict__ dsts, int* __restrict__ counts, int E)
{
    int i = blockIdx.x * 256 + threadIdx.x;
    if (i < E) atomicAdd(&counts[dsts[i]], 1);
}

__global__ __launch_bounds__(256) void scan1(const int* __restrict__ counts,
                                             int* __restrict__ offsets,
                                             int* __restrict__ blocksums, int N)
{
    __shared__ int sdata[256];
    int t = threadIdx.x;
    int bbase = blockIdx.x * 1024;
    int v[4]; int s = 0;
#pragma unroll
    for (int q = 0; q < 4; q++) {
        int idx = bbase + t * 4 + q;
        v[q] = (idx < N) ? counts[idx] : 0;
        s += v[q];
    }
    sdata[t] = s;
    __syncthreads();
    for (int off = 1; off < 256; off <<= 1) {
        int x = (t >= off) ? sdata[t - off] : 0;
        __syncthreads();
        sdata[t] += x;
        __syncthreads();
    }
    int excl = sdata[t] - s;
    int run = excl;
#pragma unroll
    for (int q = 0; q < 4; q++) {
        int idx = bbase + t * 4 + q;
        if (idx < N) offsets[idx] = run;
        run += v[q];
    }
    if (t == 255) blocksums[blockIdx.x] = sdata[255];
}

__global__ void scan2(int* __restrict__ blocksums, int nb)
{
    if (threadIdx.x == 0 && blockIdx.x == 0) {
        int run = 0;
        for (int b = 0; b < nb; b++) { int t = blocksums[b]; blocksums[b] = run; run += t; }
    }
}

__global__ void scan3(int* __restrict__ offsets, const int* __restrict__ blocksums,
                      int* __restrict__ cursor, int N)
{
    int i = blockIdx.x * 256 + threadIdx.x;
    if (i < N) {
        int v = offsets[i] + blocksums[i >> 10];
        offsets[i] = v;
        cursor[i] = v;
    }
}

__global__ void scatter_kernel(const int* __restrict__ srcs, const int* __restrict__ dsts,
                               int* __restrict__ cursor, int* __restrict__ perm,
                               int* __restrict__ srcp, int* __restrict__ dstp, int E)
{
    int i = blockIdx.x * 256 + threadIdx.x;
    if (i < E) {
        int d = dsts[i];
        int slot = atomicAdd(&cursor[d], 1);
        perm[slot] = i;
        srcp[slot] = srcs[i];
        dstp[slot] = d;
    }
}

// ---------------- init projections ----------------
__global__ void init_proj4(const float* __restrict__ in, const float* __restrict__ w,
                           const float* __restrict__ b, float4* __restrict__ out, size_t n4)
{
    size_t i = (size_t)blockIdx.x * 256 + threadIdx.x;
    if (i < n4) {
        int j4 = (int)(i & 7) * 4;
        float xv = in[i >> 3];
        float4 wv = *(const float4*)(w + j4);
        float4 bv = *(const float4*)(b + j4);
        out[i] = make_float4(fmaf(xv, wv.x, bv.x), fmaf(xv, wv.y, bv.y),
                             fmaf(xv, wv.z, bv.z), fmaf(xv, wv.w, bv.w));
    }
}

__global__ void init_ep4(const float* __restrict__ e_in, const int* __restrict__ perm,
                         const float* __restrict__ w, const float* __restrict__ b,
                         float4* __restrict__ out, size_t n4)
{
    size_t i = (size_t)blockIdx.x * 256 + threadIdx.x;
    if (i < n4) {
        int row = (int)(i >> 3);
        float xv = e_in[perm[row]];
        int j4 = (int)(i & 7) * 4;
        float4 wv = *(const float4*)(w + j4);
        float4 bv = *(const float4*)(b + j4);
        out[i] = make_float4(fmaf(xv, wv.x, bv.x), fmaf(xv, wv.y, bv.y),
                             fmaf(xv, wv.z, bv.z), fmaf(xv, wv.w, bv.w));
    }
}

// ---------------- node GEMMs: one node per thread, scalar-broadcast weights ----------------
__device__ __forceinline__ void mat32(const float* __restrict__ hrow,
                                      const float* __restrict__ W, const float* __restrict__ Wb,
                                      float* __restrict__ dst)
{
    float acc[32];
#pragma unroll
    for (int j = 0; j < 32; j++) acc[j] = Wb[j];
#pragma unroll 4
    for (int k = 0; k < 32; k++) {
        float hk = hrow[k];
#pragma unroll
        for (int j = 0; j < 32; j++) acc[j] = fmaf(hk, W[k * 32 + j], acc[j]);
    }
    float4* o = (float4*)dst;
#pragma unroll
    for (int q = 0; q < 8; q++) o[q] = make_float4(acc[4*q], acc[4*q+1], acc[4*q+2], acc[4*q+3]);
}

__global__ __launch_bounds__(64) void node_gemm(
    const float* __restrict__ h,
    const float* __restrict__ Aw, const float* __restrict__ Ab,
    const float* __restrict__ Bw, const float* __restrict__ Bb,
    const float* __restrict__ Uw, const float* __restrict__ Ub,
    const float* __restrict__ Vw, const float* __restrict__ Vb,
    float* __restrict__ Ahh, float* __restrict__ Bhh,
    float* __restrict__ Uhh, float* __restrict__ Vhh, int N)
{
    int nid = blockIdx.x * 64 + threadIdx.x;
    if (nid >= N) return;
    const float* hrow = h + (size_t)nid * 32;
    size_t o = (size_t)nid * 32;
    mat32(hrow, Aw, Ab, Ahh + o);
    mat32(hrow, Bw, Bb, Bhh + o);
    mat32(hrow, Uw, Ub, Uhh + o);
    mat32(hrow, Vw, Vb, Vhh + o);
}

// ---- aggregation v2: persistent block per node, 8-edge LDS tiles, no atomics at all ----
__global__ __launch_bounds__(256) void agg_kernel(
    const float* __restrict__ ep, const int* __restrict__ srcp,
    const int* __restrict__ offsets, const int* __restrict__ counts,
    const float* __restrict__ Ah, const float* __restrict__ Bh,
    const float* __restrict__ Vh, const float* __restrict__ Uh,
    const float* __restrict__ Cw, const float* __restrict__ Cb,
    float* __restrict__ hnew, float* __restrict__ partial, int N)
{
    __shared__ float le[256];
    __shared__ float red[512];
    __shared__ int lsrc[8];
    int tid = threadIdx.x, j = tid & 31, el = tid >> 5;
    float cw[32];
#pragma unroll
    for (int k = 0; k < 32; k++) cw[k] = Cw[k * 32 + j];
    float cb = Cb[j];
    float esum = 0.f, esq = 0.f, hsum = 0.f, hsq = 0.f;   // hsum/hsq live in tid<32 only
    for (int node = blockIdx.x; node < N; node += gridDim.x) {
        int start = offsets[node], len = counts[node];
        float ahd = Ah[(size_t)node * 32 + j];
        float accn = 0.f, accd = 0.f;
        for (int t8 = 0; t8 < len; t8 += 8) {
            __syncthreads();   // protect le/lsrc (and red) reuse
            int row = t8 + el;
            if (row < len) le[tid] = ep[((size_t)(start + t8)) * 32 + tid];
            if (tid < 8 && t8 + tid < len) lsrc[tid] = srcp[start + t8 + tid];
            __syncthreads();
            if (row < len) {
                const float4* lr = (const float4*)(le + el * 32);
                float4 e0 = lr[0], e1 = lr[1], e2 = lr[2], e3 = lr[3];
                float4 e4 = lr[4], e5 = lr[5], e6 = lr[6], e7 = lr[7];
                float a0 = cb, a1 = 0.f, a2 = 0.f, a3 = 0.f;
                a0 = fmaf(e0.x, cw[0],  a0); a0 = fmaf(e0.y, cw[1],  a0);
                a0 = fmaf(e0.z, cw[2],  a0); a0 = fmaf(e0.w, cw[3],  a0);
                a1 = fmaf(e1.x, cw[4],  a1); a1 = fmaf(e1.y, cw[5],  a1);
                a1 = fmaf(e1.z, cw[6],  a1); a1 = fmaf(e1.w, cw[7],  a1);
                a2 = fmaf(e2.x, cw[8],  a2); a2 = fmaf(e2.y, cw[9],  a2);
                a2 = fmaf(e2.z, cw[10], a2); a2 = fmaf(e2.w, cw[11], a2);
                a3 = fmaf(e3.x, cw[12], a3); a3 = fmaf(e3.y, cw[13], a3);
                a3 = fmaf(e3.z, cw[14], a3); a3 = fmaf(e3.w, cw[15], a3);
                a0 = fmaf(e4.x, cw[16], a0); a0 = fmaf(e4.y, cw[17], a0);
                a0 = fmaf(e4.z, cw[18], a0); a0 = fmaf(e4.w, cw[19], a0);
                a1 = fmaf(e5.x, cw[20], a1); a1 = fmaf(e5.y, cw[21], a1);
                a1 = fmaf(e5.z, cw[22], a1); a1 = fmaf(e5.w, cw[23], a1);
                a2 = fmaf(e6.x, cw[24], a2); a2 = fmaf(e6.y, cw[25], a2);
                a2 = fmaf(e6.z, cw[26], a2); a2 = fmaf(e6.w, cw[27], a2);
                a3 = fmaf(e7.x, cw[28], a3); a3 = fmaf(e7.y, cw[29], a3);
                a3 = fmaf(e7.z, cw[30], a3); a3 = fmaf(e7.w, cw[31], a3);
                int s = lsrc[el];
                float en = (a0 + a1) + (a2 + a3) + ahd + Bh[(size_t)s * 32 + j];
                float sg = 1.f / (1.f + __expf(-en));
                accn = fmaf(sg, Vh[(size_t)s * 32 + j], accn);
                accd += sg;
                esum += en; esq += en * en;
            }
        }
        __syncthreads();
        red[tid] = accn; red[256 + tid] = accd;
        __syncthreads();
        if (tid < 32) {
            float nsum = 0.f, dsum = 0.f;
#pragma unroll
            for (int r = 0; r < 8; r++) { nsum += red[r * 32 + tid]; dsum += red[256 + r * 32 + tid]; }
            float hv = Uh[(size_t)node * 32 + tid] + nsum / (dsum + 1e-6f);
            hnew[(size_t)node * 32 + tid] = hv;
            hsum += hv; hsq += hv * hv;
        }
    }
    __syncthreads();
    red[tid] = esum; red[256 + tid] = esq;
    __syncthreads();
    if (tid < 32) {
        float es = 0.f, eq = 0.f;
#pragma unroll
        for (int r = 0; r < 8; r++) { es += red[r * 32 + tid]; eq += red[256 + r * 32 + tid]; }
        float* p = partial + (size_t)blockIdx.x * 128;
        p[tid] = hsum; p[32 + tid] = hsq; p[64 + tid] = es; p[96 + tid] = eq;
    }
}

// ---------------- finalize BN stats: 64 blocks, one per (side, feature) ----------------
__global__ __launch_bounds__(256) void stats_finalize(
    const float* __restrict__ partial, int nb, double cntH, double cntE,
    const float* __restrict__ gH, const float* __restrict__ bH,
    const float* __restrict__ gE, const float* __restrict__ bE,
    float* __restrict__ stats)
{
    int side = blockIdx.x >> 5, j = blockIdx.x & 31;
    int c1 = side * 64 + j, c2 = c1 + 32;
    __shared__ double rs[256], rq[256];
    double s = 0.0, q = 0.0;
    for (int r = threadIdx.x; r < nb; r += 256) {
        s += (double)partial[(size_t)r * 128 + c1];
        q += (double)partial[(size_t)r * 128 + c2];
    }
    rs[threadIdx.x] = s; rq[threadIdx.x] = q;
    __syncthreads();
    for (int off = 128; off; off >>= 1) {
        if (threadIdx.x < off) { rs[threadIdx.x] += rs[threadIdx.x + off]; rq[threadIdx.x] += rq[threadIdx.x + off]; }
        __syncthreads();
    }
    if (threadIdx.x == 0) {
        double cnt = side ? cntE : cntH;
        const float* g = side ? gE : gH;
        const float* b = side ? bE : bH;
        double mean = rs[0] / cnt;
        double var = rq[0] / cnt - mean * mean;
        float scale = g[j] * (float)(1.0 / sqrt(var + 1e-5));
        stats[side * 64 + j] = scale;
        stats[side * 64 + 32 + j] = b[j] - (float)mean * scale;
    }
}

// ---------------- apply (h, float4): acc += relu(pre*scale + shift) ----------------
__global__ void apply4(const float4* __restrict__ pre, const float* __restrict__ scale,
                       const float* __restrict__ shift, float4* __restrict__ acc, size_t n4)
{
    size_t i = (size_t)blockIdx.x * 256 + threadIdx.x;
    if (i < n4) {
        int j4 = (int)(i & 7) * 4;
        float4 sc = *(const float4*)(scale + j4);
        float4 sh = *(const float4*)(shift + j4);
        float4 p = pre[i], a = acc[i];
        a.x += fmaxf(fmaf(p.x, sc.x, sh.x), 0.f);
        a.y += fmaxf(fmaf(p.y, sc.y, sh.y), 0.f);
        a.z += fmaxf(fmaf(p.z, sc.z, sh.z), 0.f);
        a.w += fmaxf(fmaf(p.w, sc.w, sh.w), 0.f);
        acc[i] = a;
    }
}

// ---- edge apply: recompute e_new (same FMA order as agg), BN+ReLU+residual in place ----
__global__ __launch_bounds__(256) void apply_ep(
    float* __restrict__ ep, const int* __restrict__ srcp, const int* __restrict__ dstp,
    const float* __restrict__ Ah, const float* __restrict__ Bh,
    const float* __restrict__ Cw, const float* __restrict__ Cb,
    const float* __restrict__ sc, const float* __restrict__ sh, int E)
{
    __shared__ float le[256];
    __shared__ int lsrc[8], ldst[8];
    int tid = threadIdx.x, j = tid & 31, el = tid >> 5;
    float cw[32];
#pragma unroll
    for (int k = 0; k < 32; k++) cw[k] = Cw[k * 32 + j];
    float cb = Cb[j];
    float scale = sc[j], shift = sh[j];
    int ng = (E + 7) >> 3;
    for (int g = blockIdx.x; g < ng; g += gridDim.x) {
        int base = g << 3;
        __syncthreads();
        if (tid < 64) {
            int row = base + (tid >> 3);
            if (row < E) ((float4*)le)[tid] = ((const float4*)(ep + (size_t)base * 32))[tid];
        }
        if (tid < 8) {
            int ee = base + tid;
            if (ee < E) { lsrc[tid] = srcp[ee]; ldst[tid] = dstp[ee]; }
        }
        __syncthreads();
        int eid = base + el;
        if (eid < E) {
            const float4* lr = (const float4*)(le + el * 32);
            float4 e0 = lr[0], e1 = lr[1], e2 = lr[2], e3 = lr[3];
            float4 e4 = lr[4], e5 = lr[5], e6 = lr[6], e7 = lr[7];
            float a0 = cb, a1 = 0.f, a2 = 0.f, a3 = 0.f;
            a0 = fmaf(e0.x, cw[0],  a0); a0 = fmaf(e0.y, cw[1],  a0);
            a0 = fmaf(e0.z, cw[2],  a0); a0 = fmaf(e0.w, cw[3],  a0);
            a1 = fmaf(e1.x, cw[4],  a1); a1 = fmaf(e1.y, cw[5],  a1);
            a1 = fmaf(e1.z, cw[6],  a1); a1 = fmaf(e1.w, cw[7],  a1);
            a2 = fmaf(e2.x, cw[8],  a2); a2 = fmaf(e2.y, cw[9],  a2);
            a2 = fmaf(e2.z, cw[10], a2); a2 = fmaf(e2.w, cw[11], a2);
            a3 = fmaf(e3.x, cw[12], a3); a3 = fmaf(e3.y, cw[13], a3);
            a3 = fmaf(e3.z, cw[14], a3); a3 = fmaf(e3.w, cw[15], a3);
            a0 = fmaf(e4.x, cw[16], a0); a0 = fmaf(e4.y, cw[17], a0);
            a0 = fmaf(e4.z, cw[18], a0); a0 = fmaf(e4.w, cw[19], a0);
            a1 = fmaf(e5.x, cw[20], a1); a1 = fmaf(e5.y, cw[21], a1);
            a1 = fmaf(e5.z, cw[22], a1); a1 = fmaf(e5.w, cw[23], a1);
            a2 = fmaf(e6.x, cw[24], a2); a2 = fmaf(e6.y, cw[25], a2);
            a2 = fmaf(e6.z, cw[26], a2); a2 = fmaf(e6.w, cw[27], a2);
            a3 = fmaf(e7.x, cw[28], a3); a3 = fmaf(e7.y, cw[29], a3);
            a3 = fmaf(e7.z, cw[30], a3); a3 = fmaf(e7.w, cw[31], a3);
            int s = lsrc[el], d = ldst[el];
            float en = (a0 + a1) + (a2 + a3) + Ah[(size_t)d * 32 + j] + Bh[(size_t)s * 32 + j];
            float v = fmaf(en, scale, shift);
            ep[(size_t)eid * 32 + j] = le[el * 32 + j] + fmaxf(v, 0.f);
        }
    }
}

// ---------------- predictor: one permuted edge per thread, scatter output ----------------
__global__ __launch_bounds__(256) void predictor(
    const float* __restrict__ h, const float* __restrict__ ep,
    const int* __restrict__ srcp, const int* __restrict__ dstp, const int* __restrict__ perm,
    const float* __restrict__ W1, const float* __restrict__ b1,
    const float* __restrict__ W2, const float* __restrict__ b2v,
    float* __restrict__ out, int E)
{
    int pos = blockIdx.x * 256 + threadIdx.x;
    if (pos >= E) return;
    int s = srcp[pos], d = dstp[pos];
    float acc[32];
#pragma unroll
    for (int j = 0; j < 32; j++) acc[j] = b1[j];
    const float* zs = h + (size_t)s * 32;
    const float* zd = h + (size_t)d * 32;
    const float* ze = ep + (size_t)pos * 32;
#pragma unroll 4
    for (int k = 0; k < 32; k++) {
        float zk = zs[k];
#pragma unroll
        for (int j = 0; j < 32; j++) acc[j] = fmaf(zk, W1[k * 32 + j], acc[j]);
    }
#pragma unroll 4
    for (int k = 0; k < 32; k++) {
        float zk = zd[k];
#pragma unroll
        for (int j = 0; j < 32; j++) acc[j] = fmaf(zk, W1[(32 + k) * 32 + j], acc[j]);
    }
#pragma unroll 4
    for (int k = 0; k < 32; k++) {
        float zk = ze[k];
#pragma unroll
        for (int j = 0; j < 32; j++) acc[j] = fmaf(zk, W1[(64 + k) * 32 + j], acc[j]);
    }
    float t = b2v[0];
#pragma unroll
    for (int j = 0; j < 32; j++) t += fmaxf(acc[j], 0.f) * W2[j];
    out[perm[pos]] = t;
}

extern "C" void kernel_launch(void* const* d_in, const int* in_sizes, int n_in,
                              void* d_out, int out_size, void* d_ws, size_t ws_size,
                              hipStream_t stream)
{
    const int N = in_sizes[0];
    const int E = in_sizes[1];

    const float* x    = (const float*)d_in[0];
    const float* e_in = (const float*)d_in[1];
    const int*   eidx = (const int*)d_in[2];
    const float* pe_w = (const float*)d_in[3];
    const float* pe_b = (const float*)d_in[4];
    const float* ed_w = (const float*)d_in[5];
    const float* ed_b = (const float*)d_in[6];
    const float* Aw = (const float*)d_in[7];
    const float* Ab = (const float*)d_in[8];
    const float* Bw = (const float*)d_in[9];
    const float* Bb = (const float*)d_in[10];
    const float* Cw = (const float*)d_in[11];
    const float* Cb = (const float*)d_in[12];
    const float* Uw = (const float*)d_in[13];
    const float* Ub = (const float*)d_in[14];
    const float* Vw = (const float*)d_in[15];
    const float* Vb = (const float*)d_in[16];
    const float* bn_h_g = (const float*)d_in[17];
    const float* bn_h_b = (const float*)d_in[18];
    const float* bn_e_g = (const float*)d_in[19];
    const float* bn_e_b = (const float*)d_in[20];
    const float* W1w = (const float*)d_in[21];
    const float* W1b = (const float*)d_in[22];
    const float* W2w = (const float*)d_in[23];
    const float* W2b = (const float*)d_in[24];

    const int* srcs = eidx;
    const int* dsts = eidx + E;

    size_t nh = (size_t)N * 32;
    size_t eh = (size_t)E * 32;

    float* ws = (float*)d_ws;
    float* stats = ws;                       // 128
    float* partial = stats + 128;            // AGG_BLOCKS*128
    float* h    = partial + (size_t)AGG_BLOCKS * 128;
    float* Ah   = h + nh;
    float* Bh   = Ah + nh;
    float* Uh   = Bh + nh;
    float* Vh   = Uh + nh;
    float* hnew = Vh + nh;
    float* ep   = hnew + nh;
    int* counts    = (int*)(ep + eh);
    int* offsets   = counts + N;
    int* cursor    = offsets + N;
    int* blocksums = cursor + N;   // 128
    int* perm      = blocksums + 128;
    int* srcp      = perm + E;
    int* dstp      = srcp + E;

    size_t nh4 = nh / 4, eh4 = eh / 4;
    int gh4 = (int)((nh4 + 255) / 256);
    int ge4 = (int)((eh4 + 255) / 256);
    int gN = (N + 255) / 256;
    int gE = (E + 255) / 256;
    int nb = (N + 1023) / 1024;

    // ---- CSR build (dst-sorted edge permutation) ----
    zero_ints<<<gN, 256, 0, stream>>>(counts, N);
    hist_kernel<<<gE, 256, 0, stream>>>(dsts, counts, E);
    scan1<<<nb, 256, 0, stream>>>(counts, offsets, blocksums, N);
    scan2<<<1, 64, 0, stream>>>(blocksums, nb);
    scan3<<<gN, 256, 0, stream>>>(offsets, blocksums, cursor, N);
    scatter_kernel<<<gE, 256, 0, stream>>>(srcs, dsts, cursor, perm, srcp, dstp, E);

    // ---- input projections ----
    init_proj4<<<gh4, 256, 0, stream>>>(x, pe_w, pe_b, (float4*)h, nh4);
    init_ep4<<<ge4, 256, 0, stream>>>(e_in, perm, ed_w, ed_b, (float4*)ep, eh4);

    for (int l = 0; l < NLAYERS; l++) {
        node_gemm<<<(N + 63) / 64, 64, 0, stream>>>(h,
            Aw + l * 1024, Ab + l * 32,
            Bw + l * 1024, Bb + l * 32,
            Uw + l * 1024, Ub + l * 32,
            Vw + l * 1024, Vb + l * 32,
            Ah, Bh, Uh, Vh, N);
        agg_kernel<<<AGG_BLOCKS, 256, 0, stream>>>(ep, srcp, offsets, counts,
            Ah, Bh, Vh, Uh, Cw + l * 1024, Cb + l * 32, hnew, partial, N);
        stats_finalize<<<64, 256, 0, stream>>>(partial, AGG_BLOCKS, (double)N, (double)E,
            bn_h_g + l * 32, bn_h_b + l * 32, bn_e_g + l * 32, bn_e_b + l * 32, stats);
        apply4<<<gh4, 256, 0, stream>>>((const float4*)hnew, stats + 0, stats + 32, (float4*)h, nh4);
        apply_ep<<<4096, 256, 0, stream>>>(ep, srcp, dstp, Ah, Bh,
            Cw + l * 1024, Cb + l * 32, stats + 64, stats + 96, E);
    }

    predictor<<<gE, 256, 0, stream>>>(h, ep, srcp, dstp, perm, W1w, W1b, W2w, W2b,
                                      (float*)d_out, E);
}

// Round 7
// 1690.587 us; speedup vs baseline: 1.2765x; 1.0629x over previous
//
#include <hip/hip_runtime.h>
#include <hip/hip_bf16.h>

#define NLAYERS 4

// ---------------- small zero kernel ----------------
__global__ void zero_ints(int* __restrict__ p, int n)
{
    int i = blockIdx.x * 256 + threadIdx.x;
    if (i < n) p[i] = 0;
}

// ---------------- CSR build ----------------
__global__ void hist_kernel(const int* __restrict__ dsts, int* __restrict__ counts, int E)
{
    int i = blockIdx.x * 256 + threadIdx.x;
    if (i < E) atomicAdd(&counts[dsts[i]], 1);
}

__global__ __launch_bounds__(256) void scan1(const int* __restrict__ counts,
                                             int* __restrict__ offsets,
                                             int* __restrict__ blocksums, int N)
{
    __shared__ int sdata[256];
    int t = threadIdx.x;
    int bbase = blockIdx.x * 1024;
    int v[4]; int s = 0;
#pragma unroll
    for (int q = 0; q < 4; q++) {
        int idx = bbase + t * 4 + q;
        v[q] = (idx < N) ? counts[idx] : 0;
        s += v[q];
    }
    sdata[t] = s;
    __syncthreads();
    for (int off = 1; off < 256; off <<= 1) {
        int x = (t >= off) ? sdata[t - off] : 0;
        __syncthreads();
        sdata[t] += x;
        __syncthreads();
    }
    int excl = sdata[t] - s;
    int run = excl;
#pragma unroll
    for (int q = 0; q < 4; q++) {
        int idx = bbase + t * 4 + q;
        if (idx < N) offsets[idx] = run;
        run += v[q];
    }
    if (t == 255) blocksums[blockIdx.x] = sdata[255];
}

__global__ void scan2(int* __restrict__ blocksums, int nb)
{
    if (threadIdx.x == 0 && blockIdx.x == 0) {
        int run = 0;
        for (int b = 0; b < nb; b++) { int t = blocksums[b]; blocksums[b] = run; run += t; }
    }
}

__global__ void scan3(int* __restrict__ offsets, const int* __restrict__ blocksums,
                      int* __restrict__ cursor, int N)
{
    int i = blockIdx.x * 256 + threadIdx.x;
    if (i < N) {
        int v = offsets[i] + blocksums[i >> 10];
        offsets[i] = v;
        cursor[i] = v;
    }
}

__global__ void scatter_kernel(const int* __restrict__ srcs, const int* __restrict__ dsts,
                               int* __restrict__ cursor, int* __restrict__ perm,
                               int* __restrict__ srcp, int* __restrict__ dstp, int E)
{
    int i = blockIdx.x * 256 + threadIdx.x;
    if (i < E) {
        int d = dsts[i];
        int slot = atomicAdd(&cursor[d], 1);
        perm[slot] = i;
        srcp[slot] = srcs[i];
        dstp[slot] = d;
    }
}

// ---------------- init projections ----------------
__global__ void init_proj4(const float* __restrict__ in, const float* __restrict__ w,
                           const float* __restrict__ b, float4* __restrict__ out, size_t n4)
{
    size_t i = (size_t)blockIdx.x * 256 + threadIdx.x;
    if (i < n4) {
        int j4 = (int)(i & 7) * 4;
        float xv = in[i >> 3];
        float4 wv = *(const float4*)(w + j4);
        float4 bv = *(const float4*)(b + j4);
        out[i] = make_float4(fmaf(xv, wv.x, bv.x), fmaf(xv, wv.y, bv.y),
                             fmaf(xv, wv.z, bv.z), fmaf(xv, wv.w, bv.w));
    }
}

__global__ void init_ep4(const float* __restrict__ e_in, const int* __restrict__ perm,
                         const float* __restrict__ w, const float* __restrict__ b,
                         float4* __restrict__ out, size_t n4)
{
    size_t i = (size_t)blockIdx.x * 256 + threadIdx.x;
    if (i < n4) {
        int row = (int)(i >> 3);
        float xv = e_in[perm[row]];
        int j4 = (int)(i & 7) * 4;
        float4 wv = *(const float4*)(w + j4);
        float4 bv = *(const float4*)(b + j4);
        out[i] = make_float4(fmaf(xv, wv.x, bv.x), fmaf(xv, wv.y, bv.y),
                             fmaf(xv, wv.z, bv.z), fmaf(xv, wv.w, bv.w));
    }
}

// ---------------- node GEMMs: one node per thread, scalar-broadcast weights ----------------
__device__ __forceinline__ void mat32(const float* __restrict__ hrow,
                                      const float* __restrict__ W, const float* __restrict__ Wb,
                                      float* __restrict__ dst)
{
    float acc[32];
#pragma unroll
    for (int j = 0; j < 32; j++) acc[j] = Wb[j];
#pragma unroll 4
    for (int k = 0; k < 32; k++) {
        float hk = hrow[k];
#pragma unroll
        for (int j = 0; j < 32; j++) acc[j] = fmaf(hk, W[k * 32 + j], acc[j]);
    }
    float4* o = (float4*)dst;
#pragma unroll
    for (int q = 0; q < 8; q++) o[q] = make_float4(acc[4*q], acc[4*q+1], acc[4*q+2], acc[4*q+3]);
}

__global__ __launch_bounds__(64) void node_gemm(
    const float* __restrict__ h,
    const float* __restrict__ Aw, const float* __restrict__ Ab,
    const float* __restrict__ Bw, const float* __restrict__ Bb,
    const float* __restrict__ Uw, const float* __restrict__ Ub,
    const float* __restrict__ Vw, const float* __restrict__ Vb,
    float* __restrict__ Ahh, float* __restrict__ Bhh,
    float* __restrict__ Uhh, float* __restrict__ Vhh, int N)
{
    int nid = blockIdx.x * 64 + threadIdx.x;
    if (nid >= N) return;
    const float* hrow = h + (size_t)nid * 32;
    size_t o = (size_t)nid * 32;
    mat32(hrow, Aw, Ab, Ahh + o);
    mat32(hrow, Bw, Bb, Bhh + o);
    mat32(hrow, Uw, Ub, Uhh + o);
    mat32(hrow, Vw, Vb, Vhh + o);
}

// ---- aggregation v3: independent 32-lane group per node, shfl-broadcast Ce GEMM ----
// lane j loads only its own column; num/den are pure per-lane registers; no barriers
// in the hot loop; optionally stores pre-BN en to enew.
template <bool STORE>
__global__ __launch_bounds__(256) void agg_kernel(
    const float* __restrict__ ep, const int* __restrict__ srcp,
    const int* __restrict__ offsets, const int* __restrict__ counts,
    const float* __restrict__ Ah, const float* __restrict__ Bh,
    const float* __restrict__ Vh, const float* __restrict__ Uh,
    const float* __restrict__ Cw, const float* __restrict__ Cb,
    float* __restrict__ hnew, float* __restrict__ enew,
    float* __restrict__ partial, int N)
{
    __shared__ float red[512];
    int tid = threadIdx.x, j = tid & 31, grp = tid >> 5;
    float cw[32];
#pragma unroll
    for (int k = 0; k < 32; k++) cw[k] = Cw[k * 32 + j];
    float esum = 0.f, esq = 0.f, hsum = 0.f, hsq = 0.f;
    int node = blockIdx.x * 8 + grp;
    if (node < N) {
        int start = offsets[node], len = counts[node];
        float ahd = Ah[(size_t)node * 32 + j] + Cb[j];
        float num = 0.f, den = 0.f;
        for (int q = 0; q < len; q++) {
            int pos = start + q;
            int s = srcp[pos];
            float ev = ep[(size_t)pos * 32 + j];
            float bh = Bh[(size_t)s * 32 + j];
            float vh = Vh[(size_t)s * 32 + j];
            float en = ahd + bh;
#pragma unroll
            for (int k = 0; k < 32; k++)
                en = fmaf(__shfl(ev, k, 32), cw[k], en);
            float sg = 1.f / (1.f + __expf(-en));
            num = fmaf(sg, vh, num);
            den += sg;
            esum += en; esq += en * en;
            if (STORE) enew[(size_t)pos * 32 + j] = en;
        }
        float hv = Uh[(size_t)node * 32 + j] + num / (den + 1e-6f);
        hnew[(size_t)node * 32 + j] = hv;
        hsum = hv; hsq = hv * hv;
    }
    // one-time block reduction of BN partials
    red[tid] = hsum; red[256 + tid] = hsq;
    __syncthreads();
    float hS = 0.f, hQ = 0.f;
    if (tid < 32) {
#pragma unroll
        for (int r = 0; r < 8; r++) { hS += red[r * 32 + tid]; hQ += red[256 + r * 32 + tid]; }
    }
    __syncthreads();
    red[tid] = esum; red[256 + tid] = esq;
    __syncthreads();
    if (tid < 32) {
        float eS = 0.f, eQ = 0.f;
#pragma unroll
        for (int r = 0; r < 8; r++) { eS += red[r * 32 + tid]; eQ += red[256 + r * 32 + tid]; }
        float* p = partial + (size_t)blockIdx.x * 128;
        p[tid] = hS; p[32 + tid] = hQ; p[64 + tid] = eS; p[96 + tid] = eQ;
    }
}

// ---------------- finalize BN stats: 64 blocks, one per (side, feature) ----------------
__global__ __launch_bounds__(256) void stats_finalize(
    const float* __restrict__ partial, int nb, double cntH, double cntE,
    const float* __restrict__ gH, const float* __restrict__ bH,
    const float* __restrict__ gE, const float* __restrict__ bE,
    float* __restrict__ stats)
{
    int side = blockIdx.x >> 5, j = blockIdx.x & 31;
    int c1 = side * 64 + j, c2 = c1 + 32;
    __shared__ double rs[256], rq[256];
    double s = 0.0, q = 0.0;
    for (int r = threadIdx.x; r < nb; r += 256) {
        s += (double)partial[(size_t)r * 128 + c1];
        q += (double)partial[(size_t)r * 128 + c2];
    }
    rs[threadIdx.x] = s; rq[threadIdx.x] = q;
    __syncthreads();
    for (int off = 128; off; off >>= 1) {
        if (threadIdx.x < off) { rs[threadIdx.x] += rs[threadIdx.x + off]; rq[threadIdx.x] += rq[threadIdx.x + off]; }
        __syncthreads();
    }
    if (threadIdx.x == 0) {
        double cnt = side ? cntE : cntH;
        const float* g = side ? gE : gH;
        const float* b = side ? bE : bH;
        double mean = rs[0] / cnt;
        double var = rq[0] / cnt - mean * mean;
        float scale = g[j] * (float)(1.0 / sqrt(var + 1e-5));
        stats[side * 64 + j] = scale;
        stats[side * 64 + 32 + j] = b[j] - (float)mean * scale;
    }
}

// ---------------- apply (float4): acc += relu(pre*scale + shift) ----------------
__global__ void apply4(const float4* __restrict__ pre, const float* __restrict__ scale,
                       const float* __restrict__ shift, float4* __restrict__ acc, size_t n4)
{
    size_t i = (size_t)blockIdx.x * 256 + threadIdx.x;
    if (i < n4) {
        int j4 = (int)(i & 7) * 4;
        float4 sc = *(const float4*)(scale + j4);
        float4 sh = *(const float4*)(shift + j4);
        float4 p = pre[i], a = acc[i];
        a.x += fmaxf(fmaf(p.x, sc.x, sh.x), 0.f);
        a.y += fmaxf(fmaf(p.y, sc.y, sh.y), 0.f);
        a.z += fmaxf(fmaf(p.z, sc.z, sh.z), 0.f);
        a.w += fmaxf(fmaf(p.w, sc.w, sh.w), 0.f);
        acc[i] = a;
    }
}

// ---- fallback edge apply (recompute path, used only if ws too small for enew) ----
__global__ __launch_bounds__(256) void apply_ep(
    float* __restrict__ ep, const int* __restrict__ srcp, const int* __restrict__ dstp,
    const float* __restrict__ Ah, const float* __restrict__ Bh,
    const float* __restrict__ Cw, const float* __restrict__ Cb,
    const float* __restrict__ sc, const float* __restrict__ sh, int E)
{
    __shared__ float le[256];
    __shared__ int lsrc[8], ldst[8];
    int tid = threadIdx.x, j = tid & 31, el = tid >> 5;
    float cw[32];
#pragma unroll
    for (int k = 0; k < 32; k++) cw[k] = Cw[k * 32 + j];
    float cb = Cb[j];
    float scale = sc[j], shift = sh[j];
    int ng = (E + 7) >> 3;
    for (int g = blockIdx.x; g < ng; g += gridDim.x) {
        int base = g << 3;
        __syncthreads();
        if (tid < 64) {
            int row = base + (tid >> 3);
            if (row < E) ((float4*)le)[tid] = ((const float4*)(ep + (size_t)base * 32))[tid];
        }
        if (tid < 8) {
            int ee = base + tid;
            if (ee < E) { lsrc[tid] = srcp[ee]; ldst[tid] = dstp[ee]; }
        }
        __syncthreads();
        int eid = base + el;
        if (eid < E) {
            const float4* lr = (const float4*)(le + el * 32);
            float acc = cb;
#pragma unroll
            for (int q = 0; q < 8; q++) {
                float4 ev = lr[q];
                acc = fmaf(ev.x, cw[4*q],   acc);
                acc = fmaf(ev.y, cw[4*q+1], acc);
                acc = fmaf(ev.z, cw[4*q+2], acc);
                acc = fmaf(ev.w, cw[4*q+3], acc);
            }
            int s = lsrc[el], d = ldst[el];
            float en = acc + Ah[(size_t)d * 32 + j] + Bh[(size_t)s * 32 + j];
            float v = fmaf(en, scale, shift);
            ep[(size_t)eid * 32 + j] = le[el * 32 + j] + fmaxf(v, 0.f);
        }
    }
}

// ---------------- predictor: one permuted edge per thread, scatter output ----------------
__global__ __launch_bounds__(256) void predictor(
    const float* __restrict__ h, const float* __restrict__ ep,
    const int* __restrict__ srcp, const int* __restrict__ dstp, const int* __restrict__ perm,
    const float* __restrict__ W1, const float* __restrict__ b1,
    const float* __restrict__ W2, const float* __restrict__ b2v,
    float* __restrict__ out, int E)
{
    int pos = blockIdx.x * 256 + threadIdx.x;
    if (pos >= E) return;
    int s = srcp[pos], d = dstp[pos];
    float acc[32];
#pragma unroll
    for (int j = 0; j < 32; j++) acc[j] = b1[j];
    const float* zs = h + (size_t)s * 32;
    const float* zd = h + (size_t)d * 32;
    const float* ze = ep + (size_t)pos * 32;
#pragma unroll 4
    for (int k = 0; k < 32; k++) {
        float zk = zs[k];
#pragma unroll
        for (int j = 0; j < 32; j++) acc[j] = fmaf(zk, W1[k * 32 + j], acc[j]);
    }
#pragma unroll 4
    for (int k = 0; k < 32; k++) {
        float zk = zd[k];
#pragma unroll
        for (int j = 0; j < 32; j++) acc[j] = fmaf(zk, W1[(32 + k) * 32 + j], acc[j]);
    }
#pragma unroll 4
    for (int k = 0; k < 32; k++) {
        float zk = ze[k];
#pragma unroll
        for (int j = 0; j < 32; j++) acc[j] = fmaf(zk, W1[(64 + k) * 32 + j], acc[j]);
    }
    float t = b2v[0];
#pragma unroll
    for (int j = 0; j < 32; j++) t += fmaxf(acc[j], 0.f) * W2[j];
    out[perm[pos]] = t;
}

extern "C" void kernel_launch(void* const* d_in, const int* in_sizes, int n_in,
                              void* d_out, int out_size, void* d_ws, size_t ws_size,
                              hipStream_t stream)
{
    const int N = in_sizes[0];
    const int E = in_sizes[1];

    const float* x    = (const float*)d_in[0];
    const float* e_in = (const float*)d_in[1];
    const int*   eidx = (const int*)d_in[2];
    const float* pe_w = (const float*)d_in[3];
    const float* pe_b = (const float*)d_in[4];
    const float* ed_w = (const float*)d_in[5];
    const float* ed_b = (const float*)d_in[6];
    const float* Aw = (const float*)d_in[7];
    const float* Ab = (const float*)d_in[8];
    const float* Bw = (const float*)d_in[9];
    const float* Bb = (const float*)d_in[10];
    const float* Cw = (const float*)d_in[11];
    const float* Cb = (const float*)d_in[12];
    const float* Uw = (const float*)d_in[13];
    const float* Ub = (const float*)d_in[14];
    const float* Vw = (const float*)d_in[15];
    const float* Vb = (const float*)d_in[16];
    const float* bn_h_g = (const float*)d_in[17];
    const float* bn_h_b = (const float*)d_in[18];
    const float* bn_e_g = (const float*)d_in[19];
    const float* bn_e_b = (const float*)d_in[20];
    const float* W1w = (const float*)d_in[21];
    const float* W1b = (const float*)d_in[22];
    const float* W2w = (const float*)d_in[23];
    const float* W2b = (const float*)d_in[24];

    const int* srcs = eidx;
    const int* dsts = eidx + E;

    size_t nh = (size_t)N * 32;
    size_t eh = (size_t)E * 32;
    int nAgg = (N + 7) / 8;            // agg blocks == partial rows

    float* ws = (float*)d_ws;
    float* stats   = ws;                              // 128
    float* partial = stats + 128;                     // nAgg*128
    float* h    = partial + (size_t)nAgg * 128;
    float* Ah   = h + nh;
    float* Bh   = Ah + nh;
    float* Uh   = Bh + nh;
    float* Vh   = Uh + nh;
    float* hnew = Vh + nh;
    float* ep   = hnew + nh;
    int* counts    = (int*)(ep + eh);
    int* offsets   = counts + N;
    int* cursor    = offsets + N;
    int* blocksums = cursor + N;   // 128
    int* perm      = blocksums + 128;
    int* srcp      = perm + E;
    int* dstp      = srcp + E;
    float* enew    = (float*)(dstp + E);              // optional, eh floats

    size_t base_floats = (size_t)(dstp + E - (int*)ws);
    bool storeE = ((base_floats + eh) * 4 <= ws_size);

    size_t nh4 = nh / 4, eh4 = eh / 4;
    int gh4 = (int)((nh4 + 255) / 256);
    int ge4 = (int)((eh4 + 255) / 256);
    int gN = (N + 255) / 256;
    int gE = (E + 255) / 256;
    int nb = (N + 1023) / 1024;

    // ---- CSR build (dst-sorted edge permutation) ----
    zero_ints<<<gN, 256, 0, stream>>>(counts, N);
    hist_kernel<<<gE, 256, 0, stream>>>(dsts, counts, E);
    scan1<<<nb, 256, 0, stream>>>(counts, offsets, blocksums, N);
    scan2<<<1, 64, 0, stream>>>(blocksums, nb);
    scan3<<<gN, 256, 0, stream>>>(offsets, blocksums, cursor, N);
    scatter_kernel<<<gE, 256, 0, stream>>>(srcs, dsts, cursor, perm, srcp, dstp, E);

    // ---- input projections ----
    init_proj4<<<gh4, 256, 0, stream>>>(x, pe_w, pe_b, (float4*)h, nh4);
    init_ep4<<<ge4, 256, 0, stream>>>(e_in, perm, ed_w, ed_b, (float4*)ep, eh4);

    for (int l = 0; l < NLAYERS; l++) {
        node_gemm<<<(N + 63) / 64, 64, 0, stream>>>(h,
            Aw + l * 1024, Ab + l * 32,
            Bw + l * 1024, Bb + l * 32,
            Uw + l * 1024, Ub + l * 32,
            Vw + l * 1024, Vb + l * 32,
            Ah, Bh, Uh, Vh, N);
        if (storeE)
            agg_kernel<true><<<nAgg, 256, 0, stream>>>(ep, srcp, offsets, counts,
                Ah, Bh, Vh, Uh, Cw + l * 1024, Cb + l * 32, hnew, enew, partial, N);
        else
            agg_kernel<false><<<nAgg, 256, 0, stream>>>(ep, srcp, offsets, counts,
                Ah, Bh, Vh, Uh, Cw + l * 1024, Cb + l * 32, hnew, enew, partial, N);
        stats_finalize<<<64, 256, 0, stream>>>(partial, nAgg, (double)N, (double)E,
            bn_h_g + l * 32, bn_h_b + l * 32, bn_e_g + l * 32, bn_e_b + l * 32, stats);
        apply4<<<gh4, 256, 0, stream>>>((const float4*)hnew, stats + 0, stats + 32, (float4*)h, nh4);
        if (storeE)
            apply4<<<ge4, 256, 0, stream>>>((const float4*)enew, stats + 64, stats + 96, (float4*)ep, eh4);
        else
            apply_ep<<<4096, 256, 0, stream>>>(ep, srcp, dstp, Ah, Bh,
                Cw + l * 1024, Cb + l * 32, stats + 64, stats + 96, E);
    }

    predictor<<<gE, 256, 0, stream>>>(h, ep, srcp, dstp, perm, W1w, W1b, W2w, W2b,
                                      (float*)d_out, E);
}

// Round 8
// 1477.624 us; speedup vs baseline: 1.4604x; 1.1441x over previous
//
#include <hip/hip_runtime.h>
#include <hip/hip_bf16.h>
#include <hip/hip_fp16.h>

#define NLAYERS 4
#define AGG_BLOCKS 2048

// ---------------- small zero kernel ----------------
__global__ void zero_ints(int* __restrict__ p, int n)
{
    int i = blockIdx.x * 256 + threadIdx.x;
    if (i < n) p[i] = 0;
}

// ---------------- CSR build ----------------
__global__ void hist_kernel(const int* __restrict__ dsts, int* __restrict__ counts, int E)
{
    int i = blockIdx.x * 256 + threadIdx.x;
    if (i < E) atomicAdd(&counts[dsts[i]], 1);
}

__global__ __launch_bounds__(256) void scan1(const int* __restrict__ counts,
                                             int* __restrict__ offsets,
                                             int* __restrict__ blocksums, int N)
{
    __shared__ int sdata[256];
    int t = threadIdx.x;
    int bbase = blockIdx.x * 1024;
    int v[4]; int s = 0;
#pragma unroll
    for (int q = 0; q < 4; q++) {
        int idx = bbase + t * 4 + q;
        v[q] = (idx < N) ? counts[idx] : 0;
        s += v[q];
    }
    sdata[t] = s;
    __syncthreads();
    for (int off = 1; off < 256; off <<= 1) {
        int x = (t >= off) ? sdata[t - off] : 0;
        __syncthreads();
        sdata[t] += x;
        __syncthreads();
    }
    int excl = sdata[t] - s;
    int run = excl;
#pragma unroll
    for (int q = 0; q < 4; q++) {
        int idx = bbase + t * 4 + q;
        if (idx < N) offsets[idx] = run;
        run += v[q];
    }
    if (t == 255) blocksums[blockIdx.x] = sdata[255];
}

__global__ void scan2(int* __restrict__ blocksums, int nb)
{
    if (threadIdx.x == 0 && blockIdx.x == 0) {
        int run = 0;
        for (int b = 0; b < nb; b++) { int t = blocksums[b]; blocksums[b] = run; run += t; }
    }
}

__global__ void scan3(int* __restrict__ offsets, const int* __restrict__ blocksums,
                      int* __restrict__ cursor, int N)
{
    int i = blockIdx.x * 256 + threadIdx.x;
    if (i < N) {
        int v = offsets[i] + blocksums[i >> 10];
        offsets[i] = v;
        cursor[i] = v;
    }
}

__global__ void scatter_kernel(const int* __restrict__ srcs, const int* __restrict__ dsts,
                               int* __restrict__ cursor, int* __restrict__ perm,
                               int* __restrict__ srcp, int* __restrict__ dstp, int E)
{
    int i = blockIdx.x * 256 + threadIdx.x;
    if (i < E) {
        int d = dsts[i];
        int slot = atomicAdd(&cursor[d], 1);
        perm[slot] = i;
        srcp[slot] = srcs[i];
        dstp[slot] = d;
    }
}

// ---------------- init projections ----------------
__global__ void init_proj4(const float* __restrict__ in, const float* __restrict__ w,
                           const float* __restrict__ b, float4* __restrict__ out, size_t n4)
{
    size_t i = (size_t)blockIdx.x * 256 + threadIdx.x;
    if (i < n4) {
        int j4 = (int)(i & 7) * 4;
        float xv = in[i >> 3];
        float4 wv = *(const float4*)(w + j4);
        float4 bv = *(const float4*)(b + j4);
        out[i] = make_float4(fmaf(xv, wv.x, bv.x), fmaf(xv, wv.y, bv.y),
                             fmaf(xv, wv.z, bv.z), fmaf(xv, wv.w, bv.w));
    }
}

__global__ void init_ep4(const float* __restrict__ e_in, const int* __restrict__ perm,
                         const float* __restrict__ w, const float* __restrict__ b,
                         float4* __restrict__ out, size_t n4)
{
    size_t i = (size_t)blockIdx.x * 256 + threadIdx.x;
    if (i < n4) {
        int row = (int)(i >> 3);
        float xv = e_in[perm[row]];
        int j4 = (int)(i & 7) * 4;
        float4 wv = *(const float4*)(w + j4);
        float4 bv = *(const float4*)(b + j4);
        out[i] = make_float4(fmaf(xv, wv.x, bv.x), fmaf(xv, wv.y, bv.y),
                             fmaf(xv, wv.z, bv.z), fmaf(xv, wv.w, bv.w));
    }
}

// ---------------- node GEMMs: one node per thread, scalar-broadcast weights ----------------
__device__ __forceinline__ void mat32(const float* __restrict__ hrow,
                                      const float* __restrict__ W, const float* __restrict__ Wb,
                                      float* __restrict__ dst)
{
    float acc[32];
#pragma unroll
    for (int j = 0; j < 32; j++) acc[j] = Wb[j];
#pragma unroll 4
    for (int k = 0; k < 32; k++) {
        float hk = hrow[k];
#pragma unroll
        for (int j = 0; j < 32; j++) acc[j] = fmaf(hk, W[k * 32 + j], acc[j]);
    }
    float4* o = (float4*)dst;
#pragma unroll
    for (int q = 0; q < 8; q++) o[q] = make_float4(acc[4*q], acc[4*q+1], acc[4*q+2], acc[4*q+3]);
}

__global__ __launch_bounds__(64) void node_gemm(
    const float* __restrict__ h,
    const float* __restrict__ Aw, const float* __restrict__ Ab,
    const float* __restrict__ Bw, const float* __restrict__ Bb,
    const float* __restrict__ Uw, const float* __restrict__ Ub,
    const float* __restrict__ Vw, const float* __restrict__ Vb,
    float* __restrict__ Ahh, float* __restrict__ Bhh,
    float* __restrict__ Uhh, float* __restrict__ Vhh, int N)
{
    int nid = blockIdx.x * 64 + threadIdx.x;
    if (nid >= N) return;
    const float* hrow = h + (size_t)nid * 32;
    size_t o = (size_t)nid * 32;
    mat32(hrow, Aw, Ab, Ahh + o);
    mat32(hrow, Bw, Bb, Bhh + o);
    mat32(hrow, Uw, Ub, Uhh + o);   // Uhh == hnew (folded)
    mat32(hrow, Vw, Vb, Vhh + o);
}

// ---- aggregation v4: group-per-node, shfl GEMM, 2-edge ILP, grid-stride, enew store ----
// SMODE: 0 = no store, 1 = fp32 enew, 2 = fp16 enew
template <int SMODE>
__global__ __launch_bounds__(256) void agg_kernel(
    const float* __restrict__ ep, const int* __restrict__ srcp,
    const int* __restrict__ offsets, const int* __restrict__ counts,
    const float* __restrict__ Ah, const float* __restrict__ Bh,
    const float* __restrict__ Vh,
    const float* __restrict__ Cw, const float* __restrict__ Cb,
    float* __restrict__ hnew, void* __restrict__ enew,
    float* __restrict__ partial, int N)
{
    __shared__ float red[512];
    int tid = threadIdx.x, j = tid & 31, grp = tid >> 5;
    float cw[32];
#pragma unroll
    for (int k = 0; k < 32; k++) cw[k] = Cw[k * 32 + j];
    float cbj = Cb[j];
    float esum = 0.f, esq = 0.f, hsum = 0.f, hsq = 0.f;
    float* enf = (float*)enew;
    __half* enh = (__half*)enew;
    for (int nb0 = blockIdx.x * 8; nb0 < N; nb0 += gridDim.x * 8) {
        int node = nb0 + grp;
        if (node >= N) break;
        int start = offsets[node], len = counts[node];
        float ahd = Ah[(size_t)node * 32 + j] + cbj;
        float num = 0.f, den = 0.f;
        int q = 0;
        for (; q + 2 <= len; q += 2) {
            int pos0 = start + q, pos1 = pos0 + 1;
            int s0 = srcp[pos0], s1 = srcp[pos1];
            float ev0 = ep[(size_t)pos0 * 32 + j];
            float ev1 = ep[(size_t)pos1 * 32 + j];
            float bh0 = Bh[(size_t)s0 * 32 + j];
            float bh1 = Bh[(size_t)s1 * 32 + j];
            float vh0 = Vh[(size_t)s0 * 32 + j];
            float vh1 = Vh[(size_t)s1 * 32 + j];
            float en0 = ahd + bh0, en1 = ahd + bh1;
#pragma unroll
            for (int k = 0; k < 32; k++) {
                en0 = fmaf(__shfl(ev0, k, 32), cw[k], en0);
                en1 = fmaf(__shfl(ev1, k, 32), cw[k], en1);
            }
            float sg0 = 1.f / (1.f + __expf(-en0));
            float sg1 = 1.f / (1.f + __expf(-en1));
            num = fmaf(sg0, vh0, num); num = fmaf(sg1, vh1, num);
            den += sg0 + sg1;
            esum += en0 + en1; esq += en0 * en0 + en1 * en1;
            if (SMODE == 1) { enf[(size_t)pos0 * 32 + j] = en0; enf[(size_t)pos1 * 32 + j] = en1; }
            if (SMODE == 2) { enh[(size_t)pos0 * 32 + j] = __float2half_rn(en0); enh[(size_t)pos1 * 32 + j] = __float2half_rn(en1); }
        }
        if (q < len) {
            int pos0 = start + q;
            int s0 = srcp[pos0];
            float ev0 = ep[(size_t)pos0 * 32 + j];
            float bh0 = Bh[(size_t)s0 * 32 + j];
            float vh0 = Vh[(size_t)s0 * 32 + j];
            float en0 = ahd + bh0;
#pragma unroll
            for (int k = 0; k < 32; k++)
                en0 = fmaf(__shfl(ev0, k, 32), cw[k], en0);
            float sg0 = 1.f / (1.f + __expf(-en0));
            num = fmaf(sg0, vh0, num);
            den += sg0;
            esum += en0; esq += en0 * en0;
            if (SMODE == 1) enf[(size_t)pos0 * 32 + j] = en0;
            if (SMODE == 2) enh[(size_t)pos0 * 32 + j] = __float2half_rn(en0);
        }
        size_t ho = (size_t)node * 32 + j;
        float hv = hnew[ho] + num / (den + 1e-6f);   // hnew holds Uh
        hnew[ho] = hv;
        hsum += hv; hsq += hv * hv;
    }
    // one-time block reduction of BN partials
    red[tid] = hsum; red[256 + tid] = hsq;
    __syncthreads();
    float hS = 0.f, hQ = 0.f;
    if (tid < 32) {
#pragma unroll
        for (int r = 0; r < 8; r++) { hS += red[r * 32 + tid]; hQ += red[256 + r * 32 + tid]; }
    }
    __syncthreads();
    red[tid] = esum; red[256 + tid] = esq;
    __syncthreads();
    if (tid < 32) {
        float eS = 0.f, eQ = 0.f;
#pragma unroll
        for (int r = 0; r < 8; r++) { eS += red[r * 32 + tid]; eQ += red[256 + r * 32 + tid]; }
        float* p = partial + (size_t)blockIdx.x * 128;
        p[tid] = hS; p[32 + tid] = hQ; p[64 + tid] = eS; p[96 + tid] = eQ;
    }
}

// ---------------- finalize BN stats: 64 blocks, one per (side, feature) ----------------
__global__ __launch_bounds__(256) void stats_finalize(
    const float* __restrict__ partial, int nb, double cntH, double cntE,
    const float* __restrict__ gH, const float* __restrict__ bH,
    const float* __restrict__ gE, const float* __restrict__ bE,
    float* __restrict__ stats)
{
    int side = blockIdx.x >> 5, j = blockIdx.x & 31;
    int c1 = side * 64 + j, c2 = c1 + 32;
    __shared__ double rs[256], rq[256];
    double s = 0.0, q = 0.0;
    for (int r = threadIdx.x; r < nb; r += 256) {
        s += (double)partial[(size_t)r * 128 + c1];
        q += (double)partial[(size_t)r * 128 + c2];
    }
    rs[threadIdx.x] = s; rq[threadIdx.x] = q;
    __syncthreads();
    for (int off = 128; off; off >>= 1) {
        if (threadIdx.x < off) { rs[threadIdx.x] += rs[threadIdx.x + off]; rq[threadIdx.x] += rq[threadIdx.x + off]; }
        __syncthreads();
    }
    if (threadIdx.x == 0) {
        double cnt = side ? cntE : cntH;
        const float* g = side ? gE : gH;
        const float* b = side ? bE : bH;
        double mean = rs[0] / cnt;
        double var = rq[0] / cnt - mean * mean;
        float scale = g[j] * (float)(1.0 / sqrt(var + 1e-5));
        stats[side * 64 + j] = scale;
        stats[side * 64 + 32 + j] = b[j] - (float)mean * scale;
    }
}

// ---------------- apply (float4): acc += relu(pre*scale + shift) ----------------
__global__ void apply4(const float4* __restrict__ pre, const float* __restrict__ scale,
                       const float* __restrict__ shift, float4* __restrict__ acc, size_t n4)
{
    size_t i = (size_t)blockIdx.x * 256 + threadIdx.x;
    if (i < n4) {
        int j4 = (int)(i & 7) * 4;
        float4 sc = *(const float4*)(scale + j4);
        float4 sh = *(const float4*)(shift + j4);
        float4 p = pre[i], a = acc[i];
        a.x += fmaxf(fmaf(p.x, sc.x, sh.x), 0.f);
        a.y += fmaxf(fmaf(p.y, sc.y, sh.y), 0.f);
        a.z += fmaxf(fmaf(p.z, sc.z, sh.z), 0.f);
        a.w += fmaxf(fmaf(p.w, sc.w, sh.w), 0.f);
        acc[i] = a;
    }
}

// ---------------- apply fp16 pre: acc += relu(half(pre)*scale + shift) ----------------
__global__ void apply4h(const __half* __restrict__ pre, const float* __restrict__ scale,
                        const float* __restrict__ shift, float4* __restrict__ acc, size_t n4)
{
    size_t i = (size_t)blockIdx.x * 256 + threadIdx.x;
    if (i < n4) {
        int j4 = (int)(i & 7) * 4;
        float4 sc = *(const float4*)(scale + j4);
        float4 sh = *(const float4*)(shift + j4);
        const __half2* p2 = (const __half2*)(pre + i * 4);
        float2 p01 = __half22float2(p2[0]);
        float2 p23 = __half22float2(p2[1]);
        float4 a = acc[i];
        a.x += fmaxf(fmaf(p01.x, sc.x, sh.x), 0.f);
        a.y += fmaxf(fmaf(p01.y, sc.y, sh.y), 0.f);
        a.z += fmaxf(fmaf(p23.x, sc.z, sh.z), 0.f);
        a.w += fmaxf(fmaf(p23.y, sc.w, sh.w), 0.f);
        acc[i] = a;
    }
}

// ---- fallback edge apply (recompute path, used only if ws too small for enew) ----
__global__ __launch_bounds__(256) void apply_ep(
    float* __restrict__ ep, const int* __restrict__ srcp, const int* __restrict__ dstp,
    const float* __restrict__ Ah, const float* __restrict__ Bh,
    const float* __restrict__ Cw, const float* __restrict__ Cb,
    const float* __restrict__ sc, const float* __restrict__ sh, int E)
{
    __shared__ float le[256];
    __shared__ int lsrc[8], ldst[8];
    int tid = threadIdx.x, j = tid & 31, el = tid >> 5;
    float cw[32];
#pragma unroll
    for (int k = 0; k < 32; k++) cw[k] = Cw[k * 32 + j];
    float cb = Cb[j];
    float scale = sc[j], shift = sh[j];
    int ng = (E + 7) >> 3;
    for (int g = blockIdx.x; g < ng; g += gridDim.x) {
        int base = g << 3;
        __syncthreads();
        if (tid < 64) {
            int row = base + (tid >> 3);
            if (row < E) ((float4*)le)[tid] = ((const float4*)(ep + (size_t)base * 32))[tid];
        }
        if (tid < 8) {
            int ee = base + tid;
            if (ee < E) { lsrc[tid] = srcp[ee]; ldst[tid] = dstp[ee]; }
        }
        __syncthreads();
        int eid = base + el;
        if (eid < E) {
            const float4* lr = (const float4*)(le + el * 32);
            float acc = cb;
#pragma unroll
            for (int q = 0; q < 8; q++) {
                float4 ev = lr[q];
                acc = fmaf(ev.x, cw[4*q],   acc);
                acc = fmaf(ev.y, cw[4*q+1], acc);
                acc = fmaf(ev.z, cw[4*q+2], acc);
                acc = fmaf(ev.w, cw[4*q+3], acc);
            }
            int s = lsrc[el], d = ldst[el];
            float en = acc + Ah[(size_t)d * 32 + j] + Bh[(size_t)s * 32 + j];
            float v = fmaf(en, scale, shift);
            ep[(size_t)eid * 32 + j] = le[el * 32 + j] + fmaxf(v, 0.f);
        }
    }
}

// ---------------- predictor: one permuted edge per thread, scatter output ----------------
__global__ __launch_bounds__(256) void predictor(
    const float* __restrict__ h, const float* __restrict__ ep,
    const int* __restrict__ srcp, const int* __restrict__ dstp, const int* __restrict__ perm,
    const float* __restrict__ W1, const float* __restrict__ b1,
    const float* __restrict__ W2, const float* __restrict__ b2v,
    float* __restrict__ out, int E)
{
    int pos = blockIdx.x * 256 + threadIdx.x;
    if (pos >= E) return;
    int s = srcp[pos], d = dstp[pos];
    float acc[32];
#pragma unroll
    for (int j = 0; j < 32; j++) acc[j] = b1[j];
    const float* zs = h + (size_t)s * 32;
    const float* zd = h + (size_t)d * 32;
    const float* ze = ep + (size_t)pos * 32;
#pragma unroll 4
    for (int k = 0; k < 32; k++) {
        float zk = zs[k];
#pragma unroll
        for (int j = 0; j < 32; j++) acc[j] = fmaf(zk, W1[k * 32 + j], acc[j]);
    }
#pragma unroll 4
    for (int k = 0; k < 32; k++) {
        float zk = zd[k];
#pragma unroll
        for (int j = 0; j < 32; j++) acc[j] = fmaf(zk, W1[(32 + k) * 32 + j], acc[j]);
    }
#pragma unroll 4
    for (int k = 0; k < 32; k++) {
        float zk = ze[k];
#pragma unroll
        for (int j = 0; j < 32; j++) acc[j] = fmaf(zk, W1[(64 + k) * 32 + j], acc[j]);
    }
    float t = b2v[0];
#pragma unroll
    for (int j = 0; j < 32; j++) t += fmaxf(acc[j], 0.f) * W2[j];
    out[perm[pos]] = t;
}

extern "C" void kernel_launch(void* const* d_in, const int* in_sizes, int n_in,
                              void* d_out, int out_size, void* d_ws, size_t ws_size,
                              hipStream_t stream)
{
    const int N = in_sizes[0];
    const int E = in_sizes[1];

    const float* x    = (const float*)d_in[0];
    const float* e_in = (const float*)d_in[1];
    const int*   eidx = (const int*)d_in[2];
    const float* pe_w = (const float*)d_in[3];
    const float* pe_b = (const float*)d_in[4];
    const float* ed_w = (const float*)d_in[5];
    const float* ed_b = (const float*)d_in[6];
    const float* Aw = (const float*)d_in[7];
    const float* Ab = (const float*)d_in[8];
    const float* Bw = (const float*)d_in[9];
    const float* Bb = (const float*)d_in[10];
    const float* Cw = (const float*)d_in[11];
    const float* Cb = (const float*)d_in[12];
    const float* Uw = (const float*)d_in[13];
    const float* Ub = (const float*)d_in[14];
    const float* Vw = (const float*)d_in[15];
    const float* Vb = (const float*)d_in[16];
    const float* bn_h_g = (const float*)d_in[17];
    const float* bn_h_b = (const float*)d_in[18];
    const float* bn_e_g = (const float*)d_in[19];
    const float* bn_e_b = (const float*)d_in[20];
    const float* W1w = (const float*)d_in[21];
    const float* W1b = (const float*)d_in[22];
    const float* W2w = (const float*)d_in[23];
    const float* W2b = (const float*)d_in[24];

    const int* srcs = eidx;
    const int* dsts = eidx + E;

    size_t nh = (size_t)N * 32;
    size_t eh = (size_t)E * 32;

    float* ws = (float*)d_ws;
    float* stats   = ws;                              // 128
    float* partial = stats + 128;                     // AGG_BLOCKS*128
    float* h    = partial + (size_t)AGG_BLOCKS * 128;
    float* Ah   = h + nh;
    float* Bh   = Ah + nh;
    float* Vh   = Bh + nh;
    float* hnew = Vh + nh;                            // holds Uh then h_new
    float* ep   = hnew + nh;
    int* counts    = (int*)(ep + eh);
    int* offsets   = counts + N;
    int* cursor    = offsets + N;
    int* blocksums = cursor + N;   // 128
    int* perm      = blocksums + 128;
    int* srcp      = perm + E;
    int* dstp      = srcp + E;
    void* enew     = (void*)(dstp + E);

    size_t base_bytes = (size_t)((char*)enew - (char*)ws);
    int smode = 0;
    if (base_bytes + eh * 4 <= ws_size) smode = 1;        // fp32 enew
    else if (base_bytes + eh * 2 <= ws_size) smode = 2;   // fp16 enew

    size_t nh4 = nh / 4, eh4 = eh / 4;
    int gh4 = (int)((nh4 + 255) / 256);
    int ge4 = (int)((eh4 + 255) / 256);
    int gN = (N + 255) / 256;
    int gE = (E + 255) / 256;
    int nb = (N + 1023) / 1024;
    int nAggGrid = (N + 7) / 8 < AGG_BLOCKS ? (N + 7) / 8 : AGG_BLOCKS;

    // ---- CSR build (dst-sorted edge permutation) ----
    zero_ints<<<gN, 256, 0, stream>>>(counts, N);
    hist_kernel<<<gE, 256, 0, stream>>>(dsts, counts, E);
    scan1<<<nb, 256, 0, stream>>>(counts, offsets, blocksums, N);
    scan2<<<1, 64, 0, stream>>>(blocksums, nb);
    scan3<<<gN, 256, 0, stream>>>(offsets, blocksums, cursor, N);
    scatter_kernel<<<gE, 256, 0, stream>>>(srcs, dsts, cursor, perm, srcp, dstp, E);

    // ---- input projections ----
    init_proj4<<<gh4, 256, 0, stream>>>(x, pe_w, pe_b, (float4*)h, nh4);
    init_ep4<<<ge4, 256, 0, stream>>>(e_in, perm, ed_w, ed_b, (float4*)ep, eh4);

    for (int l = 0; l < NLAYERS; l++) {
        node_gemm<<<(N + 63) / 64, 64, 0, stream>>>(h,
            Aw + l * 1024, Ab + l * 32,
            Bw + l * 1024, Bb + l * 32,
            Uw + l * 1024, Ub + l * 32,
            Vw + l * 1024, Vb + l * 32,
            Ah, Bh, hnew, Vh, N);
        if (smode == 1)
            agg_kernel<1><<<nAggGrid, 256, 0, stream>>>(ep, srcp, offsets, counts,
                Ah, Bh, Vh, Cw + l * 1024, Cb + l * 32, hnew, enew, partial, N);
        else if (smode == 2)
            agg_kernel<2><<<nAggGrid, 256, 0, stream>>>(ep, srcp, offsets, counts,
                Ah, Bh, Vh, Cw + l * 1024, Cb + l * 32, hnew, enew, partial, N);
        else
            agg_kernel<0><<<nAggGrid, 256, 0, stream>>>(ep, srcp, offsets, counts,
                Ah, Bh, Vh, Cw + l * 1024, Cb + l * 32, hnew, enew, partial, N);
        stats_finalize<<<64, 256, 0, stream>>>(partial, nAggGrid, (double)N, (double)E,
            bn_h_g + l * 32, bn_h_b + l * 32, bn_e_g + l * 32, bn_e_b + l * 32, stats);
        apply4<<<gh4, 256, 0, stream>>>((const float4*)hnew, stats + 0, stats + 32, (float4*)h, nh4);
        if (smode == 1)
            apply4<<<ge4, 256, 0, stream>>>((const float4*)enew, stats + 64, stats + 96, (float4*)ep, eh4);
        else if (smode == 2)
            apply4h<<<ge4, 256, 0, stream>>>((const __half*)enew, stats + 64, stats + 96, (float4*)ep, eh4);
        else
            apply_ep<<<4096, 256, 0, stream>>>(ep, srcp, dstp, Ah, Bh,
                Cw + l * 1024, Cb + l * 32, stats + 64, stats + 96, E);
    }

    predictor<<<gE, 256, 0, stream>>>(h, ep, srcp, dstp, perm, W1w, W1b, W2w, W2b,
                                      (float*)d_out, E);
}

// Round 9
// 1168.726 us; speedup vs baseline: 1.8464x; 1.2643x over previous
//
#include <hip/hip_runtime.h>
#include <hip/hip_bf16.h>
#include <hip/hip_fp16.h>

#define NLAYERS 4
#define GRID_STRIDE 2048

// ---------------- small zero kernel ----------------
__global__ void zero_ints(int* __restrict__ p, int n)
{
    int i = blockIdx.x * 256 + threadIdx.x;
    if (i < n) p[i] = 0;
}

// ---------------- CSR build ----------------
__global__ void hist_kernel(const int* __restrict__ dsts, int* __restrict__ counts, int E)
{
    int i = blockIdx.x * 256 + threadIdx.x;
    if (i < E) atomicAdd(&counts[dsts[i]], 1);
}

__global__ __launch_bounds__(256) void scan1(const int* __restrict__ counts,
                                             int* __restrict__ offsets,
                                             int* __restrict__ blocksums, int N)
{
    __shared__ int sdata[256];
    int t = threadIdx.x;
    int bbase = blockIdx.x * 1024;
    int v[4]; int s = 0;
#pragma unroll
    for (int q = 0; q < 4; q++) {
        int idx = bbase + t * 4 + q;
        v[q] = (idx < N) ? counts[idx] : 0;
        s += v[q];
    }
    sdata[t] = s;
    __syncthreads();
    for (int off = 1; off < 256; off <<= 1) {
        int x = (t >= off) ? sdata[t - off] : 0;
        __syncthreads();
        sdata[t] += x;
        __syncthreads();
    }
    int excl = sdata[t] - s;
    int run = excl;
#pragma unroll
    for (int q = 0; q < 4; q++) {
        int idx = bbase + t * 4 + q;
        if (idx < N) offsets[idx] = run;
        run += v[q];
    }
    if (t == 255) blocksums[blockIdx.x] = sdata[255];
}

__global__ void scan2(int* __restrict__ blocksums, int nb)
{
    if (threadIdx.x == 0 && blockIdx.x == 0) {
        int run = 0;
        for (int b = 0; b < nb; b++) { int t = blocksums[b]; blocksums[b] = run; run += t; }
    }
}

__global__ void scan3(int* __restrict__ offsets, const int* __restrict__ blocksums,
                      int* __restrict__ cursor, int N)
{
    int i = blockIdx.x * 256 + threadIdx.x;
    if (i < N) {
        int v = offsets[i] + blocksums[i >> 10];
        offsets[i] = v;
        cursor[i] = v;
    }
}

__global__ void scatter_kernel(const int* __restrict__ srcs, const int* __restrict__ dsts,
                               int* __restrict__ cursor, int* __restrict__ perm,
                               int* __restrict__ srcp, int* __restrict__ dstp, int E)
{
    int i = blockIdx.x * 256 + threadIdx.x;
    if (i < E) {
        int d = dsts[i];
        int slot = atomicAdd(&cursor[d], 1);
        perm[slot] = i;
        srcp[slot] = srcs[i];
        dstp[slot] = d;
    }
}

// ---------------- init projections ----------------
__global__ void init_proj4(const float* __restrict__ in, const float* __restrict__ w,
                           const float* __restrict__ b, float4* __restrict__ out, size_t n4)
{
    size_t i = (size_t)blockIdx.x * 256 + threadIdx.x;
    if (i < n4) {
        int j4 = (int)(i & 7) * 4;
        float xv = in[i >> 3];
        float4 wv = *(const float4*)(w + j4);
        float4 bv = *(const float4*)(b + j4);
        out[i] = make_float4(fmaf(xv, wv.x, bv.x), fmaf(xv, wv.y, bv.y),
                             fmaf(xv, wv.z, bv.z), fmaf(xv, wv.w, bv.w));
    }
}

__global__ void init_ep4(const float* __restrict__ e_in, const int* __restrict__ perm,
                         const float* __restrict__ w, const float* __restrict__ b,
                         float4* __restrict__ out, size_t n4)
{
    size_t i = (size_t)blockIdx.x * 256 + threadIdx.x;
    if (i < n4) {
        int row = (int)(i >> 3);
        float xv = e_in[perm[row]];
        int j4 = (int)(i & 7) * 4;
        float4 wv = *(const float4*)(w + j4);
        float4 bv = *(const float4*)(b + j4);
        out[i] = make_float4(fmaf(xv, wv.x, bv.x), fmaf(xv, wv.y, bv.y),
                             fmaf(xv, wv.z, bv.z), fmaf(xv, wv.w, bv.w));
    }
}

// ---------------- node GEMMs: one node per thread, scalar-broadcast weights ----------------
__device__ __forceinline__ void mat32(const float* __restrict__ hrow,
                                      const float* __restrict__ W, const float* __restrict__ Wb,
                                      float* __restrict__ dst)
{
    float acc[32];
#pragma unroll
    for (int j = 0; j < 32; j++) acc[j] = Wb[j];
#pragma unroll 4
    for (int k = 0; k < 32; k++) {
        float hk = hrow[k];
#pragma unroll
        for (int j = 0; j < 32; j++) acc[j] = fmaf(hk, W[k * 32 + j], acc[j]);
    }
    float4* o = (float4*)dst;
#pragma unroll
    for (int q = 0; q < 8; q++) o[q] = make_float4(acc[4*q], acc[4*q+1], acc[4*q+2], acc[4*q+3]);
}

__global__ __launch_bounds__(64) void node_gemm(
    const float* __restrict__ h,
    const float* __restrict__ Aw, const float* __restrict__ Ab,
    const float* __restrict__ Bw, const float* __restrict__ Bb,
    const float* __restrict__ Uw, const float* __restrict__ Ub,
    const float* __restrict__ Vw, const float* __restrict__ Vb,
    float* __restrict__ Ahh, float* __restrict__ Bhh,
    float* __restrict__ Uhh, float* __restrict__ Vhh, int N)
{
    int nid = blockIdx.x * 64 + threadIdx.x;
    if (nid >= N) return;
    const float* hrow = h + (size_t)nid * 32;
    size_t o = (size_t)nid * 32;
    mat32(hrow, Aw, Ab, Ahh + o);
    mat32(hrow, Bw, Bb, Bhh + o);
    mat32(hrow, Uw, Ub, Uhh + o);   // Uhh == hnew (folded)
    mat32(hrow, Vw, Vb, Vhh + o);
}

// ---- phase A: edge-bulk en = Ce*e + Ah[dst] + Bh[src]; fp16 store + e-BN partials ----
__global__ __launch_bounds__(256) void edge_en(
    const float* __restrict__ ep, const int* __restrict__ srcp, const int* __restrict__ dstp,
    const float* __restrict__ Ah, const float* __restrict__ Bh,
    const float* __restrict__ Cw, const float* __restrict__ Cb,
    __half* __restrict__ enh, float* __restrict__ partial, int E)
{
    __shared__ float le[512];              // 16 edges x 32
    __shared__ int lsrc[16], ldst[16];
    __shared__ float red[256];
    int tid = threadIdx.x, j = tid & 31, el = tid >> 5;
    float cw[32];
#pragma unroll
    for (int k = 0; k < 32; k++) cw[k] = Cw[k * 32 + j];
    float cb = Cb[j];
    float esum = 0.f, esq = 0.f;
    int ntile = (E + 15) >> 4;
    for (int t = blockIdx.x; t < ntile; t += gridDim.x) {
        int base = t << 4;
        __syncthreads();
        if (tid < 128) {
            size_t f4 = (size_t)base * 8 + tid;      // float4 index into ep
            if (f4 < (size_t)E * 8) ((float4*)le)[tid] = ((const float4*)ep)[f4];
        }
        if (tid < 16) {
            int ee = base + tid;
            if (ee < E) { lsrc[tid] = srcp[ee]; ldst[tid] = dstp[ee]; }
        }
        __syncthreads();
#pragma unroll
        for (int hh = 0; hh < 2; hh++) {
            int row = el + hh * 8;
            int eid = base + row;
            if (eid < E) {
                const float4* lr = (const float4*)(le + row * 32);
                float4 e0 = lr[0], e1 = lr[1], e2 = lr[2], e3 = lr[3];
                float4 e4 = lr[4], e5 = lr[5], e6 = lr[6], e7 = lr[7];
                float a0 = cb, a1 = 0.f, a2 = 0.f, a3 = 0.f;
                a0 = fmaf(e0.x, cw[0],  a0); a0 = fmaf(e0.y, cw[1],  a0);
                a0 = fmaf(e0.z, cw[2],  a0); a0 = fmaf(e0.w, cw[3],  a0);
                a1 = fmaf(e1.x, cw[4],  a1); a1 = fmaf(e1.y, cw[5],  a1);
                a1 = fmaf(e1.z, cw[6],  a1); a1 = fmaf(e1.w, cw[7],  a1);
                a2 = fmaf(e2.x, cw[8],  a2); a2 = fmaf(e2.y, cw[9],  a2);
                a2 = fmaf(e2.z, cw[10], a2); a2 = fmaf(e2.w, cw[11], a2);
                a3 = fmaf(e3.x, cw[12], a3); a3 = fmaf(e3.y, cw[13], a3);
                a3 = fmaf(e3.z, cw[14], a3); a3 = fmaf(e3.w, cw[15], a3);
                a0 = fmaf(e4.x, cw[16], a0); a0 = fmaf(e4.y, cw[17], a0);
                a0 = fmaf(e4.z, cw[18], a0); a0 = fmaf(e4.w, cw[19], a0);
                a1 = fmaf(e5.x, cw[20], a1); a1 = fmaf(e5.y, cw[21], a1);
                a1 = fmaf(e5.z, cw[22], a1); a1 = fmaf(e5.w, cw[23], a1);
                a2 = fmaf(e6.x, cw[24], a2); a2 = fmaf(e6.y, cw[25], a2);
                a2 = fmaf(e6.z, cw[26], a2); a2 = fmaf(e6.w, cw[27], a2);
                a3 = fmaf(e7.x, cw[28], a3); a3 = fmaf(e7.y, cw[29], a3);
                a3 = fmaf(e7.z, cw[30], a3); a3 = fmaf(e7.w, cw[31], a3);
                int s = lsrc[row], d = ldst[row];
                float en = (a0 + a1) + (a2 + a3)
                         + Ah[(size_t)d * 32 + j] + Bh[(size_t)s * 32 + j];
                enh[(size_t)eid * 32 + j] = __float2half_rn(en);
                esum += en; esq += en * en;
            }
        }
    }
    __syncthreads();
    red[tid] = esum;
    __syncthreads();
    float eS = 0.f;
    if (tid < 32) {
#pragma unroll
        for (int r = 0; r < 8; r++) eS += red[r * 32 + tid];
    }
    __syncthreads();
    red[tid] = esq;
    __syncthreads();
    if (tid < 32) {
        float eQ = 0.f;
#pragma unroll
        for (int r = 0; r < 8; r++) eQ += red[r * 32 + tid];
        float* p = partial + (size_t)blockIdx.x * 64;
        p[tid] = eS; p[32 + tid] = eQ;
    }
}

// ---- phase B: CSR walk; sigmoid(enh) + Vh gather; register num/den; h-BN partials ----
__global__ __launch_bounds__(256) void node_agg(
    const __half* __restrict__ enh, const int* __restrict__ srcp,
    const int* __restrict__ offsets, const int* __restrict__ counts,
    const float* __restrict__ Vh, float* __restrict__ hnew,
    float* __restrict__ partial, int N)
{
    __shared__ float red[256];
    int tid = threadIdx.x, j = tid & 31, grp = tid >> 5;
    float hsum = 0.f, hsq = 0.f;
    for (int nb0 = blockIdx.x * 8; nb0 < N; nb0 += gridDim.x * 8) {
        int node = nb0 + grp;
        if (node >= N) break;
        int start = offsets[node], len = counts[node];
        float num = 0.f, den = 0.f;
        int q = 0;
        for (; q + 2 <= len; q += 2) {
            int p0 = start + q, p1 = p0 + 1;
            int s0 = srcp[p0], s1 = srcp[p1];
            float en0 = __half2float(enh[(size_t)p0 * 32 + j]);
            float en1 = __half2float(enh[(size_t)p1 * 32 + j]);
            float vh0 = Vh[(size_t)s0 * 32 + j];
            float vh1 = Vh[(size_t)s1 * 32 + j];
            float sg0 = 1.f / (1.f + __expf(-en0));
            float sg1 = 1.f / (1.f + __expf(-en1));
            num = fmaf(sg0, vh0, num); num = fmaf(sg1, vh1, num);
            den += sg0 + sg1;
        }
        if (q < len) {
            int p0 = start + q;
            int s0 = srcp[p0];
            float en0 = __half2float(enh[(size_t)p0 * 32 + j]);
            float vh0 = Vh[(size_t)s0 * 32 + j];
            float sg0 = 1.f / (1.f + __expf(-en0));
            num = fmaf(sg0, vh0, num);
            den += sg0;
        }
        size_t ho = (size_t)node * 32 + j;
        float hv = hnew[ho] + num / (den + 1e-6f);   // hnew holds Uh
        hnew[ho] = hv;
        hsum += hv; hsq += hv * hv;
    }
    __syncthreads();
    red[tid] = hsum;
    __syncthreads();
    float hS = 0.f;
    if (tid < 32) {
#pragma unroll
        for (int r = 0; r < 8; r++) hS += red[r * 32 + tid];
    }
    __syncthreads();
    red[tid] = hsq;
    __syncthreads();
    if (tid < 32) {
        float hQ = 0.f;
#pragma unroll
        for (int r = 0; r < 8; r++) hQ += red[r * 32 + tid];
        float* p = partial + (size_t)blockIdx.x * 64;
        p[tid] = hS; p[32 + tid] = hQ;
    }
}

// ---------------- finalize BN stats: 64 blocks, one per (side, feature) ----------------
__global__ __launch_bounds__(256) void stats_finalize(
    const float* __restrict__ ph, int nrh, const float* __restrict__ pe, int nre,
    double cntH, double cntE,
    const float* __restrict__ gH, const float* __restrict__ bH,
    const float* __restrict__ gE, const float* __restrict__ bE,
    float* __restrict__ stats)
{
    int side = blockIdx.x >> 5, j = blockIdx.x & 31;
    const float* p = side ? pe : ph;
    int n = side ? nre : nrh;
    __shared__ double rs[256], rq[256];
    double s = 0.0, q = 0.0;
    for (int r = threadIdx.x; r < n; r += 256) {
        s += (double)p[(size_t)r * 64 + j];
        q += (double)p[(size_t)r * 64 + 32 + j];
    }
    rs[threadIdx.x] = s; rq[threadIdx.x] = q;
    __syncthreads();
    for (int off = 128; off; off >>= 1) {
        if (threadIdx.x < off) { rs[threadIdx.x] += rs[threadIdx.x + off]; rq[threadIdx.x] += rq[threadIdx.x + off]; }
        __syncthreads();
    }
    if (threadIdx.x == 0) {
        double cnt = side ? cntE : cntH;
        const float* g = side ? gE : gH;
        const float* b = side ? bE : bH;
        double mean = rs[0] / cnt;
        double var = rq[0] / cnt - mean * mean;
        float scale = g[j] * (float)(1.0 / sqrt(var + 1e-5));
        stats[side * 64 + j] = scale;
        stats[side * 64 + 32 + j] = b[j] - (float)mean * scale;
    }
}

// ---------------- apply (float4): acc += relu(pre*scale + shift) ----------------
__global__ void apply4(const float4* __restrict__ pre, const float* __restrict__ scale,
                       const float* __restrict__ shift, float4* __restrict__ acc, size_t n4)
{
    size_t i = (size_t)blockIdx.x * 256 + threadIdx.x;
    if (i < n4) {
        int j4 = (int)(i & 7) * 4;
        float4 sc = *(const float4*)(scale + j4);
        float4 sh = *(const float4*)(shift + j4);
        float4 p = pre[i], a = acc[i];
        a.x += fmaxf(fmaf(p.x, sc.x, sh.x), 0.f);
        a.y += fmaxf(fmaf(p.y, sc.y, sh.y), 0.f);
        a.z += fmaxf(fmaf(p.z, sc.z, sh.z), 0.f);
        a.w += fmaxf(fmaf(p.w, sc.w, sh.w), 0.f);
        acc[i] = a;
    }
}

// ---------------- apply fp16 pre: acc += relu(half(pre)*scale + shift) ----------------
__global__ void apply4h(const __half* __restrict__ pre, const float* __restrict__ scale,
                        const float* __restrict__ shift, float4* __restrict__ acc, size_t n4)
{
    size_t i = (size_t)blockIdx.x * 256 + threadIdx.x;
    if (i < n4) {
        int j4 = (int)(i & 7) * 4;
        float4 sc = *(const float4*)(scale + j4);
        float4 sh = *(const float4*)(shift + j4);
        const __half2* p2 = (const __half2*)(pre + i * 4);
        float2 p01 = __half22float2(p2[0]);
        float2 p23 = __half22float2(p2[1]);
        float4 a = acc[i];
        a.x += fmaxf(fmaf(p01.x, sc.x, sh.x), 0.f);
        a.y += fmaxf(fmaf(p01.y, sc.y, sh.y), 0.f);
        a.z += fmaxf(fmaf(p23.x, sc.z, sh.z), 0.f);
        a.w += fmaxf(fmaf(p23.y, sc.w, sh.w), 0.f);
        acc[i] = a;
    }
}

// ---------------- predictor: one permuted edge per thread, scatter output ----------------
__global__ __launch_bounds__(256) void predictor(
    const float* __restrict__ h, const float* __restrict__ ep,
    const int* __restrict__ srcp, const int* __restrict__ dstp, const int* __restrict__ perm,
    const float* __restrict__ W1, const float* __restrict__ b1,
    const float* __restrict__ W2, const float* __restrict__ b2v,
    float* __restrict__ out, int E)
{
    int pos = blockIdx.x * 256 + threadIdx.x;
    if (pos >= E) return;
    int s = srcp[pos], d = dstp[pos];
    float acc[32];
#pragma unroll
    for (int j = 0; j < 32; j++) acc[j] = b1[j];
    const float* zs = h + (size_t)s * 32;
    const float* zd = h + (size_t)d * 32;
    const float* ze = ep + (size_t)pos * 32;
#pragma unroll 4
    for (int k = 0; k < 32; k++) {
        float zk = zs[k];
#pragma unroll
        for (int j = 0; j < 32; j++) acc[j] = fmaf(zk, W1[k * 32 + j], acc[j]);
    }
#pragma unroll 4
    for (int k = 0; k < 32; k++) {
        float zk = zd[k];
#pragma unroll
        for (int j = 0; j < 32; j++) acc[j] = fmaf(zk, W1[(32 + k) * 32 + j], acc[j]);
    }
#pragma unroll 4
    for (int k = 0; k < 32; k++) {
        float zk = ze[k];
#pragma unroll
        for (int j = 0; j < 32; j++) acc[j] = fmaf(zk, W1[(64 + k) * 32 + j], acc[j]);
    }
    float t = b2v[0];
#pragma unroll
    for (int j = 0; j < 32; j++) t += fmaxf(acc[j], 0.f) * W2[j];
    out[perm[pos]] = t;
}

extern "C" void kernel_launch(void* const* d_in, const int* in_sizes, int n_in,
                              void* d_out, int out_size, void* d_ws, size_t ws_size,
                              hipStream_t stream)
{
    const int N = in_sizes[0];
    const int E = in_sizes[1];

    const float* x    = (const float*)d_in[0];
    const float* e_in = (const float*)d_in[1];
    const int*   eidx = (const int*)d_in[2];
    const float* pe_w = (const float*)d_in[3];
    const float* pe_b = (const float*)d_in[4];
    const float* ed_w = (const float*)d_in[5];
    const float* ed_b = (const float*)d_in[6];
    const float* Aw = (const float*)d_in[7];
    const float* Ab = (const float*)d_in[8];
    const float* Bw = (const float*)d_in[9];
    const float* Bb = (const float*)d_in[10];
    const float* Cw = (const float*)d_in[11];
    const float* Cb = (const float*)d_in[12];
    const float* Uw = (const float*)d_in[13];
    const float* Ub = (const float*)d_in[14];
    const float* Vw = (const float*)d_in[15];
    const float* Vb = (const float*)d_in[16];
    const float* bn_h_g = (const float*)d_in[17];
    const float* bn_h_b = (const float*)d_in[18];
    const float* bn_e_g = (const float*)d_in[19];
    const float* bn_e_b = (const float*)d_in[20];
    const float* W1w = (const float*)d_in[21];
    const float* W1b = (const float*)d_in[22];
    const float* W2w = (const float*)d_in[23];
    const float* W2b = (const float*)d_in[24];

    const int* srcs = eidx;
    const int* dsts = eidx + E;

    size_t nh = (size_t)N * 32;
    size_t eh = (size_t)E * 32;

    float* ws = (float*)d_ws;
    float* stats     = ws;                            // 128
    float* partial_h = stats + 128;                   // GRID_STRIDE*64
    float* partial_e = partial_h + GRID_STRIDE * 64;  // GRID_STRIDE*64
    float* h    = partial_e + GRID_STRIDE * 64;
    float* Ah   = h + nh;
    float* Bh   = Ah + nh;
    float* Vh   = Bh + nh;
    float* hnew = Vh + nh;                            // holds Uh then h_new
    float* ep   = hnew + nh;
    int* counts    = (int*)(ep + eh);
    int* offsets   = counts + N;
    int* cursor    = offsets + N;
    int* blocksums = cursor + N;   // 128
    int* perm      = blocksums + 128;
    int* srcp      = perm + E;
    int* dstp      = srcp + E;
    __half* enh    = (__half*)(dstp + E);             // eh halves (fits: measured round 8)

    size_t nh4 = nh / 4, eh4 = eh / 4;
    int gh4 = (int)((nh4 + 255) / 256);
    int ge4 = (int)((eh4 + 255) / 256);
    int gN = (N + 255) / 256;
    int gE = (E + 255) / 256;
    int nb = (N + 1023) / 1024;

    // ---- CSR build (dst-sorted edge permutation) ----
    zero_ints<<<gN, 256, 0, stream>>>(counts, N);
    hist_kernel<<<gE, 256, 0, stream>>>(dsts, counts, E);
    scan1<<<nb, 256, 0, stream>>>(counts, offsets, blocksums, N);
    scan2<<<1, 64, 0, stream>>>(blocksums, nb);
    scan3<<<gN, 256, 0, stream>>>(offsets, blocksums, cursor, N);
    scatter_kernel<<<gE, 256, 0, stream>>>(srcs, dsts, cursor, perm, srcp, dstp, E);

    // ---- input projections ----
    init_proj4<<<gh4, 256, 0, stream>>>(x, pe_w, pe_b, (float4*)h, nh4);
    init_ep4<<<ge4, 256, 0, stream>>>(e_in, perm, ed_w, ed_b, (float4*)ep, eh4);

    for (int l = 0; l < NLAYERS; l++) {
        node_gemm<<<(N + 63) / 64, 64, 0, stream>>>(h,
            Aw + l * 1024, Ab + l * 32,
            Bw + l * 1024, Bb + l * 32,
            Uw + l * 1024, Ub + l * 32,
            Vw + l * 1024, Vb + l * 32,
            Ah, Bh, hnew, Vh, N);
        edge_en<<<GRID_STRIDE, 256, 0, stream>>>(ep, srcp, dstp, Ah, Bh,
            Cw + l * 1024, Cb + l * 32, enh, partial_e, E);
        node_agg<<<GRID_STRIDE, 256, 0, stream>>>(enh, srcp, offsets, counts,
            Vh, hnew, partial_h, N);
        stats_finalize<<<64, 256, 0, stream>>>(partial_h, GRID_STRIDE, partial_e, GRID_STRIDE,
            (double)N, (double)E,
            bn_h_g + l * 32, bn_h_b + l * 32, bn_e_g + l * 32, bn_e_b + l * 32, stats);
        apply4<<<gh4, 256, 0, stream>>>((const float4*)hnew, stats + 0, stats + 32, (float4*)h, nh4);
        apply4h<<<ge4, 256, 0, stream>>>(enh, stats + 64, stats + 96, (float4*)ep, eh4);
    }

    predictor<<<gE, 256, 0, stream>>>(h, ep, srcp, dstp, perm, W1w, W1b, W2w, W2b,
                                      (float*)d_out, E);
}

// Round 10
// 1023.107 us; speedup vs baseline: 2.1093x; 1.1423x over previous
//
#include <hip/hip_runtime.h>
#include <hip/hip_bf16.h>
#include <hip/hip_fp16.h>

#define NLAYERS 4
#define GRID_STRIDE 2048

// ---------------- small zero kernel ----------------
__global__ void zero_ints(int* __restrict__ p, int n)
{
    int i = blockIdx.x * 256 + threadIdx.x;
    if (i < n) p[i] = 0;
}

// ---------------- CSR build ----------------
__global__ void hist_kernel(const int* __restrict__ dsts, int* __restrict__ counts, int E)
{
    int i = blockIdx.x * 256 + threadIdx.x;
    if (i < E) atomicAdd(&counts[dsts[i]], 1);
}

__global__ __launch_bounds__(256) void scan1(const int* __restrict__ counts,
                                             int* __restrict__ offsets,
                                             int* __restrict__ blocksums, int N)
{
    __shared__ int sdata[256];
    int t = threadIdx.x;
    int bbase = blockIdx.x * 1024;
    int v[4]; int s = 0;
#pragma unroll
    for (int q = 0; q < 4; q++) {
        int idx = bbase + t * 4 + q;
        v[q] = (idx < N) ? counts[idx] : 0;
        s += v[q];
    }
    sdata[t] = s;
    __syncthreads();
    for (int off = 1; off < 256; off <<= 1) {
        int x = (t >= off) ? sdata[t - off] : 0;
        __syncthreads();
        sdata[t] += x;
        __syncthreads();
    }
    int excl = sdata[t] - s;
    int run = excl;
#pragma unroll
    for (int q = 0; q < 4; q++) {
        int idx = bbase + t * 4 + q;
        if (idx < N) offsets[idx] = run;
        run += v[q];
    }
    if (t == 255) blocksums[blockIdx.x] = sdata[255];
}

__global__ void scan2(int* __restrict__ blocksums, int nb)
{
    if (threadIdx.x == 0 && blockIdx.x == 0) {
        int run = 0;
        for (int b = 0; b < nb; b++) { int t = blocksums[b]; blocksums[b] = run; run += t; }
    }
}

__global__ void scan3(int* __restrict__ offsets, const int* __restrict__ blocksums,
                      int* __restrict__ cursor, int N)
{
    int i = blockIdx.x * 256 + threadIdx.x;
    if (i < N) {
        int v = offsets[i] + blocksums[i >> 10];
        offsets[i] = v;
        cursor[i] = v;
    }
}

__global__ void scatter_kernel(const int* __restrict__ srcs, const int* __restrict__ dsts,
                               int* __restrict__ cursor, int* __restrict__ perm,
                               int* __restrict__ srcp, int* __restrict__ dstp, int E)
{
    int i = blockIdx.x * 256 + threadIdx.x;
    if (i < E) {
        int d = dsts[i];
        int slot = atomicAdd(&cursor[d], 1);
        perm[slot] = i;
        srcp[slot] = srcs[i];
        dstp[slot] = d;
    }
}

// ---------------- init projections ----------------
__global__ void init_proj4(const float* __restrict__ in, const float* __restrict__ w,
                           const float* __restrict__ b, float4* __restrict__ out, size_t n4)
{
    size_t i = (size_t)blockIdx.x * 256 + threadIdx.x;
    if (i < n4) {
        int j4 = (int)(i & 7) * 4;
        float xv = in[i >> 3];
        float4 wv = *(const float4*)(w + j4);
        float4 bv = *(const float4*)(b + j4);
        out[i] = make_float4(fmaf(xv, wv.x, bv.x), fmaf(xv, wv.y, bv.y),
                             fmaf(xv, wv.z, bv.z), fmaf(xv, wv.w, bv.w));
    }
}

__global__ void init_ep4(const float* __restrict__ e_in, const int* __restrict__ perm,
                         const float* __restrict__ w, const float* __restrict__ b,
                         float4* __restrict__ out, size_t n4)
{
    size_t i = (size_t)blockIdx.x * 256 + threadIdx.x;
    if (i < n4) {
        int row = (int)(i >> 3);
        float xv = e_in[perm[row]];
        int j4 = (int)(i & 7) * 4;
        float4 wv = *(const float4*)(w + j4);
        float4 bv = *(const float4*)(b + j4);
        out[i] = make_float4(fmaf(xv, wv.x, bv.x), fmaf(xv, wv.y, bv.y),
                             fmaf(xv, wv.z, bv.z), fmaf(xv, wv.w, bv.w));
    }
}

// ---------------- node GEMMs: one node per thread, scalar-broadcast weights ----------------
__device__ __forceinline__ void mat32(const float* __restrict__ hrow,
                                      const float* __restrict__ W, const float* __restrict__ Wb,
                                      float* __restrict__ dst)
{
    float acc[32];
#pragma unroll
    for (int j = 0; j < 32; j++) acc[j] = Wb[j];
#pragma unroll 4
    for (int k = 0; k < 32; k++) {
        float hk = hrow[k];
#pragma unroll
        for (int j = 0; j < 32; j++) acc[j] = fmaf(hk, W[k * 32 + j], acc[j]);
    }
    float4* o = (float4*)dst;
#pragma unroll
    for (int q = 0; q < 8; q++) o[q] = make_float4(acc[4*q], acc[4*q+1], acc[4*q+2], acc[4*q+3]);
}

__global__ __launch_bounds__(64) void node_gemm(
    const float* __restrict__ h,
    const float* __restrict__ Aw, const float* __restrict__ Ab,
    const float* __restrict__ Bw, const float* __restrict__ Bb,
    const float* __restrict__ Uw, const float* __restrict__ Ub,
    const float* __restrict__ Vw, const float* __restrict__ Vb,
    float* __restrict__ Ahh, float* __restrict__ Bhh,
    float* __restrict__ Uhh, float* __restrict__ Vhh, int N)
{
    int nid = blockIdx.x * 64 + threadIdx.x;
    if (nid >= N) return;
    const float* hrow = h + (size_t)nid * 32;
    size_t o = (size_t)nid * 32;
    mat32(hrow, Aw, Ab, Ahh + o);
    mat32(hrow, Bw, Bb, Bhh + o);
    mat32(hrow, Uw, Ub, Uhh + o);   // Uhh == hnew (folded)
    mat32(hrow, Vw, Vb, Vhh + o);
}

// ---- phase A: edge-bulk en = Ce*e + Ah[dst] + Bh[src]; fp16 store + e-BN partials ----
// FUSE: staging also applies prev layer's e-update: e = ep + relu(enh*sc+sh), written back.
template <int FUSE>
__global__ __launch_bounds__(256) void edge_en(
    float* __restrict__ ep, const float* __restrict__ sc_e, const float* __restrict__ sh_e,
    const int* __restrict__ srcp, const int* __restrict__ dstp,
    const float* __restrict__ Ah, const float* __restrict__ Bh,
    const float* __restrict__ Cw, const float* __restrict__ Cb,
    __half* __restrict__ enh, float* __restrict__ partial, int E)
{
    __shared__ float le[512];              // 16 edges x 32
    __shared__ int lsrc[16], ldst[16];
    __shared__ float red[256];
    int tid = threadIdx.x, j = tid & 31, el = tid >> 5;
    float cw[32];
#pragma unroll
    for (int k = 0; k < 32; k++) cw[k] = Cw[k * 32 + j];
    float cb = Cb[j];
    float4 scv, shv;
    if (FUSE && tid < 128) {
        scv = ((const float4*)sc_e)[tid & 7];
        shv = ((const float4*)sh_e)[tid & 7];
    }
    float esum = 0.f, esq = 0.f;
    int ntile = (E + 15) >> 4;
    for (int t = blockIdx.x; t < ntile; t += gridDim.x) {
        int base = t << 4;
        __syncthreads();
        if (tid < 128) {
            size_t f4 = (size_t)base * 8 + tid;      // float4 index into ep
            if (f4 < (size_t)E * 8) {
                float4 ev = ((const float4*)ep)[f4];
                if (FUSE) {
                    const __half2* p2 = (const __half2*)enh + f4 * 2;
                    float2 p01 = __half22float2(p2[0]);
                    float2 p23 = __half22float2(p2[1]);
                    ev.x += fmaxf(fmaf(p01.x, scv.x, shv.x), 0.f);
                    ev.y += fmaxf(fmaf(p01.y, scv.y, shv.y), 0.f);
                    ev.z += fmaxf(fmaf(p23.x, scv.z, shv.z), 0.f);
                    ev.w += fmaxf(fmaf(p23.y, scv.w, shv.w), 0.f);
                    ((float4*)ep)[f4] = ev;
                }
                ((float4*)le)[tid] = ev;
            }
        }
        if (tid < 16) {
            int ee = base + tid;
            if (ee < E) { lsrc[tid] = srcp[ee]; ldst[tid] = dstp[ee]; }
        }
        __syncthreads();
#pragma unroll
        for (int hh = 0; hh < 2; hh++) {
            int row = el + hh * 8;
            int eid = base + row;
            if (eid < E) {
                const float4* lr = (const float4*)(le + row * 32);
                float4 e0 = lr[0], e1 = lr[1], e2 = lr[2], e3 = lr[3];
                float4 e4 = lr[4], e5 = lr[5], e6 = lr[6], e7 = lr[7];
                float a0 = cb, a1 = 0.f, a2 = 0.f, a3 = 0.f;
                a0 = fmaf(e0.x, cw[0],  a0); a0 = fmaf(e0.y, cw[1],  a0);
                a0 = fmaf(e0.z, cw[2],  a0); a0 = fmaf(e0.w, cw[3],  a0);
                a1 = fmaf(e1.x, cw[4],  a1); a1 = fmaf(e1.y, cw[5],  a1);
                a1 = fmaf(e1.z, cw[6],  a1); a1 = fmaf(e1.w, cw[7],  a1);
                a2 = fmaf(e2.x, cw[8],  a2); a2 = fmaf(e2.y, cw[9],  a2);
                a2 = fmaf(e2.z, cw[10], a2); a2 = fmaf(e2.w, cw[11], a2);
                a3 = fmaf(e3.x, cw[12], a3); a3 = fmaf(e3.y, cw[13], a3);
                a3 = fmaf(e3.z, cw[14], a3); a3 = fmaf(e3.w, cw[15], a3);
                a0 = fmaf(e4.x, cw[16], a0); a0 = fmaf(e4.y, cw[17], a0);
                a0 = fmaf(e4.z, cw[18], a0); a0 = fmaf(e4.w, cw[19], a0);
                a1 = fmaf(e5.x, cw[20], a1); a1 = fmaf(e5.y, cw[21], a1);
                a1 = fmaf(e5.z, cw[22], a1); a1 = fmaf(e5.w, cw[23], a1);
                a2 = fmaf(e6.x, cw[24], a2); a2 = fmaf(e6.y, cw[25], a2);
                a2 = fmaf(e6.z, cw[26], a2); a2 = fmaf(e6.w, cw[27], a2);
                a3 = fmaf(e7.x, cw[28], a3); a3 = fmaf(e7.y, cw[29], a3);
                a3 = fmaf(e7.z, cw[30], a3); a3 = fmaf(e7.w, cw[31], a3);
                int s = lsrc[row], d = ldst[row];
                float en = (a0 + a1) + (a2 + a3)
                         + Ah[(size_t)d * 32 + j] + Bh[(size_t)s * 32 + j];
                enh[(size_t)eid * 32 + j] = __float2half_rn(en);
                esum += en; esq += en * en;
            }
        }
    }
    __syncthreads();
    red[tid] = esum;
    __syncthreads();
    float eS = 0.f;
    if (tid < 32) {
#pragma unroll
        for (int r = 0; r < 8; r++) eS += red[r * 32 + tid];
    }
    __syncthreads();
    red[tid] = esq;
    __syncthreads();
    if (tid < 32) {
        float eQ = 0.f;
#pragma unroll
        for (int r = 0; r < 8; r++) eQ += red[r * 32 + tid];
        float* p = partial + (size_t)blockIdx.x * 64;
        p[tid] = eS; p[32 + tid] = eQ;
    }
}

// ---- phase B: CSR walk; sigmoid(enh) + Vh gather; register num/den; h-BN partials ----
__global__ __launch_bounds__(256) void node_agg(
    const __half* __restrict__ enh, const int* __restrict__ srcp,
    const int* __restrict__ offsets, const int* __restrict__ counts,
    const float* __restrict__ Vh, float* __restrict__ hnew,
    float* __restrict__ partial, int N)
{
    __shared__ float red[256];
    int tid = threadIdx.x, j = tid & 31, grp = tid >> 5;
    float hsum = 0.f, hsq = 0.f;
    for (int nb0 = blockIdx.x * 8; nb0 < N; nb0 += gridDim.x * 8) {
        int node = nb0 + grp;
        if (node >= N) break;
        int start = offsets[node], len = counts[node];
        float num = 0.f, den = 0.f;
        int q = 0;
        for (; q + 2 <= len; q += 2) {
            int p0 = start + q, p1 = p0 + 1;
            int s0 = srcp[p0], s1 = srcp[p1];
            float en0 = __half2float(enh[(size_t)p0 * 32 + j]);
            float en1 = __half2float(enh[(size_t)p1 * 32 + j]);
            float vh0 = Vh[(size_t)s0 * 32 + j];
            float vh1 = Vh[(size_t)s1 * 32 + j];
            float sg0 = 1.f / (1.f + __expf(-en0));
            float sg1 = 1.f / (1.f + __expf(-en1));
            num = fmaf(sg0, vh0, num); num = fmaf(sg1, vh1, num);
            den += sg0 + sg1;
        }
        if (q < len) {
            int p0 = start + q;
            int s0 = srcp[p0];
            float en0 = __half2float(enh[(size_t)p0 * 32 + j]);
            float vh0 = Vh[(size_t)s0 * 32 + j];
            float sg0 = 1.f / (1.f + __expf(-en0));
            num = fmaf(sg0, vh0, num);
            den += sg0;
        }
        size_t ho = (size_t)node * 32 + j;
        float hv = hnew[ho] + num / (den + 1e-6f);   // hnew holds Uh
        hnew[ho] = hv;
        hsum += hv; hsq += hv * hv;
    }
    __syncthreads();
    red[tid] = hsum;
    __syncthreads();
    float hS = 0.f;
    if (tid < 32) {
#pragma unroll
        for (int r = 0; r < 8; r++) hS += red[r * 32 + tid];
    }
    __syncthreads();
    red[tid] = hsq;
    __syncthreads();
    if (tid < 32) {
        float hQ = 0.f;
#pragma unroll
        for (int r = 0; r < 8; r++) hQ += red[r * 32 + tid];
        float* p = partial + (size_t)blockIdx.x * 64;
        p[tid] = hS; p[32 + tid] = hQ;
    }
}

// ---------------- finalize BN stats: 64 blocks, one per (side, feature) ----------------
__global__ __launch_bounds__(256) void stats_finalize(
    const float* __restrict__ ph, int nrh, const float* __restrict__ pe, int nre,
    double cntH, double cntE,
    const float* __restrict__ gH, const float* __restrict__ bH,
    const float* __restrict__ gE, const float* __restrict__ bE,
    float* __restrict__ stats)
{
    int side = blockIdx.x >> 5, j = blockIdx.x & 31;
    const float* p = side ? pe : ph;
    int n = side ? nre : nrh;
    __shared__ double rs[256], rq[256];
    double s = 0.0, q = 0.0;
    for (int r = threadIdx.x; r < n; r += 256) {
        s += (double)p[(size_t)r * 64 + j];
        q += (double)p[(size_t)r * 64 + 32 + j];
    }
    rs[threadIdx.x] = s; rq[threadIdx.x] = q;
    __syncthreads();
    for (int off = 128; off; off >>= 1) {
        if (threadIdx.x < off) { rs[threadIdx.x] += rs[threadIdx.x + off]; rq[threadIdx.x] += rq[threadIdx.x + off]; }
        __syncthreads();
    }
    if (threadIdx.x == 0) {
        double cnt = side ? cntE : cntH;
        const float* g = side ? gE : gH;
        const float* b = side ? bE : bH;
        double mean = rs[0] / cnt;
        double var = rq[0] / cnt - mean * mean;
        float scale = g[j] * (float)(1.0 / sqrt(var + 1e-5));
        stats[side * 64 + j] = scale;
        stats[side * 64 + 32 + j] = b[j] - (float)mean * scale;
    }
}

// ---------------- apply (float4): acc += relu(pre*scale + shift) ----------------
__global__ void apply4(const float4* __restrict__ pre, const float* __restrict__ scale,
                       const float* __restrict__ shift, float4* __restrict__ acc, size_t n4)
{
    size_t i = (size_t)blockIdx.x * 256 + threadIdx.x;
    if (i < n4) {
        int j4 = (int)(i & 7) * 4;
        float4 sc = *(const float4*)(scale + j4);
        float4 sh = *(const float4*)(shift + j4);
        float4 p = pre[i], a = acc[i];
        a.x += fmaxf(fmaf(p.x, sc.x, sh.x), 0.f);
        a.y += fmaxf(fmaf(p.y, sc.y, sh.y), 0.f);
        a.z += fmaxf(fmaf(p.z, sc.z, sh.z), 0.f);
        a.w += fmaxf(fmaf(p.w, sc.w, sh.w), 0.f);
        acc[i] = a;
    }
}

// ---- final h apply: h16 = fp16(h + relu(hnew*sc+sh)) into a separate buffer ----
__global__ void apply4_h16(const float4* __restrict__ pre, const float* __restrict__ scale,
                           const float* __restrict__ shift, const float4* __restrict__ hold,
                           __half2* __restrict__ h16, size_t n4)
{
    size_t i = (size_t)blockIdx.x * 256 + threadIdx.x;
    if (i < n4) {
        int j4 = (int)(i & 7) * 4;
        float4 sc = *(const float4*)(scale + j4);
        float4 sh = *(const float4*)(shift + j4);
        float4 p = pre[i], a = hold[i];
        a.x += fmaxf(fmaf(p.x, sc.x, sh.x), 0.f);
        a.y += fmaxf(fmaf(p.y, sc.y, sh.y), 0.f);
        a.z += fmaxf(fmaf(p.z, sc.z, sh.z), 0.f);
        a.w += fmaxf(fmaf(p.w, sc.w, sh.w), 0.f);
        h16[i * 2]     = __floats2half2_rn(a.x, a.y);
        h16[i * 2 + 1] = __floats2half2_rn(a.z, a.w);
    }
}

// ---- final e apply, in place on enh: e16 = fp16(ep + relu(enh*sc+sh)) ----
__global__ void apply_e16(__half2* __restrict__ enh, const float* __restrict__ scale,
                          const float* __restrict__ shift, const float4* __restrict__ ep,
                          size_t n4)
{
    size_t i = (size_t)blockIdx.x * 256 + threadIdx.x;
    if (i < n4) {
        int j4 = (int)(i & 7) * 4;
        float4 sc = *(const float4*)(scale + j4);
        float4 sh = *(const float4*)(shift + j4);
        float2 p01 = __half22float2(enh[i * 2]);
        float2 p23 = __half22float2(enh[i * 2 + 1]);
        float4 a = ep[i];
        a.x += fmaxf(fmaf(p01.x, sc.x, sh.x), 0.f);
        a.y += fmaxf(fmaf(p01.y, sc.y, sh.y), 0.f);
        a.z += fmaxf(fmaf(p23.x, sc.z, sh.z), 0.f);
        a.w += fmaxf(fmaf(p23.y, sc.w, sh.w), 0.f);
        enh[i * 2]     = __floats2half2_rn(a.x, a.y);
        enh[i * 2 + 1] = __floats2half2_rn(a.z, a.w);
    }
}

// ---------------- predictor: fp16 inputs, one permuted edge per thread ----------------
__global__ __launch_bounds__(256) void predictor(
    const __half* __restrict__ h16, const __half* __restrict__ e16,
    const int* __restrict__ srcp, const int* __restrict__ dstp, const int* __restrict__ perm,
    const float* __restrict__ W1, const float* __restrict__ b1,
    const float* __restrict__ W2, const float* __restrict__ b2v,
    float* __restrict__ out, int E)
{
    int pos = blockIdx.x * 256 + threadIdx.x;
    if (pos >= E) return;
    int s = srcp[pos], d = dstp[pos];
    float acc[32];
#pragma unroll
    for (int j = 0; j < 32; j++) acc[j] = b1[j];
    const __half* zs = h16 + (size_t)s * 32;
    const __half* zd = h16 + (size_t)d * 32;
    const __half* ze = e16 + (size_t)pos * 32;
#pragma unroll 4
    for (int k = 0; k < 32; k++) {
        float zk = __half2float(zs[k]);
#pragma unroll
        for (int j = 0; j < 32; j++) acc[j] = fmaf(zk, W1[k * 32 + j], acc[j]);
    }
#pragma unroll 4
    for (int k = 0; k < 32; k++) {
        float zk = __half2float(zd[k]);
#pragma unroll
        for (int j = 0; j < 32; j++) acc[j] = fmaf(zk, W1[(32 + k) * 32 + j], acc[j]);
    }
#pragma unroll 4
    for (int k = 0; k < 32; k++) {
        float zk = __half2float(ze[k]);
#pragma unroll
        for (int j = 0; j < 32; j++) acc[j] = fmaf(zk, W1[(64 + k) * 32 + j], acc[j]);
    }
    float t = b2v[0];
#pragma unroll
    for (int j = 0; j < 32; j++) t += fmaxf(acc[j], 0.f) * W2[j];
    out[perm[pos]] = t;
}

extern "C" void kernel_launch(void* const* d_in, const int* in_sizes, int n_in,
                              void* d_out, int out_size, void* d_ws, size_t ws_size,
                              hipStream_t stream)
{
    const int N = in_sizes[0];
    const int E = in_sizes[1];

    const float* x    = (const float*)d_in[0];
    const float* e_in = (const float*)d_in[1];
    const int*   eidx = (const int*)d_in[2];
    const float* pe_w = (const float*)d_in[3];
    const float* pe_b = (const float*)d_in[4];
    const float* ed_w = (const float*)d_in[5];
    const float* ed_b = (const float*)d_in[6];
    const float* Aw = (const float*)d_in[7];
    const float* Ab = (const float*)d_in[8];
    const float* Bw = (const float*)d_in[9];
    const float* Bb = (const float*)d_in[10];
    const float* Cw = (const float*)d_in[11];
    const float* Cb = (const float*)d_in[12];
    const float* Uw = (const float*)d_in[13];
    const float* Ub = (const float*)d_in[14];
    const float* Vw = (const float*)d_in[15];
    const float* Vb = (const float*)d_in[16];
    const float* bn_h_g = (const float*)d_in[17];
    const float* bn_h_b = (const float*)d_in[18];
    const float* bn_e_g = (const float*)d_in[19];
    const float* bn_e_b = (const float*)d_in[20];
    const float* W1w = (const float*)d_in[21];
    const float* W1b = (const float*)d_in[22];
    const float* W2w = (const float*)d_in[23];
    const float* W2b = (const float*)d_in[24];

    const int* srcs = eidx;
    const int* dsts = eidx + E;

    size_t nh = (size_t)N * 32;
    size_t eh = (size_t)E * 32;

    float* ws = (float*)d_ws;
    float* stats     = ws;                            // 128
    float* partial_h = stats + 128;                   // GRID_STRIDE*64
    float* partial_e = partial_h + GRID_STRIDE * 64;  // GRID_STRIDE*64
    float* h    = partial_e + GRID_STRIDE * 64;
    float* Ah   = h + nh;                             // reused as h16 after last layer
    float* Bh   = Ah + nh;
    float* Vh   = Bh + nh;
    float* hnew = Vh + nh;                            // holds Uh then h_new
    float* ep   = hnew + nh;
    int* counts    = (int*)(ep + eh);
    int* offsets   = counts + N;
    int* cursor    = offsets + N;
    int* blocksums = cursor + N;   // 128
    int* perm      = blocksums + 128;
    int* srcp      = perm + E;
    int* dstp      = srcp + E;
    __half* enh    = (__half*)(dstp + E);             // eh halves; becomes e16 at the end

    size_t nh4 = nh / 4, eh4 = eh / 4;
    int gh4 = (int)((nh4 + 255) / 256);
    int ge4 = (int)((eh4 + 255) / 256);
    int gN = (N + 255) / 256;
    int gE = (E + 255) / 256;
    int nb = (N + 1023) / 1024;

    // ---- CSR build (dst-sorted edge permutation) ----
    zero_ints<<<gN, 256, 0, stream>>>(counts, N);
    hist_kernel<<<gE, 256, 0, stream>>>(dsts, counts, E);
    scan1<<<nb, 256, 0, stream>>>(counts, offsets, blocksums, N);
    scan2<<<1, 64, 0, stream>>>(blocksums, nb);
    scan3<<<gN, 256, 0, stream>>>(offsets, blocksums, cursor, N);
    scatter_kernel<<<gE, 256, 0, stream>>>(srcs, dsts, cursor, perm, srcp, dstp, E);

    // ---- input projections ----
    init_proj4<<<gh4, 256, 0, stream>>>(x, pe_w, pe_b, (float4*)h, nh4);
    init_ep4<<<ge4, 256, 0, stream>>>(e_in, perm, ed_w, ed_b, (float4*)ep, eh4);

    for (int l = 0; l < NLAYERS; l++) {
        node_gemm<<<(N + 63) / 64, 64, 0, stream>>>(h,
            Aw + l * 1024, Ab + l * 32,
            Bw + l * 1024, Bb + l * 32,
            Uw + l * 1024, Ub + l * 32,
            Vw + l * 1024, Vb + l * 32,
            Ah, Bh, hnew, Vh, N);
        // edge_en: for l>0, fuse the previous layer's e-update (stats still hold layer l-1)
        if (l == 0)
            edge_en<0><<<GRID_STRIDE, 256, 0, stream>>>(ep, stats + 64, stats + 96,
                srcp, dstp, Ah, Bh, Cw + l * 1024, Cb + l * 32, enh, partial_e, E);
        else
            edge_en<1><<<GRID_STRIDE, 256, 0, stream>>>(ep, stats + 64, stats + 96,
                srcp, dstp, Ah, Bh, Cw + l * 1024, Cb + l * 32, enh, partial_e, E);
        node_agg<<<GRID_STRIDE, 256, 0, stream>>>(enh, srcp, offsets, counts,
            Vh, hnew, partial_h, N);
        stats_finalize<<<64, 256, 0, stream>>>(partial_h, GRID_STRIDE, partial_e, GRID_STRIDE,
            (double)N, (double)E,
            bn_h_g + l * 32, bn_h_b + l * 32, bn_e_g + l * 32, bn_e_b + l * 32, stats);
        if (l < NLAYERS - 1)
            apply4<<<gh4, 256, 0, stream>>>((const float4*)hnew, stats + 0, stats + 32,
                                            (float4*)h, nh4);
        else
            apply4_h16<<<gh4, 256, 0, stream>>>((const float4*)hnew, stats + 0, stats + 32,
                                                (const float4*)h, (__half2*)Ah, nh4);
    }

    // final e-update: e16 in place over enh
    apply_e16<<<ge4, 256, 0, stream>>>((__half2*)enh, stats + 64, stats + 96,
                                       (const float4*)ep, eh4);

    predictor<<<gE, 256, 0, stream>>>((const __half*)Ah, (const __half*)enh,
                                      srcp, dstp, perm, W1w, W1b, W2w, W2b,
                                      (float*)d_out, E);
}

// Round 11
// 1016.890 us; speedup vs baseline: 2.1221x; 1.0061x over previous
//
#include <hip/hip_runtime.h>
#include <hip/hip_bf16.h>
#include <hip/hip_fp16.h>

#define NLAYERS 4
#define GRID_STRIDE 2048

// ---------------- small zero kernel ----------------
__global__ void zero_ints(int* __restrict__ p, int n)
{
    int i = blockIdx.x * 256 + threadIdx.x;
    if (i < n) p[i] = 0;
}

// ---------------- CSR build ----------------
__global__ void hist_kernel(const int* __restrict__ dsts, int* __restrict__ counts, int E)
{
    int i = blockIdx.x * 256 + threadIdx.x;
    if (i < E) atomicAdd(&counts[dsts[i]], 1);
}

__global__ __launch_bounds__(256) void scan1(const int* __restrict__ counts,
                                             int* __restrict__ offsets,
                                             int* __restrict__ blocksums, int N)
{
    __shared__ int sdata[256];
    int t = threadIdx.x;
    int bbase = blockIdx.x * 1024;
    int v[4]; int s = 0;
#pragma unroll
    for (int q = 0; q < 4; q++) {
        int idx = bbase + t * 4 + q;
        v[q] = (idx < N) ? counts[idx] : 0;
        s += v[q];
    }
    sdata[t] = s;
    __syncthreads();
    for (int off = 1; off < 256; off <<= 1) {
        int x = (t >= off) ? sdata[t - off] : 0;
        __syncthreads();
        sdata[t] += x;
        __syncthreads();
    }
    int excl = sdata[t] - s;
    int run = excl;
#pragma unroll
    for (int q = 0; q < 4; q++) {
        int idx = bbase + t * 4 + q;
        if (idx < N) offsets[idx] = run;
        run += v[q];
    }
    if (t == 255) blocksums[blockIdx.x] = sdata[255];
}

__global__ void scan2(int* __restrict__ blocksums, int nb)
{
    if (threadIdx.x == 0 && blockIdx.x == 0) {
        int run = 0;
        for (int b = 0; b < nb; b++) { int t = blocksums[b]; blocksums[b] = run; run += t; }
    }
}

__global__ void scan3(int* __restrict__ offsets, const int* __restrict__ blocksums,
                      int* __restrict__ cursor, int N)
{
    int i = blockIdx.x * 256 + threadIdx.x;
    if (i < N) {
        int v = offsets[i] + blocksums[i >> 10];
        offsets[i] = v;
        cursor[i] = v;
    }
}

__global__ void scatter_kernel(const int* __restrict__ srcs, const int* __restrict__ dsts,
                               int* __restrict__ cursor, int* __restrict__ perm,
                               int* __restrict__ srcp, int* __restrict__ dstp, int E)
{
    int i = blockIdx.x * 256 + threadIdx.x;
    if (i < E) {
        int d = dsts[i];
        int slot = atomicAdd(&cursor[d], 1);
        perm[slot] = i;
        srcp[slot] = srcs[i];
        dstp[slot] = d;
    }
}

// ---------------- init projections ----------------
__global__ void init_proj4(const float* __restrict__ in, const float* __restrict__ w,
                           const float* __restrict__ b, float4* __restrict__ out, size_t n4)
{
    size_t i = (size_t)blockIdx.x * 256 + threadIdx.x;
    if (i < n4) {
        int j4 = (int)(i & 7) * 4;
        float xv = in[i >> 3];
        float4 wv = *(const float4*)(w + j4);
        float4 bv = *(const float4*)(b + j4);
        out[i] = make_float4(fmaf(xv, wv.x, bv.x), fmaf(xv, wv.y, bv.y),
                             fmaf(xv, wv.z, bv.z), fmaf(xv, wv.w, bv.w));
    }
}

// permuted edge init, fp16 out: row i gets e_in[perm[i]]
__global__ void init_ep16(const float* __restrict__ e_in, const int* __restrict__ perm,
                          const float* __restrict__ w, const float* __restrict__ b,
                          __half2* __restrict__ out, size_t n4)
{
    size_t i = (size_t)blockIdx.x * 256 + threadIdx.x;
    if (i < n4) {
        int row = (int)(i >> 3);
        float xv = e_in[perm[row]];
        int j4 = (int)(i & 7) * 4;
        float4 wv = *(const float4*)(w + j4);
        float4 bv = *(const float4*)(b + j4);
        out[i * 2]     = __floats2half2_rn(fmaf(xv, wv.x, bv.x), fmaf(xv, wv.y, bv.y));
        out[i * 2 + 1] = __floats2half2_rn(fmaf(xv, wv.z, bv.z), fmaf(xv, wv.w, bv.w));
    }
}

// ---------------- node GEMMs: one node per thread, scalar-broadcast weights ----------------
__device__ __forceinline__ void mat32(const float* __restrict__ hrow,
                                      const float* __restrict__ W, const float* __restrict__ Wb,
                                      float* __restrict__ dst)
{
    float acc[32];
#pragma unroll
    for (int j = 0; j < 32; j++) acc[j] = Wb[j];
#pragma unroll 4
    for (int k = 0; k < 32; k++) {
        float hk = hrow[k];
#pragma unroll
        for (int j = 0; j < 32; j++) acc[j] = fmaf(hk, W[k * 32 + j], acc[j]);
    }
    float4* o = (float4*)dst;
#pragma unroll
    for (int q = 0; q < 8; q++) o[q] = make_float4(acc[4*q], acc[4*q+1], acc[4*q+2], acc[4*q+3]);
}

__device__ __forceinline__ void mat32h(const float* __restrict__ hrow,
                                       const float* __restrict__ W, const float* __restrict__ Wb,
                                       __half* __restrict__ dst)
{
    float acc[32];
#pragma unroll
    for (int j = 0; j < 32; j++) acc[j] = Wb[j];
#pragma unroll 4
    for (int k = 0; k < 32; k++) {
        float hk = hrow[k];
#pragma unroll
        for (int j = 0; j < 32; j++) acc[j] = fmaf(hk, W[k * 32 + j], acc[j]);
    }
    __half2* o = (__half2*)dst;
#pragma unroll
    for (int q = 0; q < 16; q++) o[q] = __floats2half2_rn(acc[2*q], acc[2*q+1]);
}

__global__ __launch_bounds__(64) void node_gemm(
    const float* __restrict__ h,
    const float* __restrict__ Aw, const float* __restrict__ Ab,
    const float* __restrict__ Bw, const float* __restrict__ Bb,
    const float* __restrict__ Uw, const float* __restrict__ Ub,
    const float* __restrict__ Vw, const float* __restrict__ Vb,
    __half* __restrict__ Ahh, __half* __restrict__ Bhh,
    float* __restrict__ Uhh, __half* __restrict__ Vhh, int N)
{
    int nid = blockIdx.x * 64 + threadIdx.x;
    if (nid >= N) return;
    const float* hrow = h + (size_t)nid * 32;
    size_t o = (size_t)nid * 32;
    mat32h(hrow, Aw, Ab, Ahh + o);
    mat32h(hrow, Bw, Bb, Bhh + o);
    mat32(hrow, Uw, Ub, Uhh + o);   // Uhh == hnew (folded)
    mat32h(hrow, Vw, Vb, Vhh + o);
}

// ---- phase A: edge-bulk en = Ce*e + Ah[dst] + Bh[src]; fp16 e, fp16 en; e-BN partials ----
// FUSE: staging also applies prev layer's e-update: e = ep + relu(enh*sc+sh), written back.
template <int FUSE>
__global__ __launch_bounds__(256) void edge_en(
    __half* __restrict__ ep, const float* __restrict__ sc_e, const float* __restrict__ sh_e,
    const int* __restrict__ srcp, const int* __restrict__ dstp,
    const __half* __restrict__ Ah, const __half* __restrict__ Bh,
    const float* __restrict__ Cw, const float* __restrict__ Cb,
    __half* __restrict__ enh, float* __restrict__ partial, int E)
{
    __shared__ float le[512];              // 16 edges x 32
    __shared__ int lsrc[16], ldst[16];
    __shared__ float red[256];
    int tid = threadIdx.x, j = tid & 31, el = tid >> 5;
    float cw[32];
#pragma unroll
    for (int k = 0; k < 32; k++) cw[k] = Cw[k * 32 + j];
    float cb = Cb[j];
    float4 scv, shv;
    if (FUSE && tid < 128) {
        scv = ((const float4*)sc_e)[tid & 7];
        shv = ((const float4*)sh_e)[tid & 7];
    }
    float esum = 0.f, esq = 0.f;
    int ntile = (E + 15) >> 4;
    for (int t = blockIdx.x; t < ntile; t += gridDim.x) {
        int base = t << 4;
        __syncthreads();
        if (tid < 128) {
            size_t g4 = (size_t)base * 8 + tid;      // group of 4 halves
            if (g4 < (size_t)E * 8) {
                __half2 h01 = ((const __half2*)ep)[g4 * 2];
                __half2 h23 = ((const __half2*)ep)[g4 * 2 + 1];
                float2 f01 = __half22float2(h01);
                float2 f23 = __half22float2(h23);
                float4 ev = make_float4(f01.x, f01.y, f23.x, f23.y);
                if (FUSE) {
                    float2 p01 = __half22float2(((const __half2*)enh)[g4 * 2]);
                    float2 p23 = __half22float2(((const __half2*)enh)[g4 * 2 + 1]);
                    ev.x += fmaxf(fmaf(p01.x, scv.x, shv.x), 0.f);
                    ev.y += fmaxf(fmaf(p01.y, scv.y, shv.y), 0.f);
                    ev.z += fmaxf(fmaf(p23.x, scv.z, shv.z), 0.f);
                    ev.w += fmaxf(fmaf(p23.y, scv.w, shv.w), 0.f);
                    ((__half2*)ep)[g4 * 2]     = __floats2half2_rn(ev.x, ev.y);
                    ((__half2*)ep)[g4 * 2 + 1] = __floats2half2_rn(ev.z, ev.w);
                }
                ((float4*)le)[tid] = ev;
            }
        }
        if (tid < 16) {
            int ee = base + tid;
            if (ee < E) { lsrc[tid] = srcp[ee]; ldst[tid] = dstp[ee]; }
        }
        __syncthreads();
#pragma unroll
        for (int hh = 0; hh < 2; hh++) {
            int row = el + hh * 8;
            int eid = base + row;
            if (eid < E) {
                const float4* lr = (const float4*)(le + row * 32);
                float4 e0 = lr[0], e1 = lr[1], e2 = lr[2], e3 = lr[3];
                float4 e4 = lr[4], e5 = lr[5], e6 = lr[6], e7 = lr[7];
                float a0 = cb, a1 = 0.f, a2 = 0.f, a3 = 0.f;
                a0 = fmaf(e0.x, cw[0],  a0); a0 = fmaf(e0.y, cw[1],  a0);
                a0 = fmaf(e0.z, cw[2],  a0); a0 = fmaf(e0.w, cw[3],  a0);
                a1 = fmaf(e1.x, cw[4],  a1); a1 = fmaf(e1.y, cw[5],  a1);
                a1 = fmaf(e1.z, cw[6],  a1); a1 = fmaf(e1.w, cw[7],  a1);
                a2 = fmaf(e2.x, cw[8],  a2); a2 = fmaf(e2.y, cw[9],  a2);
                a2 = fmaf(e2.z, cw[10], a2); a2 = fmaf(e2.w, cw[11], a2);
                a3 = fmaf(e3.x, cw[12], a3); a3 = fmaf(e3.y, cw[13], a3);
                a3 = fmaf(e3.z, cw[14], a3); a3 = fmaf(e3.w, cw[15], a3);
                a0 = fmaf(e4.x, cw[16], a0); a0 = fmaf(e4.y, cw[17], a0);
                a0 = fmaf(e4.z, cw[18], a0); a0 = fmaf(e4.w, cw[19], a0);
                a1 = fmaf(e5.x, cw[20], a1); a1 = fmaf(e5.y, cw[21], a1);
                a1 = fmaf(e5.z, cw[22], a1); a1 = fmaf(e5.w, cw[23], a1);
                a2 = fmaf(e6.x, cw[24], a2); a2 = fmaf(e6.y, cw[25], a2);
                a2 = fmaf(e6.z, cw[26], a2); a2 = fmaf(e6.w, cw[27], a2);
                a3 = fmaf(e7.x, cw[28], a3); a3 = fmaf(e7.y, cw[29], a3);
                a3 = fmaf(e7.z, cw[30], a3); a3 = fmaf(e7.w, cw[31], a3);
                int s = lsrc[row], d = ldst[row];
                float en = (a0 + a1) + (a2 + a3)
                         + __half2float(Ah[(size_t)d * 32 + j])
                         + __half2float(Bh[(size_t)s * 32 + j]);
                enh[(size_t)eid * 32 + j] = __float2half_rn(en);
                esum += en; esq += en * en;
            }
        }
    }
    __syncthreads();
    red[tid] = esum;
    __syncthreads();
    float eS = 0.f;
    if (tid < 32) {
#pragma unroll
        for (int r = 0; r < 8; r++) eS += red[r * 32 + tid];
    }
    __syncthreads();
    red[tid] = esq;
    __syncthreads();
    if (tid < 32) {
        float eQ = 0.f;
#pragma unroll
        for (int r = 0; r < 8; r++) eQ += red[r * 32 + tid];
        float* p = partial + (size_t)blockIdx.x * 64;
        p[tid] = eS; p[32 + tid] = eQ;
    }
}

// ---- phase B: CSR walk; sigmoid(enh) + fp16 Vh gather; register num/den; h-BN partials ----
__global__ __launch_bounds__(256) void node_agg(
    const __half* __restrict__ enh, const int* __restrict__ srcp,
    const int* __restrict__ offsets, const int* __restrict__ counts,
    const __half* __restrict__ Vh, float* __restrict__ hnew,
    float* __restrict__ partial, int N)
{
    __shared__ float red[256];
    int tid = threadIdx.x, j = tid & 31, grp = tid >> 5;
    float hsum = 0.f, hsq = 0.f;
    for (int nb0 = blockIdx.x * 8; nb0 < N; nb0 += gridDim.x * 8) {
        int node = nb0 + grp;
        if (node >= N) break;
        int start = offsets[node], len = counts[node];
        float num = 0.f, den = 0.f;
        int q = 0;
        for (; q + 2 <= len; q += 2) {
            int p0 = start + q, p1 = p0 + 1;
            int s0 = srcp[p0], s1 = srcp[p1];
            float en0 = __half2float(enh[(size_t)p0 * 32 + j]);
            float en1 = __half2float(enh[(size_t)p1 * 32 + j]);
            float vh0 = __half2float(Vh[(size_t)s0 * 32 + j]);
            float vh1 = __half2float(Vh[(size_t)s1 * 32 + j]);
            float sg0 = 1.f / (1.f + __expf(-en0));
            float sg1 = 1.f / (1.f + __expf(-en1));
            num = fmaf(sg0, vh0, num); num = fmaf(sg1, vh1, num);
            den += sg0 + sg1;
        }
        if (q < len) {
            int p0 = start + q;
            int s0 = srcp[p0];
            float en0 = __half2float(enh[(size_t)p0 * 32 + j]);
            float vh0 = __half2float(Vh[(size_t)s0 * 32 + j]);
            float sg0 = 1.f / (1.f + __expf(-en0));
            num = fmaf(sg0, vh0, num);
            den += sg0;
        }
        size_t ho = (size_t)node * 32 + j;
        float hv = hnew[ho] + num / (den + 1e-6f);   // hnew holds Uh
        hnew[ho] = hv;
        hsum += hv; hsq += hv * hv;
    }
    __syncthreads();
    red[tid] = hsum;
    __syncthreads();
    float hS = 0.f;
    if (tid < 32) {
#pragma unroll
        for (int r = 0; r < 8; r++) hS += red[r * 32 + tid];
    }
    __syncthreads();
    red[tid] = hsq;
    __syncthreads();
    if (tid < 32) {
        float hQ = 0.f;
#pragma unroll
        for (int r = 0; r < 8; r++) hQ += red[r * 32 + tid];
        float* p = partial + (size_t)blockIdx.x * 64;
        p[tid] = hS; p[32 + tid] = hQ;
    }
}

// ---------------- finalize BN stats: 64 blocks, one per (side, feature) ----------------
__global__ __launch_bounds__(256) void stats_finalize(
    const float* __restrict__ ph, int nrh, const float* __restrict__ pe, int nre,
    double cntH, double cntE,
    const float* __restrict__ gH, const float* __restrict__ bH,
    const float* __restrict__ gE, const float* __restrict__ bE,
    float* __restrict__ stats)
{
    int side = blockIdx.x >> 5, j = blockIdx.x & 31;
    const float* p = side ? pe : ph;
    int n = side ? nre : nrh;
    __shared__ double rs[256], rq[256];
    double s = 0.0, q = 0.0;
    for (int r = threadIdx.x; r < n; r += 256) {
        s += (double)p[(size_t)r * 64 + j];
        q += (double)p[(size_t)r * 64 + 32 + j];
    }
    rs[threadIdx.x] = s; rq[threadIdx.x] = q;
    __syncthreads();
    for (int off = 128; off; off >>= 1) {
        if (threadIdx.x < off) { rs[threadIdx.x] += rs[threadIdx.x + off]; rq[threadIdx.x] += rq[threadIdx.x + off]; }
        __syncthreads();
    }
    if (threadIdx.x == 0) {
        double cnt = side ? cntE : cntH;
        const float* g = side ? gE : gH;
        const float* b = side ? bE : bH;
        double mean = rs[0] / cnt;
        double var = rq[0] / cnt - mean * mean;
        float scale = g[j] * (float)(1.0 / sqrt(var + 1e-5));
        stats[side * 64 + j] = scale;
        stats[side * 64 + 32 + j] = b[j] - (float)mean * scale;
    }
}

// ---------------- apply (float4): acc += relu(pre*scale + shift) ----------------
__global__ void apply4(const float4* __restrict__ pre, const float* __restrict__ scale,
                       const float* __restrict__ shift, float4* __restrict__ acc, size_t n4)
{
    size_t i = (size_t)blockIdx.x * 256 + threadIdx.x;
    if (i < n4) {
        int j4 = (int)(i & 7) * 4;
        float4 sc = *(const float4*)(scale + j4);
        float4 sh = *(const float4*)(shift + j4);
        float4 p = pre[i], a = acc[i];
        a.x += fmaxf(fmaf(p.x, sc.x, sh.x), 0.f);
        a.y += fmaxf(fmaf(p.y, sc.y, sh.y), 0.f);
        a.z += fmaxf(fmaf(p.z, sc.z, sh.z), 0.f);
        a.w += fmaxf(fmaf(p.w, sc.w, sh.w), 0.f);
        acc[i] = a;
    }
}

// ---- final h apply: h16 = fp16(h + relu(hnew*sc+sh)) into a separate buffer ----
__global__ void apply4_h16(const float4* __restrict__ pre, const float* __restrict__ scale,
                           const float* __restrict__ shift, const float4* __restrict__ hold,
                           __half2* __restrict__ h16, size_t n4)
{
    size_t i = (size_t)blockIdx.x * 256 + threadIdx.x;
    if (i < n4) {
        int j4 = (int)(i & 7) * 4;
        float4 sc = *(const float4*)(scale + j4);
        float4 sh = *(const float4*)(shift + j4);
        float4 p = pre[i], a = hold[i];
        a.x += fmaxf(fmaf(p.x, sc.x, sh.x), 0.f);
        a.y += fmaxf(fmaf(p.y, sc.y, sh.y), 0.f);
        a.z += fmaxf(fmaf(p.z, sc.z, sh.z), 0.f);
        a.w += fmaxf(fmaf(p.w, sc.w, sh.w), 0.f);
        h16[i * 2]     = __floats2half2_rn(a.x, a.y);
        h16[i * 2 + 1] = __floats2half2_rn(a.z, a.w);
    }
}

// ---- final e apply, in place on enh: e16 = fp16(ep + relu(enh*sc+sh)) ----
__global__ void apply_e16(__half2* __restrict__ enh, const float* __restrict__ scale,
                          const float* __restrict__ shift, const __half2* __restrict__ ep,
                          size_t n4)
{
    size_t i = (size_t)blockIdx.x * 256 + threadIdx.x;
    if (i < n4) {
        int j4 = (int)(i & 7) * 4;
        float4 sc = *(const float4*)(scale + j4);
        float4 sh = *(const float4*)(shift + j4);
        float2 p01 = __half22float2(enh[i * 2]);
        float2 p23 = __half22float2(enh[i * 2 + 1]);
        float2 a01 = __half22float2(ep[i * 2]);
        float2 a23 = __half22float2(ep[i * 2 + 1]);
        a01.x += fmaxf(fmaf(p01.x, sc.x, sh.x), 0.f);
        a01.y += fmaxf(fmaf(p01.y, sc.y, sh.y), 0.f);
        a23.x += fmaxf(fmaf(p23.x, sc.z, sh.z), 0.f);
        a23.y += fmaxf(fmaf(p23.y, sc.w, sh.w), 0.f);
        enh[i * 2]     = __floats2half2_rn(a01.x, a01.y);
        enh[i * 2 + 1] = __floats2half2_rn(a23.x, a23.y);
    }
}

// ---------------- predictor: fp16 inputs, one permuted edge per thread ----------------
__global__ __launch_bounds__(256) void predictor(
    const __half* __restrict__ h16, const __half* __restrict__ e16,
    const int* __restrict__ srcp, const int* __restrict__ dstp, const int* __restrict__ perm,
    const float* __restrict__ W1, const float* __restrict__ b1,
    const float* __restrict__ W2, const float* __restrict__ b2v,
    float* __restrict__ out, int E)
{
    int pos = blockIdx.x * 256 + threadIdx.x;
    if (pos >= E) return;
    int s = srcp[pos], d = dstp[pos];
    float acc[32];
#pragma unroll
    for (int j = 0; j < 32; j++) acc[j] = b1[j];
    const __half* zs = h16 + (size_t)s * 32;
    const __half* zd = h16 + (size_t)d * 32;
    const __half* ze = e16 + (size_t)pos * 32;
#pragma unroll 4
    for (int k = 0; k < 32; k++) {
        float zk = __half2float(zs[k]);
#pragma unroll
        for (int j = 0; j < 32; j++) acc[j] = fmaf(zk, W1[k * 32 + j], acc[j]);
    }
#pragma unroll 4
    for (int k = 0; k < 32; k++) {
        float zk = __half2float(zd[k]);
#pragma unroll
        for (int j = 0; j < 32; j++) acc[j] = fmaf(zk, W1[(32 + k) * 32 + j], acc[j]);
    }
#pragma unroll 4
    for (int k = 0; k < 32; k++) {
        float zk = __half2float(ze[k]);
#pragma unroll
        for (int j = 0; j < 32; j++) acc[j] = fmaf(zk, W1[(64 + k) * 32 + j], acc[j]);
    }
    float t = b2v[0];
#pragma unroll
    for (int j = 0; j < 32; j++) t += fmaxf(acc[j], 0.f) * W2[j];
    out[perm[pos]] = t;
}

extern "C" void kernel_launch(void* const* d_in, const int* in_sizes, int n_in,
                              void* d_out, int out_size, void* d_ws, size_t ws_size,
                              hipStream_t stream)
{
    const int N = in_sizes[0];
    const int E = in_sizes[1];

    const float* x    = (const float*)d_in[0];
    const float* e_in = (const float*)d_in[1];
    const int*   eidx = (const int*)d_in[2];
    const float* pe_w = (const float*)d_in[3];
    const float* pe_b = (const float*)d_in[4];
    const float* ed_w = (const float*)d_in[5];
    const float* ed_b = (const float*)d_in[6];
    const float* Aw = (const float*)d_in[7];
    const float* Ab = (const float*)d_in[8];
    const float* Bw = (const float*)d_in[9];
    const float* Bb = (const float*)d_in[10];
    const float* Cw = (const float*)d_in[11];
    const float* Cb = (const float*)d_in[12];
    const float* Uw = (const float*)d_in[13];
    const float* Ub = (const float*)d_in[14];
    const float* Vw = (const float*)d_in[15];
    const float* Vb = (const float*)d_in[16];
    const float* bn_h_g = (const float*)d_in[17];
    const float* bn_h_b = (const float*)d_in[18];
    const float* bn_e_g = (const float*)d_in[19];
    const float* bn_e_b = (const float*)d_in[20];
    const float* W1w = (const float*)d_in[21];
    const float* W1b = (const float*)d_in[22];
    const float* W2w = (const float*)d_in[23];
    const float* W2b = (const float*)d_in[24];

    const int* srcs = eidx;
    const int* dsts = eidx + E;

    size_t nh = (size_t)N * 32;
    size_t eh = (size_t)E * 32;

    float* ws = (float*)d_ws;
    float* stats     = ws;                            // 128
    float* partial_h = stats + 128;                   // GRID_STRIDE*64
    float* partial_e = partial_h + GRID_STRIDE * 64;  // GRID_STRIDE*64
    float* h    = partial_e + GRID_STRIDE * 64;       // nh floats
    float* hnew = h + nh;                             // nh floats (Uh then h_new)
    __half* Ah  = (__half*)(hnew + nh);               // nh halves (h16 at the end)
    __half* Bh  = Ah + nh;                            // nh halves
    __half* Vh  = Bh + nh;                            // nh halves
    __half* ep  = Vh + nh;                            // eh halves
    __half* enh = ep + eh;                            // eh halves (e16 at the end)
    int* counts    = (int*)(enh + eh);
    int* offsets   = counts + N;
    int* cursor    = offsets + N;
    int* blocksums = cursor + N;   // 128
    int* perm      = blocksums + 128;
    int* srcp      = perm + E;
    int* dstp      = srcp + E;

    size_t nh4 = nh / 4, eh4 = eh / 4;
    int gh4 = (int)((nh4 + 255) / 256);
    int ge4 = (int)((eh4 + 255) / 256);
    int gN = (N + 255) / 256;
    int gE = (E + 255) / 256;
    int nb = (N + 1023) / 1024;

    // ---- CSR build (dst-sorted edge permutation) ----
    zero_ints<<<gN, 256, 0, stream>>>(counts, N);
    hist_kernel<<<gE, 256, 0, stream>>>(dsts, counts, E);
    scan1<<<nb, 256, 0, stream>>>(counts, offsets, blocksums, N);
    scan2<<<1, 64, 0, stream>>>(blocksums, nb);
    scan3<<<gN, 256, 0, stream>>>(offsets, blocksums, cursor, N);
    scatter_kernel<<<gE, 256, 0, stream>>>(srcs, dsts, cursor, perm, srcp, dstp, E);

    // ---- input projections ----
    init_proj4<<<gh4, 256, 0, stream>>>(x, pe_w, pe_b, (float4*)h, nh4);
    init_ep16<<<ge4, 256, 0, stream>>>(e_in, perm, ed_w, ed_b, (__half2*)ep, eh4);

    for (int l = 0; l < NLAYERS; l++) {
        node_gemm<<<(N + 63) / 64, 64, 0, stream>>>(h,
            Aw + l * 1024, Ab + l * 32,
            Bw + l * 1024, Bb + l * 32,
            Uw + l * 1024, Ub + l * 32,
            Vw + l * 1024, Vb + l * 32,
            Ah, Bh, hnew, Vh, N);
        // edge_en: for l>0, fuse the previous layer's e-update (stats still hold layer l-1)
        if (l == 0)
            edge_en<0><<<GRID_STRIDE, 256, 0, stream>>>(ep, stats + 64, stats + 96,
                srcp, dstp, Ah, Bh, Cw + l * 1024, Cb + l * 32, enh, partial_e, E);
        else
            edge_en<1><<<GRID_STRIDE, 256, 0, stream>>>(ep, stats + 64, stats + 96,
                srcp, dstp, Ah, Bh, Cw + l * 1024, Cb + l * 32, enh, partial_e, E);
        node_agg<<<GRID_STRIDE, 256, 0, stream>>>(enh, srcp, offsets, counts,
            Vh, hnew, partial_h, N);
        stats_finalize<<<64, 256, 0, stream>>>(partial_h, GRID_STRIDE, partial_e, GRID_STRIDE,
            (double)N, (double)E,
            bn_h_g + l * 32, bn_h_b + l * 32, bn_e_g + l * 32, bn_e_b + l * 32, stats);
        if (l < NLAYERS - 1)
            apply4<<<gh4, 256, 0, stream>>>((const float4*)hnew, stats + 0, stats + 32,
                                            (float4*)h, nh4);
        else
            apply4_h16<<<gh4, 256, 0, stream>>>((const float4*)hnew, stats + 0, stats + 32,
                                                (const float4*)h, (__half2*)Ah, nh4);
    }

    // final e-update: e16 in place over enh
    apply_e16<<<ge4, 256, 0, stream>>>((__half2*)enh, stats + 64, stats + 96,
                                       (const __half2*)ep, eh4);

    predictor<<<gE, 256, 0, stream>>>((const __half*)Ah, (const __half*)enh,
                                      srcp, dstp, perm, W1w, W1b, W2w, W2b,
                                      (float*)d_out, E);
}

// Round 12
// 823.939 us; speedup vs baseline: 2.6191x; 1.2342x over previous
//
#include <hip/hip_runtime.h>
#include <hip/hip_bf16.h>
#include <hip/hip_fp16.h>

#define NLAYERS 4
#define GRID_STRIDE 2048

typedef _Float16 half8_t __attribute__((ext_vector_type(8)));
typedef float float4_t __attribute__((ext_vector_type(4)));

// ---------------- small zero kernel ----------------
__global__ void zero_ints(int* __restrict__ p, int n)
{
    int i = blockIdx.x * 256 + threadIdx.x;
    if (i < n) p[i] = 0;
}

// ---------------- CSR build ----------------
__global__ void hist_kernel(const int* __restrict__ dsts, int* __restrict__ counts, int E)
{
    int i = blockIdx.x * 256 + threadIdx.x;
    if (i < E) atomicAdd(&counts[dsts[i]], 1);
}

__global__ __launch_bounds__(256) void scan1(const int* __restrict__ counts,
                                             int* __restrict__ offsets,
                                             int* __restrict__ blocksums, int N)
{
    __shared__ int sdata[256];
    int t = threadIdx.x;
    int bbase = blockIdx.x * 1024;
    int v[4]; int s = 0;
#pragma unroll
    for (int q = 0; q < 4; q++) {
        int idx = bbase + t * 4 + q;
        v[q] = (idx < N) ? counts[idx] : 0;
        s += v[q];
    }
    sdata[t] = s;
    __syncthreads();
    for (int off = 1; off < 256; off <<= 1) {
        int x = (t >= off) ? sdata[t - off] : 0;
        __syncthreads();
        sdata[t] += x;
        __syncthreads();
    }
    int excl = sdata[t] - s;
    int run = excl;
#pragma unroll
    for (int q = 0; q < 4; q++) {
        int idx = bbase + t * 4 + q;
        if (idx < N) offsets[idx] = run;
        run += v[q];
    }
    if (t == 255) blocksums[blockIdx.x] = sdata[255];
}

__global__ void scan2(int* __restrict__ blocksums, int nb)
{
    if (threadIdx.x == 0 && blockIdx.x == 0) {
        int run = 0;
        for (int b = 0; b < nb; b++) { int t = blocksums[b]; blocksums[b] = run; run += t; }
    }
}

__global__ void scan3(int* __restrict__ offsets, const int* __restrict__ blocksums,
                      int* __restrict__ cursor, int N)
{
    int i = blockIdx.x * 256 + threadIdx.x;
    if (i < N) {
        int v = offsets[i] + blocksums[i >> 10];
        offsets[i] = v;
        cursor[i] = v;
    }
}

__global__ void scatter_kernel(const int* __restrict__ srcs, const int* __restrict__ dsts,
                               int* __restrict__ cursor, int* __restrict__ perm,
                               int* __restrict__ srcp, int* __restrict__ dstp, int E)
{
    int i = blockIdx.x * 256 + threadIdx.x;
    if (i < E) {
        int d = dsts[i];
        int slot = atomicAdd(&cursor[d], 1);
        perm[slot] = i;
        srcp[slot] = srcs[i];
        dstp[slot] = d;
    }
}

// ---------------- init projections ----------------
__global__ void init_proj4(const float* __restrict__ in, const float* __restrict__ w,
                           const float* __restrict__ b, float4* __restrict__ out, size_t n4)
{
    size_t i = (size_t)blockIdx.x * 256 + threadIdx.x;
    if (i < n4) {
        int j4 = (int)(i & 7) * 4;
        float xv = in[i >> 3];
        float4 wv = *(const float4*)(w + j4);
        float4 bv = *(const float4*)(b + j4);
        out[i] = make_float4(fmaf(xv, wv.x, bv.x), fmaf(xv, wv.y, bv.y),
                             fmaf(xv, wv.z, bv.z), fmaf(xv, wv.w, bv.w));
    }
}

__global__ void init_ep16(const float* __restrict__ e_in, const int* __restrict__ perm,
                          const float* __restrict__ w, const float* __restrict__ b,
                          __half2* __restrict__ out, size_t n4)
{
    size_t i = (size_t)blockIdx.x * 256 + threadIdx.x;
    if (i < n4) {
        int row = (int)(i >> 3);
        float xv = e_in[perm[row]];
        int j4 = (int)(i & 7) * 4;
        float4 wv = *(const float4*)(w + j4);
        float4 bv = *(const float4*)(b + j4);
        out[i * 2]     = __floats2half2_rn(fmaf(xv, wv.x, bv.x), fmaf(xv, wv.y, bv.y));
        out[i * 2 + 1] = __floats2half2_rn(fmaf(xv, wv.z, bv.z), fmaf(xv, wv.w, bv.w));
    }
}

// ---------------- node GEMMs: one node per thread, scalar-broadcast weights ----------------
__device__ __forceinline__ void mat32(const float* __restrict__ hrow,
                                      const float* __restrict__ W, const float* __restrict__ Wb,
                                      float* __restrict__ dst)
{
    float acc[32];
#pragma unroll
    for (int j = 0; j < 32; j++) acc[j] = Wb[j];
#pragma unroll 4
    for (int k = 0; k < 32; k++) {
        float hk = hrow[k];
#pragma unroll
        for (int j = 0; j < 32; j++) acc[j] = fmaf(hk, W[k * 32 + j], acc[j]);
    }
    float4* o = (float4*)dst;
#pragma unroll
    for (int q = 0; q < 8; q++) o[q] = make_float4(acc[4*q], acc[4*q+1], acc[4*q+2], acc[4*q+3]);
}

__device__ __forceinline__ void mat32h(const float* __restrict__ hrow,
                                       const float* __restrict__ W, const float* __restrict__ Wb,
                                       __half* __restrict__ dst)
{
    float acc[32];
#pragma unroll
    for (int j = 0; j < 32; j++) acc[j] = Wb[j];
#pragma unroll 4
    for (int k = 0; k < 32; k++) {
        float hk = hrow[k];
#pragma unroll
        for (int j = 0; j < 32; j++) acc[j] = fmaf(hk, W[k * 32 + j], acc[j]);
    }
    __half2* o = (__half2*)dst;
#pragma unroll
    for (int q = 0; q < 16; q++) o[q] = __floats2half2_rn(acc[2*q], acc[2*q+1]);
}

__global__ __launch_bounds__(64) void node_gemm(
    const float* __restrict__ h,
    const float* __restrict__ Aw, const float* __restrict__ Ab,
    const float* __restrict__ Bw, const float* __restrict__ Bb,
    const float* __restrict__ Uw, const float* __restrict__ Ub,
    const float* __restrict__ Vw, const float* __restrict__ Vb,
    __half* __restrict__ Ahh, __half* __restrict__ Bhh,
    float* __restrict__ Uhh, __half* __restrict__ Vhh, int N)
{
    int nid = blockIdx.x * 64 + threadIdx.x;
    if (nid >= N) return;
    const float* hrow = h + (size_t)nid * 32;
    size_t o = (size_t)nid * 32;
    mat32h(hrow, Aw, Ab, Ahh + o);
    mat32h(hrow, Bw, Bb, Bhh + o);
    mat32(hrow, Uw, Ub, Uhh + o);   // Uhh == hnew (folded)
    mat32h(hrow, Vw, Vb, Vhh + o);
}

// ---- phase A (MFMA): en = e @ Cw + Cb + Ah[dst] + Bh[src] for 16-edge tiles per wave ----
// A-frag: lane holds ep[row=base+(lane&15)][k=(lane>>4)*8 .. +8]  (one 16B load)
// B-frag: lane holds Cw[k=(lane>>4)*8+i][n=lane&15 (+16 for tile1)]
// C/D:    element (row=(lane>>4)*4+reg, col=lane&15)
__global__ __launch_bounds__(256) void edge_en(
    const __half* __restrict__ ep,
    const int* __restrict__ srcp, const int* __restrict__ dstp,
    const __half* __restrict__ Ah, const __half* __restrict__ Bh,
    const float* __restrict__ Cw, const float* __restrict__ Cb,
    __half* __restrict__ enh, float* __restrict__ partial, int E)
{
    __shared__ float red[256];
    int tid = threadIdx.x;
    int lane = tid & 63;
    int m = lane & 15, q = lane >> 4;         // q in 0..3
    // B fragments (constant per kernel)
    half8_t b0, b1;
#pragma unroll
    for (int i = 0; i < 8; i++) {
        int k = q * 8 + i;
        b0[i] = (_Float16)Cw[k * 32 + m];
        b1[i] = (_Float16)Cw[k * 32 + m + 16];
    }
    float cb0 = Cb[m], cb1 = Cb[m + 16];
    float es0 = 0.f, eq0 = 0.f, es1 = 0.f, eq1 = 0.f;

    int ntile = (E + 15) >> 4;
    int wid = blockIdx.x * 4 + (tid >> 6);
    int nwave = gridDim.x * 4;
    for (int t = wid; t < ntile; t += nwave) {
        int base = t << 4;
        int arow = base + m;
        if (arow >= E) arow = E - 1;
        half8_t a = *(const half8_t*)(ep + (size_t)arow * 32 + q * 8);
        float4_t acc0 = __builtin_amdgcn_mfma_f32_16x16x32_f16(a, b0, (float4_t){0.f,0.f,0.f,0.f}, 0, 0, 0);
        float4_t acc1 = __builtin_amdgcn_mfma_f32_16x16x32_f16(a, b1, (float4_t){0.f,0.f,0.f,0.f}, 0, 0, 0);
#pragma unroll
        for (int reg = 0; reg < 4; reg++) {
            int row = q * 4 + reg;
            int edge = base + row;
            if (edge < E) {
                int s = srcp[edge], d = dstp[edge];
                float ah0 = __half2float(Ah[(size_t)d * 32 + m]);
                float bh0 = __half2float(Bh[(size_t)s * 32 + m]);
                float ah1 = __half2float(Ah[(size_t)d * 32 + m + 16]);
                float bh1 = __half2float(Bh[(size_t)s * 32 + m + 16]);
                float en0 = acc0[reg] + cb0 + ah0 + bh0;
                float en1 = acc1[reg] + cb1 + ah1 + bh1;
                enh[(size_t)edge * 32 + m]      = __float2half_rn(en0);
                enh[(size_t)edge * 32 + m + 16] = __float2half_rn(en1);
                es0 += en0; eq0 += en0 * en0;
                es1 += en1; eq1 += en1 * en1;
            }
        }
    }
    // block reduction of per-column partials: col c<16 <- (tile0), c+16 <- (tile1)
    float* p = partial + (size_t)blockIdx.x * 64;
    __syncthreads();
    red[tid] = es0;
    __syncthreads();
    if (tid < 16) {
        float s = 0.f;
#pragma unroll
        for (int w = 0; w < 4; w++)
#pragma unroll
            for (int k = 0; k < 4; k++) s += red[w * 64 + k * 16 + tid];
        p[tid] = s;
    }
    __syncthreads();
    red[tid] = es1;
    __syncthreads();
    if (tid < 16) {
        float s = 0.f;
#pragma unroll
        for (int w = 0; w < 4; w++)
#pragma unroll
            for (int k = 0; k < 4; k++) s += red[w * 64 + k * 16 + tid];
        p[16 + tid] = s;
    }
    __syncthreads();
    red[tid] = eq0;
    __syncthreads();
    if (tid < 16) {
        float s = 0.f;
#pragma unroll
        for (int w = 0; w < 4; w++)
#pragma unroll
            for (int k = 0; k < 4; k++) s += red[w * 64 + k * 16 + tid];
        p[32 + tid] = s;
    }
    __syncthreads();
    red[tid] = eq1;
    __syncthreads();
    if (tid < 16) {
        float s = 0.f;
#pragma unroll
        for (int w = 0; w < 4; w++)
#pragma unroll
            for (int k = 0; k < 4; k++) s += red[w * 64 + k * 16 + tid];
        p[48 + tid] = s;
    }
}

// ---- phase B: CSR walk; sigmoid + Vh gather; fused e-apply (ep += relu(en*sc+sh)) ----
__global__ __launch_bounds__(256) void node_agg(
    const __half* __restrict__ enh, const int* __restrict__ srcp,
    const int* __restrict__ offsets, const int* __restrict__ counts,
    const __half* __restrict__ Vh, float* __restrict__ hnew,
    __half* __restrict__ ep, const float* __restrict__ sc_e, const float* __restrict__ sh_e,
    float* __restrict__ partial, int N)
{
    __shared__ float red[256];
    int tid = threadIdx.x, j = tid & 31, grp = tid >> 5;
    float sc = sc_e[j], sh = sh_e[j];
    float hsum = 0.f, hsq = 0.f;
    for (int nb0 = blockIdx.x * 8; nb0 < N; nb0 += gridDim.x * 8) {
        int node = nb0 + grp;
        if (node >= N) break;
        int start = offsets[node], len = counts[node];
        float num = 0.f, den = 0.f;
        int qq = 0;
        for (; qq + 2 <= len; qq += 2) {
            int p0 = start + qq, p1 = p0 + 1;
            int s0 = srcp[p0], s1 = srcp[p1];
            float en0 = __half2float(enh[(size_t)p0 * 32 + j]);
            float en1 = __half2float(enh[(size_t)p1 * 32 + j]);
            float vh0 = __half2float(Vh[(size_t)s0 * 32 + j]);
            float vh1 = __half2float(Vh[(size_t)s1 * 32 + j]);
            float sg0 = 1.f / (1.f + __expf(-en0));
            float sg1 = 1.f / (1.f + __expf(-en1));
            num = fmaf(sg0, vh0, num); num = fmaf(sg1, vh1, num);
            den += sg0 + sg1;
            float e0 = __half2float(ep[(size_t)p0 * 32 + j]);
            float e1 = __half2float(ep[(size_t)p1 * 32 + j]);
            ep[(size_t)p0 * 32 + j] = __float2half_rn(e0 + fmaxf(fmaf(en0, sc, sh), 0.f));
            ep[(size_t)p1 * 32 + j] = __float2half_rn(e1 + fmaxf(fmaf(en1, sc, sh), 0.f));
        }
        if (qq < len) {
            int p0 = start + qq;
            int s0 = srcp[p0];
            float en0 = __half2float(enh[(size_t)p0 * 32 + j]);
            float vh0 = __half2float(Vh[(size_t)s0 * 32 + j]);
            float sg0 = 1.f / (1.f + __expf(-en0));
            num = fmaf(sg0, vh0, num);
            den += sg0;
            float e0 = __half2float(ep[(size_t)p0 * 32 + j]);
            ep[(size_t)p0 * 32 + j] = __float2half_rn(e0 + fmaxf(fmaf(en0, sc, sh), 0.f));
        }
        size_t ho = (size_t)node * 32 + j;
        float hv = hnew[ho] + num / (den + 1e-6f);   // hnew holds Uh
        hnew[ho] = hv;
        hsum += hv; hsq += hv * hv;
    }
    __syncthreads();
    red[tid] = hsum;
    __syncthreads();
    float hS = 0.f;
    if (tid < 32) {
#pragma unroll
        for (int r = 0; r < 8; r++) hS += red[r * 32 + tid];
    }
    __syncthreads();
    red[tid] = hsq;
    __syncthreads();
    if (tid < 32) {
        float hQ = 0.f;
#pragma unroll
        for (int r = 0; r < 8; r++) hQ += red[r * 32 + tid];
        float* p = partial + (size_t)blockIdx.x * 64;
        p[tid] = hS; p[32 + tid] = hQ;
    }
}

// ---------------- finalize BN stats for one side: 32 blocks, one per feature ----------------
__global__ __launch_bounds__(256) void stats_side(
    const float* __restrict__ partial, int nrows, double cnt,
    const float* __restrict__ g, const float* __restrict__ b,
    float* __restrict__ sc_out, float* __restrict__ sh_out)
{
    int j = blockIdx.x;
    __shared__ double rs[256], rq[256];
    double s = 0.0, q = 0.0;
    for (int r = threadIdx.x; r < nrows; r += 256) {
        s += (double)partial[(size_t)r * 64 + j];
        q += (double)partial[(size_t)r * 64 + 32 + j];
    }
    rs[threadIdx.x] = s; rq[threadIdx.x] = q;
    __syncthreads();
    for (int off = 128; off; off >>= 1) {
        if (threadIdx.x < off) { rs[threadIdx.x] += rs[threadIdx.x + off]; rq[threadIdx.x] += rq[threadIdx.x + off]; }
        __syncthreads();
    }
    if (threadIdx.x == 0) {
        double mean = rs[0] / cnt;
        double var = rq[0] / cnt - mean * mean;
        float scale = g[j] * (float)(1.0 / sqrt(var + 1e-5));
        sc_out[j] = scale;
        sh_out[j] = b[j] - (float)mean * scale;
    }
}

// ---------------- apply (float4): acc += relu(pre*scale + shift) ----------------
__global__ void apply4(const float4* __restrict__ pre, const float* __restrict__ scale,
                       const float* __restrict__ shift, float4* __restrict__ acc, size_t n4)
{
    size_t i = (size_t)blockIdx.x * 256 + threadIdx.x;
    if (i < n4) {
        int j4 = (int)(i & 7) * 4;
        float4 sc = *(const float4*)(scale + j4);
        float4 sh = *(const float4*)(shift + j4);
        float4 p = pre[i], a = acc[i];
        a.x += fmaxf(fmaf(p.x, sc.x, sh.x), 0.f);
        a.y += fmaxf(fmaf(p.y, sc.y, sh.y), 0.f);
        a.z += fmaxf(fmaf(p.z, sc.z, sh.z), 0.f);
        a.w += fmaxf(fmaf(p.w, sc.w, sh.w), 0.f);
        acc[i] = a;
    }
}

// ---- final h apply: h16 = fp16(h + relu(hnew*sc+sh)) into a separate buffer ----
__global__ void apply4_h16(const float4* __restrict__ pre, const float* __restrict__ scale,
                           const float* __restrict__ shift, const float4* __restrict__ hold,
                           __half2* __restrict__ h16, size_t n4)
{
    size_t i = (size_t)blockIdx.x * 256 + threadIdx.x;
    if (i < n4) {
        int j4 = (int)(i & 7) * 4;
        float4 sc = *(const float4*)(scale + j4);
        float4 sh = *(const float4*)(shift + j4);
        float4 p = pre[i], a = hold[i];
        a.x += fmaxf(fmaf(p.x, sc.x, sh.x), 0.f);
        a.y += fmaxf(fmaf(p.y, sc.y, sh.y), 0.f);
        a.z += fmaxf(fmaf(p.z, sc.z, sh.z), 0.f);
        a.w += fmaxf(fmaf(p.w, sc.w, sh.w), 0.f);
        h16[i * 2]     = __floats2half2_rn(a.x, a.y);
        h16[i * 2 + 1] = __floats2half2_rn(a.z, a.w);
    }
}

// ---------------- predictor: fp16 inputs, one permuted edge per thread ----------------
__global__ __launch_bounds__(256) void predictor(
    const __half* __restrict__ h16, const __half* __restrict__ e16,
    const int* __restrict__ srcp, const int* __restrict__ dstp, const int* __restrict__ perm,
    const float* __restrict__ W1, const float* __restrict__ b1,
    const float* __restrict__ W2, const float* __restrict__ b2v,
    float* __restrict__ out, int E)
{
    int pos = blockIdx.x * 256 + threadIdx.x;
    if (pos >= E) return;
    int s = srcp[pos], d = dstp[pos];
    float acc[32];
#pragma unroll
    for (int j = 0; j < 32; j++) acc[j] = b1[j];
    const __half* zs = h16 + (size_t)s * 32;
    const __half* zd = h16 + (size_t)d * 32;
    const __half* ze = e16 + (size_t)pos * 32;
#pragma unroll 4
    for (int k = 0; k < 32; k++) {
        float zk = __half2float(zs[k]);
#pragma unroll
        for (int j = 0; j < 32; j++) acc[j] = fmaf(zk, W1[k * 32 + j], acc[j]);
    }
#pragma unroll 4
    for (int k = 0; k < 32; k++) {
        float zk = __half2float(zd[k]);
#pragma unroll
        for (int j = 0; j < 32; j++) acc[j] = fmaf(zk, W1[(32 + k) * 32 + j], acc[j]);
    }
#pragma unroll 4
    for (int k = 0; k < 32; k++) {
        float zk = __half2float(ze[k]);
#pragma unroll
        for (int j = 0; j < 32; j++) acc[j] = fmaf(zk, W1[(64 + k) * 32 + j], acc[j]);
    }
    float t = b2v[0];
#pragma unroll
    for (int j = 0; j < 32; j++) t += fmaxf(acc[j], 0.f) * W2[j];
    out[perm[pos]] = t;
}

extern "C" void kernel_launch(void* const* d_in, const int* in_sizes, int n_in,
                              void* d_out, int out_size, void* d_ws, size_t ws_size,
                              hipStream_t stream)
{
    const int N = in_sizes[0];
    const int E = in_sizes[1];

    const float* x    = (const float*)d_in[0];
    const float* e_in = (const float*)d_in[1];
    const int*   eidx = (const int*)d_in[2];
    const float* pe_w = (const float*)d_in[3];
    const float* pe_b = (const float*)d_in[4];
    const float* ed_w = (const float*)d_in[5];
    const float* ed_b = (const float*)d_in[6];
    const float* Aw = (const float*)d_in[7];
    const float* Ab = (const float*)d_in[8];
    const float* Bw = (const float*)d_in[9];
    const float* Bb = (const float*)d_in[10];
    const float* Cw = (const float*)d_in[11];
    const float* Cb = (const float*)d_in[12];
    const float* Uw = (const float*)d_in[13];
    const float* Ub = (const float*)d_in[14];
    const float* Vw = (const float*)d_in[15];
    const float* Vb = (const float*)d_in[16];
    const float* bn_h_g = (const float*)d_in[17];
    const float* bn_h_b = (const float*)d_in[18];
    const float* bn_e_g = (const float*)d_in[19];
    const float* bn_e_b = (const float*)d_in[20];
    const float* W1w = (const float*)d_in[21];
    const float* W1b = (const float*)d_in[22];
    const float* W2w = (const float*)d_in[23];
    const float* W2b = (const float*)d_in[24];

    const int* srcs = eidx;
    const int* dsts = eidx + E;

    size_t nh = (size_t)N * 32;
    size_t eh = (size_t)E * 32;

    float* ws = (float*)d_ws;
    float* stats     = ws;                            // 128
    float* partial_h = stats + 128;                   // GRID_STRIDE*64
    float* partial_e = partial_h + GRID_STRIDE * 64;  // GRID_STRIDE*64
    float* h    = partial_e + GRID_STRIDE * 64;       // nh floats
    float* hnew = h + nh;                             // nh floats (Uh then h_new)
    __half* Ah  = (__half*)(hnew + nh);               // nh halves (h16 at the end)
    __half* Bh  = Ah + nh;                            // nh halves
    __half* Vh  = Bh + nh;                            // nh halves
    __half* ep  = Vh + nh;                            // eh halves (final e16 at the end)
    __half* enh = ep + eh;                            // eh halves
    int* counts    = (int*)(enh + eh);
    int* offsets   = counts + N;
    int* cursor    = offsets + N;
    int* blocksums = cursor + N;   // 128
    int* perm      = blocksums + 128;
    int* srcp      = perm + E;
    int* dstp      = srcp + E;

    size_t nh4 = nh / 4, eh4 = eh / 4;
    int gh4 = (int)((nh4 + 255) / 256);
    int ge4 = (int)((eh4 + 255) / 256);
    int gN = (N + 255) / 256;
    int gE = (E + 255) / 256;
    int nb = (N + 1023) / 1024;

    // ---- CSR build (dst-sorted edge permutation) ----
    zero_ints<<<gN, 256, 0, stream>>>(counts, N);
    hist_kernel<<<gE, 256, 0, stream>>>(dsts, counts, E);
    scan1<<<nb, 256, 0, stream>>>(counts, offsets, blocksums, N);
    scan2<<<1, 64, 0, stream>>>(blocksums, nb);
    scan3<<<gN, 256, 0, stream>>>(offsets, blocksums, cursor, N);
    scatter_kernel<<<gE, 256, 0, stream>>>(srcs, dsts, cursor, perm, srcp, dstp, E);

    // ---- input projections ----
    init_proj4<<<gh4, 256, 0, stream>>>(x, pe_w, pe_b, (float4*)h, nh4);
    init_ep16<<<ge4, 256, 0, stream>>>(e_in, perm, ed_w, ed_b, (__half2*)ep, eh4);

    for (int l = 0; l < NLAYERS; l++) {
        node_gemm<<<(N + 63) / 64, 64, 0, stream>>>(h,
            Aw + l * 1024, Ab + l * 32,
            Bw + l * 1024, Bb + l * 32,
            Uw + l * 1024, Ub + l * 32,
            Vw + l * 1024, Vb + l * 32,
            Ah, Bh, hnew, Vh, N);
        edge_en<<<GRID_STRIDE, 256, 0, stream>>>(ep, srcp, dstp, Ah, Bh,
            Cw + l * 1024, Cb + l * 32, enh, partial_e, E);
        stats_side<<<32, 256, 0, stream>>>(partial_e, GRID_STRIDE, (double)E,
            bn_e_g + l * 32, bn_e_b + l * 32, stats + 64, stats + 96);
        node_agg<<<GRID_STRIDE, 256, 0, stream>>>(enh, srcp, offsets, counts,
            Vh, hnew, ep, stats + 64, stats + 96, partial_h, N);
        stats_side<<<32, 256, 0, stream>>>(partial_h, GRID_STRIDE, (double)N,
            bn_h_g + l * 32, bn_h_b + l * 32, stats + 0, stats + 32);
        if (l < NLAYERS - 1)
            apply4<<<gh4, 256, 0, stream>>>((const float4*)hnew, stats + 0, stats + 32,
                                            (float4*)h, nh4);
        else
            apply4_h16<<<gh4, 256, 0, stream>>>((const float4*)hnew, stats + 0, stats + 32,
                                                (const float4*)h, (__half2*)Ah, nh4);
    }

    predictor<<<gE, 256, 0, stream>>>((const __half*)Ah, (const __half*)ep,
                                      srcp, dstp, perm, W1w, W1b, W2w, W2b,
                                      (float*)d_out, E);
}

// Round 13
// 788.024 us; speedup vs baseline: 2.7385x; 1.0456x over previous
//
#include <hip/hip_runtime.h>
#include <hip/hip_bf16.h>
#include <hip/hip_fp16.h>

#define NLAYERS 4
#define GRID_STRIDE 2048

typedef _Float16 half8_t __attribute__((ext_vector_type(8)));
typedef float float4_t __attribute__((ext_vector_type(4)));

// ---------------- small zero kernel ----------------
__global__ void zero_ints(int* __restrict__ p, int n)
{
    int i = blockIdx.x * 256 + threadIdx.x;
    if (i < n) p[i] = 0;
}

// ---------------- CSR build ----------------
__global__ void hist_kernel(const int* __restrict__ dsts, int* __restrict__ counts, int E)
{
    int i = blockIdx.x * 256 + threadIdx.x;
    if (i < E) atomicAdd(&counts[dsts[i]], 1);
}

__global__ __launch_bounds__(256) void scan1(const int* __restrict__ counts,
                                             int* __restrict__ offsets,
                                             int* __restrict__ blocksums, int N)
{
    __shared__ int sdata[256];
    int t = threadIdx.x;
    int bbase = blockIdx.x * 1024;
    int v[4]; int s = 0;
#pragma unroll
    for (int q = 0; q < 4; q++) {
        int idx = bbase + t * 4 + q;
        v[q] = (idx < N) ? counts[idx] : 0;
        s += v[q];
    }
    sdata[t] = s;
    __syncthreads();
    for (int off = 1; off < 256; off <<= 1) {
        int x = (t >= off) ? sdata[t - off] : 0;
        __syncthreads();
        sdata[t] += x;
        __syncthreads();
    }
    int excl = sdata[t] - s;
    int run = excl;
#pragma unroll
    for (int q = 0; q < 4; q++) {
        int idx = bbase + t * 4 + q;
        if (idx < N) offsets[idx] = run;
        run += v[q];
    }
    if (t == 255) blocksums[blockIdx.x] = sdata[255];
}

__global__ void scan2(int* __restrict__ blocksums, int nb)
{
    if (threadIdx.x == 0 && blockIdx.x == 0) {
        int run = 0;
        for (int b = 0; b < nb; b++) { int t = blocksums[b]; blocksums[b] = run; run += t; }
    }
}

__global__ void scan3(int* __restrict__ offsets, const int* __restrict__ blocksums,
                      int* __restrict__ cursor, int N)
{
    int i = blockIdx.x * 256 + threadIdx.x;
    if (i < N) {
        int v = offsets[i] + blocksums[i >> 10];
        offsets[i] = v;
        cursor[i] = v;
    }
}

__global__ void scatter_kernel(const int* __restrict__ srcs, const int* __restrict__ dsts,
                               int* __restrict__ cursor, int* __restrict__ perm,
                               int* __restrict__ srcp, int* __restrict__ dstp, int E)
{
    int i = blockIdx.x * 256 + threadIdx.x;
    if (i < E) {
        int d = dsts[i];
        int slot = atomicAdd(&cursor[d], 1);
        perm[slot] = i;
        srcp[slot] = srcs[i];
        dstp[slot] = d;
    }
}

// ---------------- init projections ----------------
__global__ void init_proj4(const float* __restrict__ in, const float* __restrict__ w,
                           const float* __restrict__ b, float4* __restrict__ out, size_t n4)
{
    size_t i = (size_t)blockIdx.x * 256 + threadIdx.x;
    if (i < n4) {
        int j4 = (int)(i & 7) * 4;
        float xv = in[i >> 3];
        float4 wv = *(const float4*)(w + j4);
        float4 bv = *(const float4*)(b + j4);
        out[i] = make_float4(fmaf(xv, wv.x, bv.x), fmaf(xv, wv.y, bv.y),
                             fmaf(xv, wv.z, bv.z), fmaf(xv, wv.w, bv.w));
    }
}

__global__ void init_ep16(const float* __restrict__ e_in, const int* __restrict__ perm,
                          const float* __restrict__ w, const float* __restrict__ b,
                          __half2* __restrict__ out, size_t n4)
{
    size_t i = (size_t)blockIdx.x * 256 + threadIdx.x;
    if (i < n4) {
        int row = (int)(i >> 3);
        float xv = e_in[perm[row]];
        int j4 = (int)(i & 7) * 4;
        float4 wv = *(const float4*)(w + j4);
        float4 bv = *(const float4*)(b + j4);
        out[i * 2]     = __floats2half2_rn(fmaf(xv, wv.x, bv.x), fmaf(xv, wv.y, bv.y));
        out[i * 2 + 1] = __floats2half2_rn(fmaf(xv, wv.z, bv.z), fmaf(xv, wv.w, bv.w));
    }
}

// ---------------- node GEMMs: one node per thread, scalar-broadcast weights ----------------
__device__ __forceinline__ void mat32(const float* __restrict__ hrow,
                                      const float* __restrict__ W, const float* __restrict__ Wb,
                                      float* __restrict__ dst)
{
    float acc[32];
#pragma unroll
    for (int j = 0; j < 32; j++) acc[j] = Wb[j];
#pragma unroll 4
    for (int k = 0; k < 32; k++) {
        float hk = hrow[k];
#pragma unroll
        for (int j = 0; j < 32; j++) acc[j] = fmaf(hk, W[k * 32 + j], acc[j]);
    }
    float4* o = (float4*)dst;
#pragma unroll
    for (int q = 0; q < 8; q++) o[q] = make_float4(acc[4*q], acc[4*q+1], acc[4*q+2], acc[4*q+3]);
}

__device__ __forceinline__ void mat32h(const float* __restrict__ hrow,
                                       const float* __restrict__ W, const float* __restrict__ Wb,
                                       __half* __restrict__ dst)
{
    float acc[32];
#pragma unroll
    for (int j = 0; j < 32; j++) acc[j] = Wb[j];
#pragma unroll 4
    for (int k = 0; k < 32; k++) {
        float hk = hrow[k];
#pragma unroll
        for (int j = 0; j < 32; j++) acc[j] = fmaf(hk, W[k * 32 + j], acc[j]);
    }
    __half2* o = (__half2*)dst;
#pragma unroll
    for (int q = 0; q < 16; q++) o[q] = __floats2half2_rn(acc[2*q], acc[2*q+1]);
}

__global__ __launch_bounds__(64) void node_gemm(
    const float* __restrict__ h,
    const float* __restrict__ Aw, const float* __restrict__ Ab,
    const float* __restrict__ Bw, const float* __restrict__ Bb,
    const float* __restrict__ Uw, const float* __restrict__ Ub,
    const float* __restrict__ Vw, const float* __restrict__ Vb,
    __half* __restrict__ Ahh, __half* __restrict__ Bhh,
    float* __restrict__ Uhh, __half* __restrict__ Vhh, int N)
{
    int nid = blockIdx.x * 64 + threadIdx.x;
    if (nid >= N) return;
    const float* hrow = h + (size_t)nid * 32;
    size_t o = (size_t)nid * 32;
    mat32h(hrow, Aw, Ab, Ahh + o);
    mat32h(hrow, Bw, Bb, Bhh + o);
    mat32(hrow, Uw, Ub, Uhh + o);   // Uhh == hnew (folded)
    mat32h(hrow, Vw, Vb, Vhh + o);
}

// ---- phase A (MFMA): en = e @ Cw + Cb + Ah[dst] + Bh[src] for 16-edge tiles per wave ----
__global__ __launch_bounds__(256) void edge_en(
    const __half* __restrict__ ep,
    const int* __restrict__ srcp, const int* __restrict__ dstp,
    const __half* __restrict__ Ah, const __half* __restrict__ Bh,
    const float* __restrict__ Cw, const float* __restrict__ Cb,
    __half* __restrict__ enh, float* __restrict__ partial, int E)
{
    __shared__ float red[256];
    int tid = threadIdx.x;
    int lane = tid & 63;
    int m = lane & 15, q = lane >> 4;         // q in 0..3
    half8_t b0, b1;
#pragma unroll
    for (int i = 0; i < 8; i++) {
        int k = q * 8 + i;
        b0[i] = (_Float16)Cw[k * 32 + m];
        b1[i] = (_Float16)Cw[k * 32 + m + 16];
    }
    float cb0 = Cb[m], cb1 = Cb[m + 16];
    float es0 = 0.f, eq0 = 0.f, es1 = 0.f, eq1 = 0.f;

    int ntile = (E + 15) >> 4;
    int wid = blockIdx.x * 4 + (tid >> 6);
    int nwave = gridDim.x * 4;
    for (int t = wid; t < ntile; t += nwave) {
        int base = t << 4;
        int arow = base + m;
        if (arow >= E) arow = E - 1;
        half8_t a = *(const half8_t*)(ep + (size_t)arow * 32 + q * 8);
        float4_t acc0 = __builtin_amdgcn_mfma_f32_16x16x32_f16(a, b0, (float4_t){0.f,0.f,0.f,0.f}, 0, 0, 0);
        float4_t acc1 = __builtin_amdgcn_mfma_f32_16x16x32_f16(a, b1, (float4_t){0.f,0.f,0.f,0.f}, 0, 0, 0);
#pragma unroll
        for (int reg = 0; reg < 4; reg++) {
            int row = q * 4 + reg;
            int edge = base + row;
            if (edge < E) {
                int s = srcp[edge], d = dstp[edge];
                float ah0 = __half2float(Ah[(size_t)d * 32 + m]);
                float bh0 = __half2float(Bh[(size_t)s * 32 + m]);
                float ah1 = __half2float(Ah[(size_t)d * 32 + m + 16]);
                float bh1 = __half2float(Bh[(size_t)s * 32 + m + 16]);
                float en0 = acc0[reg] + cb0 + ah0 + bh0;
                float en1 = acc1[reg] + cb1 + ah1 + bh1;
                enh[(size_t)edge * 32 + m]      = __float2half_rn(en0);
                enh[(size_t)edge * 32 + m + 16] = __float2half_rn(en1);
                es0 += en0; eq0 += en0 * en0;
                es1 += en1; eq1 += en1 * en1;
            }
        }
    }
    float* p = partial + (size_t)blockIdx.x * 64;
    __syncthreads();
    red[tid] = es0;
    __syncthreads();
    if (tid < 16) {
        float s = 0.f;
#pragma unroll
        for (int w = 0; w < 4; w++)
#pragma unroll
            for (int k = 0; k < 4; k++) s += red[w * 64 + k * 16 + tid];
        p[tid] = s;
    }
    __syncthreads();
    red[tid] = es1;
    __syncthreads();
    if (tid < 16) {
        float s = 0.f;
#pragma unroll
        for (int w = 0; w < 4; w++)
#pragma unroll
            for (int k = 0; k < 4; k++) s += red[w * 64 + k * 16 + tid];
        p[16 + tid] = s;
    }
    __syncthreads();
    red[tid] = eq0;
    __syncthreads();
    if (tid < 16) {
        float s = 0.f;
#pragma unroll
        for (int w = 0; w < 4; w++)
#pragma unroll
            for (int k = 0; k < 4; k++) s += red[w * 64 + k * 16 + tid];
        p[32 + tid] = s;
    }
    __syncthreads();
    red[tid] = eq1;
    __syncthreads();
    if (tid < 16) {
        float s = 0.f;
#pragma unroll
        for (int w = 0; w < 4; w++)
#pragma unroll
            for (int k = 0; k < 4; k++) s += red[w * 64 + k * 16 + tid];
        p[48 + tid] = s;
    }
}

// ---- phase B: CSR walk; sigmoid + Vh gather; fused e-apply (ep += relu(en*sc+sh)) ----
__global__ __launch_bounds__(256) void node_agg(
    const __half* __restrict__ enh, const int* __restrict__ srcp,
    const int* __restrict__ offsets, const int* __restrict__ counts,
    const __half* __restrict__ Vh, float* __restrict__ hnew,
    __half* __restrict__ ep, const float* __restrict__ sc_e, const float* __restrict__ sh_e,
    float* __restrict__ partial, int N)
{
    __shared__ float red[256];
    int tid = threadIdx.x, j = tid & 31, grp = tid >> 5;
    float sc = sc_e[j], sh = sh_e[j];
    float hsum = 0.f, hsq = 0.f;
    for (int nb0 = blockIdx.x * 8; nb0 < N; nb0 += gridDim.x * 8) {
        int node = nb0 + grp;
        if (node >= N) break;
        int start = offsets[node], len = counts[node];
        float num = 0.f, den = 0.f;
        int qq = 0;
        for (; qq + 2 <= len; qq += 2) {
            int p0 = start + qq, p1 = p0 + 1;
            int s0 = srcp[p0], s1 = srcp[p1];
            float en0 = __half2float(enh[(size_t)p0 * 32 + j]);
            float en1 = __half2float(enh[(size_t)p1 * 32 + j]);
            float vh0 = __half2float(Vh[(size_t)s0 * 32 + j]);
            float vh1 = __half2float(Vh[(size_t)s1 * 32 + j]);
            float sg0 = 1.f / (1.f + __expf(-en0));
            float sg1 = 1.f / (1.f + __expf(-en1));
            num = fmaf(sg0, vh0, num); num = fmaf(sg1, vh1, num);
            den += sg0 + sg1;
            float e0 = __half2float(ep[(size_t)p0 * 32 + j]);
            float e1 = __half2float(ep[(size_t)p1 * 32 + j]);
            ep[(size_t)p0 * 32 + j] = __float2half_rn(e0 + fmaxf(fmaf(en0, sc, sh), 0.f));
            ep[(size_t)p1 * 32 + j] = __float2half_rn(e1 + fmaxf(fmaf(en1, sc, sh), 0.f));
        }
        if (qq < len) {
            int p0 = start + qq;
            int s0 = srcp[p0];
            float en0 = __half2float(enh[(size_t)p0 * 32 + j]);
            float vh0 = __half2float(Vh[(size_t)s0 * 32 + j]);
            float sg0 = 1.f / (1.f + __expf(-en0));
            num = fmaf(sg0, vh0, num);
            den += sg0;
            float e0 = __half2float(ep[(size_t)p0 * 32 + j]);
            ep[(size_t)p0 * 32 + j] = __float2half_rn(e0 + fmaxf(fmaf(en0, sc, sh), 0.f));
        }
        size_t ho = (size_t)node * 32 + j;
        float hv = hnew[ho] + num / (den + 1e-6f);   // hnew holds Uh
        hnew[ho] = hv;
        hsum += hv; hsq += hv * hv;
    }
    __syncthreads();
    red[tid] = hsum;
    __syncthreads();
    float hS = 0.f;
    if (tid < 32) {
#pragma unroll
        for (int r = 0; r < 8; r++) hS += red[r * 32 + tid];
    }
    __syncthreads();
    red[tid] = hsq;
    __syncthreads();
    if (tid < 32) {
        float hQ = 0.f;
#pragma unroll
        for (int r = 0; r < 8; r++) hQ += red[r * 32 + tid];
        float* p = partial + (size_t)blockIdx.x * 64;
        p[tid] = hS; p[32 + tid] = hQ;
    }
}

// ---------------- finalize BN stats for one side: 32 blocks, one per feature ----------------
__global__ __launch_bounds__(256) void stats_side(
    const float* __restrict__ partial, int nrows, double cnt,
    const float* __restrict__ g, const float* __restrict__ b,
    float* __restrict__ sc_out, float* __restrict__ sh_out)
{
    int j = blockIdx.x;
    __shared__ double rs[256], rq[256];
    double s = 0.0, q = 0.0;
    for (int r = threadIdx.x; r < nrows; r += 256) {
        s += (double)partial[(size_t)r * 64 + j];
        q += (double)partial[(size_t)r * 64 + 32 + j];
    }
    rs[threadIdx.x] = s; rq[threadIdx.x] = q;
    __syncthreads();
    for (int off = 128; off; off >>= 1) {
        if (threadIdx.x < off) { rs[threadIdx.x] += rs[threadIdx.x + off]; rq[threadIdx.x] += rq[threadIdx.x + off]; }
        __syncthreads();
    }
    if (threadIdx.x == 0) {
        double mean = rs[0] / cnt;
        double var = rq[0] / cnt - mean * mean;
        float scale = g[j] * (float)(1.0 / sqrt(var + 1e-5));
        sc_out[j] = scale;
        sh_out[j] = b[j] - (float)mean * scale;
    }
}

// ---------------- apply (float4): acc += relu(pre*scale + shift) ----------------
__global__ void apply4(const float4* __restrict__ pre, const float* __restrict__ scale,
                       const float* __restrict__ shift, float4* __restrict__ acc, size_t n4)
{
    size_t i = (size_t)blockIdx.x * 256 + threadIdx.x;
    if (i < n4) {
        int j4 = (int)(i & 7) * 4;
        float4 sc = *(const float4*)(scale + j4);
        float4 sh = *(const float4*)(shift + j4);
        float4 p = pre[i], a = acc[i];
        a.x += fmaxf(fmaf(p.x, sc.x, sh.x), 0.f);
        a.y += fmaxf(fmaf(p.y, sc.y, sh.y), 0.f);
        a.z += fmaxf(fmaf(p.z, sc.z, sh.z), 0.f);
        a.w += fmaxf(fmaf(p.w, sc.w, sh.w), 0.f);
        acc[i] = a;
    }
}

// ---- final h apply: h16 = fp16(h + relu(hnew*sc+sh)) into a separate buffer ----
__global__ void apply4_h16(const float4* __restrict__ pre, const float* __restrict__ scale,
                           const float* __restrict__ shift, const float4* __restrict__ hold,
                           __half2* __restrict__ h16, size_t n4)
{
    size_t i = (size_t)blockIdx.x * 256 + threadIdx.x;
    if (i < n4) {
        int j4 = (int)(i & 7) * 4;
        float4 sc = *(const float4*)(scale + j4);
        float4 sh = *(const float4*)(shift + j4);
        float4 p = pre[i], a = hold[i];
        a.x += fmaxf(fmaf(p.x, sc.x, sh.x), 0.f);
        a.y += fmaxf(fmaf(p.y, sc.y, sh.y), 0.f);
        a.z += fmaxf(fmaf(p.z, sc.z, sh.z), 0.f);
        a.w += fmaxf(fmaf(p.w, sc.w, sh.w), 0.f);
        h16[i * 2]     = __floats2half2_rn(a.x, a.y);
        h16[i * 2 + 1] = __floats2half2_rn(a.z, a.w);
    }
}

// ---- predictor (MFMA): [16-edge tile × 96] @ [96 × 32], W1/W2 epilogue, perm scatter ----
__global__ __launch_bounds__(256) void predictor(
    const __half* __restrict__ h16, const __half* __restrict__ e16,
    const int* __restrict__ srcp, const int* __restrict__ dstp, const int* __restrict__ perm,
    const float* __restrict__ W1, const float* __restrict__ b1,
    const float* __restrict__ W2, const float* __restrict__ b2v,
    float* __restrict__ out, int E)
{
    int tid = threadIdx.x;
    int lane = tid & 63;
    int m = lane & 15, q = lane >> 4;
    // B fragments: 3 k-blocks (h[src], h[dst], e) x 2 col tiles, W1 cast to fp16
    half8_t bf00, bf01, bf10, bf11, bf20, bf21;
#pragma unroll
    for (int i = 0; i < 8; i++) {
        int k = q * 8 + i;
        bf00[i] = (_Float16)W1[k * 32 + m];
        bf01[i] = (_Float16)W1[k * 32 + m + 16];
        bf10[i] = (_Float16)W1[(32 + k) * 32 + m];
        bf11[i] = (_Float16)W1[(32 + k) * 32 + m + 16];
        bf20[i] = (_Float16)W1[(64 + k) * 32 + m];
        bf21[i] = (_Float16)W1[(64 + k) * 32 + m + 16];
    }
    float b10 = b1[m], b11 = b1[m + 16];
    float w20 = W2[m], w21 = W2[m + 16];
    float b2 = b2v[0];

    int ntile = (E + 15) >> 4;
    int wid = blockIdx.x * 4 + (tid >> 6);
    int nwave = gridDim.x * 4;
    for (int t = wid; t < ntile; t += nwave) {
        int base = t << 4;
        int arow = base + m;
        if (arow >= E) arow = E - 1;
        int s = srcp[arow], d = dstp[arow];
        half8_t a0 = *(const half8_t*)(h16 + (size_t)s * 32 + q * 8);
        half8_t a1 = *(const half8_t*)(h16 + (size_t)d * 32 + q * 8);
        half8_t a2 = *(const half8_t*)(e16 + (size_t)arow * 32 + q * 8);
        float4_t acc0 = {0.f, 0.f, 0.f, 0.f}, acc1 = {0.f, 0.f, 0.f, 0.f};
        acc0 = __builtin_amdgcn_mfma_f32_16x16x32_f16(a0, bf00, acc0, 0, 0, 0);
        acc1 = __builtin_amdgcn_mfma_f32_16x16x32_f16(a0, bf01, acc1, 0, 0, 0);
        acc0 = __builtin_amdgcn_mfma_f32_16x16x32_f16(a1, bf10, acc0, 0, 0, 0);
        acc1 = __builtin_amdgcn_mfma_f32_16x16x32_f16(a1, bf11, acc1, 0, 0, 0);
        acc0 = __builtin_amdgcn_mfma_f32_16x16x32_f16(a2, bf20, acc0, 0, 0, 0);
        acc1 = __builtin_amdgcn_mfma_f32_16x16x32_f16(a2, bf21, acc1, 0, 0, 0);
#pragma unroll
        for (int reg = 0; reg < 4; reg++) {
            float tp = fmaxf(acc0[reg] + b10, 0.f) * w20
                     + fmaxf(acc1[reg] + b11, 0.f) * w21;
            tp += __shfl_xor(tp, 1);
            tp += __shfl_xor(tp, 2);
            tp += __shfl_xor(tp, 4);
            tp += __shfl_xor(tp, 8);
            int edge = base + q * 4 + reg;
            if (m == 0 && edge < E) out[perm[edge]] = tp + b2;
        }
    }
}

extern "C" void kernel_launch(void* const* d_in, const int* in_sizes, int n_in,
                              void* d_out, int out_size, void* d_ws, size_t ws_size,
                              hipStream_t stream)
{
    const int N = in_sizes[0];
    const int E = in_sizes[1];

    const float* x    = (const float*)d_in[0];
    const float* e_in = (const float*)d_in[1];
    const int*   eidx = (const int*)d_in[2];
    const float* pe_w = (const float*)d_in[3];
    const float* pe_b = (const float*)d_in[4];
    const float* ed_w = (const float*)d_in[5];
    const float* ed_b = (const float*)d_in[6];
    const float* Aw = (const float*)d_in[7];
    const float* Ab = (const float*)d_in[8];
    const float* Bw = (const float*)d_in[9];
    const float* Bb = (const float*)d_in[10];
    const float* Cw = (const float*)d_in[11];
    const float* Cb = (const float*)d_in[12];
    const float* Uw = (const float*)d_in[13];
    const float* Ub = (const float*)d_in[14];
    const float* Vw = (const float*)d_in[15];
    const float* Vb = (const float*)d_in[16];
    const float* bn_h_g = (const float*)d_in[17];
    const float* bn_h_b = (const float*)d_in[18];
    const float* bn_e_g = (const float*)d_in[19];
    const float* bn_e_b = (const float*)d_in[20];
    const float* W1w = (const float*)d_in[21];
    const float* W1b = (const float*)d_in[22];
    const float* W2w = (const float*)d_in[23];
    const float* W2b = (const float*)d_in[24];

    const int* srcs = eidx;
    const int* dsts = eidx + E;

    size_t nh = (size_t)N * 32;
    size_t eh = (size_t)E * 32;

    float* ws = (float*)d_ws;
    float* stats     = ws;                            // 128
    float* partial_h = stats + 128;                   // GRID_STRIDE*64
    float* partial_e = partial_h + GRID_STRIDE * 64;  // GRID_STRIDE*64
    float* h    = partial_e + GRID_STRIDE * 64;       // nh floats
    float* hnew = h + nh;                             // nh floats (Uh then h_new)
    __half* Ah  = (__half*)(hnew + nh);               // nh halves (h16 at the end)
    __half* Bh  = Ah + nh;                            // nh halves
    __half* Vh  = Bh + nh;                            // nh halves
    __half* ep  = Vh + nh;                            // eh halves (final e16 at the end)
    __half* enh = ep + eh;                            // eh halves
    int* counts    = (int*)(enh + eh);
    int* offsets   = counts + N;
    int* cursor    = offsets + N;
    int* blocksums = cursor + N;   // 128
    int* perm      = blocksums + 128;
    int* srcp      = perm + E;
    int* dstp      = srcp + E;

    size_t nh4 = nh / 4, eh4 = eh / 4;
    int gh4 = (int)((nh4 + 255) / 256);
    int ge4 = (int)((eh4 + 255) / 256);
    int gN = (N + 255) / 256;
    int gE = (E + 255) / 256;
    int nb = (N + 1023) / 1024;

    // ---- CSR build (dst-sorted edge permutation) ----
    zero_ints<<<gN, 256, 0, stream>>>(counts, N);
    hist_kernel<<<gE, 256, 0, stream>>>(dsts, counts, E);
    scan1<<<nb, 256, 0, stream>>>(counts, offsets, blocksums, N);
    scan2<<<1, 64, 0, stream>>>(blocksums, nb);
    scan3<<<gN, 256, 0, stream>>>(offsets, blocksums, cursor, N);
    scatter_kernel<<<gE, 256, 0, stream>>>(srcs, dsts, cursor, perm, srcp, dstp, E);

    // ---- input projections ----
    init_proj4<<<gh4, 256, 0, stream>>>(x, pe_w, pe_b, (float4*)h, nh4);
    init_ep16<<<ge4, 256, 0, stream>>>(e_in, perm, ed_w, ed_b, (__half2*)ep, eh4);

    for (int l = 0; l < NLAYERS; l++) {
        node_gemm<<<(N + 63) / 64, 64, 0, stream>>>(h,
            Aw + l * 1024, Ab + l * 32,
            Bw + l * 1024, Bb + l * 32,
            Uw + l * 1024, Ub + l * 32,
            Vw + l * 1024, Vb + l * 32,
            Ah, Bh, hnew, Vh, N);
        edge_en<<<GRID_STRIDE, 256, 0, stream>>>(ep, srcp, dstp, Ah, Bh,
            Cw + l * 1024, Cb + l * 32, enh, partial_e, E);
        stats_side<<<32, 256, 0, stream>>>(partial_e, GRID_STRIDE, (double)E,
            bn_e_g + l * 32, bn_e_b + l * 32, stats + 64, stats + 96);
        node_agg<<<GRID_STRIDE, 256, 0, stream>>>(enh, srcp, offsets, counts,
            Vh, hnew, ep, stats + 64, stats + 96, partial_h, N);
        stats_side<<<32, 256, 0, stream>>>(partial_h, GRID_STRIDE, (double)N,
            bn_h_g + l * 32, bn_h_b + l * 32, stats + 0, stats + 32);
        if (l < NLAYERS - 1)
            apply4<<<gh4, 256, 0, stream>>>((const float4*)hnew, stats + 0, stats + 32,
                                            (float4*)h, nh4);
        else
            apply4_h16<<<gh4, 256, 0, stream>>>((const float4*)hnew, stats + 0, stats + 32,
                                                (const float4*)h, (__half2*)Ah, nh4);
    }

    predictor<<<GRID_STRIDE, 256, 0, stream>>>((const __half*)Ah, (const __half*)ep,
                                               srcp, dstp, perm, W1w, W1b, W2w, W2b,
                                               (float*)d_out, E);
}